// Round 9
// baseline (2339.348 us; speedup 1.0000x reference)
//
#include <hip/hip_runtime.h>
#include <string.h>

#define EN 8000
#define AN 800

typedef __attribute__((ext_vector_type(8))) short bf16x8;
typedef __attribute__((ext_vector_type(4))) float f32x4;
typedef unsigned short ushort_t;
typedef unsigned int uint32;

__constant__ int c_perm[49] = {
  0,2,6,12,20,30,42,
  1,5,11,19,29,41,
  3,7,13,21,31,43,
  4,10,18,28,40,
  8,14,22,32,44,
  9,17,27,39,
  15,23,33,45,
  16,26,38,
  24,34,46,
  25,37,
  35,47,
  36,
  48
};

__device__ __forceinline__ float siluf(float x) { return x / (1.0f + __expf(-x)); }
__device__ __forceinline__ ushort_t f2bf(float f) {
  uint32 u = __float_as_uint(f);
  u += 0x7fff + ((u >> 16) & 1);
  return (ushort_t)(u >> 16);
}
__device__ __forceinline__ float bf2f(ushort_t h) {
  return __uint_as_float(((uint32)h) << 16);
}
__device__ __forceinline__ void gld16(const void* g, void* l) {
  __builtin_amdgcn_global_load_lds(
      (const __attribute__((address_space(1))) void*)g,
      (__attribute__((address_space(3))) void*)l, 16, 0, 0);
}

// ---------------------------------------------------------------------------
// Weight builders (bf16 outputs)
// ---------------------------------------------------------------------------
__global__ __launch_bounds__(256) void k_build_b2b(
    const float* __restrict__ sw2r, const float* __restrict__ sw2i,
    const float* __restrict__ tw2r, const float* __restrict__ tw2i,
    ushort_t* __restrict__ dst)
{
  long long id = (long long)blockIdx.x * 256 + threadIdx.x;
  if (id >= 5505024LL) return;
  long long base = 0; int m = 1, k = 768;
  for (; m <= 6; ++m) {
    k = (7 - m) * 128;
    long long sz = 2LL * k * 1024;
    if (id < base + sz) break;
    base += sz;
  }
  long long rem = id - base;
  int p = (int)(rem / ((long long)k * 1024));
  int cj = (int)(rem - (long long)p * k * 1024);
  int c = cj >> 10, j = cj & 1023;
  int q = j >> 8, jj = j & 255;
  const float sgn = (q & 1) ? (p ? 1.f : -1.f) : 1.f;
  const float* src = (q < 2) ? (q == 0 ? sw2r : sw2i) : (q == 2 ? tw2r : tw2i);
  dst[id] = f2bf(sgn * src[(long long)(m - 1) * 196608 + c * 256 + jj]);
}

__global__ __launch_bounds__(256) void k_build_bgcat(
    const float* __restrict__ sw0, const float* __restrict__ tw0,
    const float* __restrict__ sw4, const float* __restrict__ tw4,
    const float* __restrict__ sb0, const float* __restrict__ tb0b,
    const float* __restrict__ sbd, const float* __restrict__ tbd,
    ushort_t* __restrict__ w, float* __restrict__ b)
{
  int id = blockIdx.x * 256 + threadIdx.x;
  if (id < 851968) {
    int r = id >> 7, c = id & 127;
    float v;
    if (r < 256) v = sw0[r * 128 + c];
    else if (r < 512) v = tw0[(r - 256) * 128 + c];
    else {
      int rr = r - 512, m = rr >> 10, q = rr & 1023;
      v = (q < 512) ? sw4[m * 65536 + q * 128 + c] : tw4[m * 65536 + (q - 512) * 128 + c];
    }
    w[id] = f2bf(v);
    return;
  }
  id -= 851968;
  if (id < 6656) {
    float v;
    if (id < 256) v = sb0[id];
    else if (id < 512) v = tb0b[id - 256];
    else {
      int rr = id - 512, m = rr >> 10, q = rr & 1023;
      v = (q < 512) ? sbd[m * 512 + q] : tbd[m * 512 + (q - 512)];
    }
    b[id] = v;
  }
}

__global__ __launch_bounds__(256) void k_build_b20b(
    const float* __restrict__ sw3, const float* __restrict__ tw3,
    ushort_t* __restrict__ b20)
{
  int id = blockIdx.x * 256 + threadIdx.x;
  if (id >= 458752) return;
  int cc = id >> 9, j = id & 511;
  b20[id] = f2bf((j < 256) ? sw3[cc * 256 + j] : tw3[cc * 256 + (j - 256)]);
}

__global__ __launch_bounds__(256) void k_build_s1m(
    const float* __restrict__ sw6, const float* __restrict__ sw8,
    const float* __restrict__ tw6, const float* __restrict__ tw8,
    ushort_t* __restrict__ dst)
{
  long long id = (long long)blockIdx.x * 256 + threadIdx.x;
  if (id >= 2752512LL) return;
  long long base = 0; int m = 1, k = 768;
  for (; m <= 6; ++m) {
    k = (7 - m) * 128;
    long long sz = 1024LL * k;
    if (id < base + sz) break;
    base += sz;
  }
  long long rem = id - base;
  int s = (int)(rem / (512LL * k));
  int rr = (int)(rem - (long long)s * 512 * k);
  int r = rr / k, c = rr - r * k;
  const float* src = (r < 256) ? (s ? tw6 : sw6) : (s ? tw8 : sw8);
  int r0 = (r < 256) ? r : r - 256;
  dst[id] = f2bf(src[(long long)(m - 1) * 196608 + r0 * 768 + c]);
}

// merged f32->bf16 conversions (up to 9 segments)
struct CvtM {
  const float* s[9];
  ushort_t* d[9];
  long long start[10];
};
__global__ __launch_bounds__(256) void k_cvt_multi(CvtM P) {
  long long id = (long long)blockIdx.x * 256 + threadIdx.x;
  if (id >= P.start[9]) return;
  int seg = 0;
  #pragma unroll
  for (int i = 1; i < 9; ++i) if (id >= P.start[i]) seg = i;
  long long o = id - P.start[seg];
  P.d[seg][o] = f2bf(P.s[seg][o]);
}

__global__ __launch_bounds__(256) void k_cvt(
    const float* __restrict__ src, ushort_t* __restrict__ dst, int n)
{
  int id = blockIdx.x * 256 + threadIdx.x;
  if (id < n) dst[id] = f2bf(src[id]);
}

__global__ __launch_bounds__(256) void k_build_tg(
    const float* __restrict__ tg, ushort_t* __restrict__ dst)
{
  int id = blockIdx.x * 256 + threadIdx.x;
  if (id >= 98 * 49) return;
  int r = id / 49, s = id - r * 49;
  dst[id] = f2bf(tg[r * 49 + c_perm[s]]);
}

// transpose x (f32 [49][128]) -> xbT (bf16 [128][64], j-padded)
__global__ __launch_bounds__(256) void k_xT(
    const float* __restrict__ x, ushort_t* __restrict__ xbT)
{
  __shared__ __align__(16) float xs[49 * 128];
  const int a = blockIdx.x, t = threadIdx.x;
  const float4* src = (const float4*)(x + (long long)a * 6272);
  float4* d = (float4*)xs;
  for (int i = t; i < 1568; i += 256) d[i] = src[i];
  __syncthreads();
  ushort_t* o = xbT + (long long)a * 8192;
  int c = t >> 1;
  int jg = (t & 1) << 2;
  #pragma unroll
  for (int u = 0; u < 4; ++u) {
    int g = jg + u;
    bf16x8 v = (bf16x8)0;
    #pragma unroll
    for (int j = 0; j < 8; ++j) {
      int jj = (g << 3) + j;
      if (jj < 49) v[j] = (short)f2bf(xs[jj * 128 + c]);
    }
    *(bf16x8*)&o[(c << 6) + (g << 3)] = v;
  }
}

// ---------------------------------------------------------------------------
// Edge features
// ---------------------------------------------------------------------------
__global__ __launch_bounds__(256) void k_basis(
    const float* __restrict__ dist, ushort_t* __restrict__ basis)
{
  int id = blockIdx.x * 256 + threadIdx.x;
  if (id >= EN * 512) return;
  int e = id >> 9, g = id & 511;
  const float step = 8.0f / 511.0f;
  const float coeff = -2040.0078125f;
  float df = dist[e] - (float)g * step;
  basis[id] = f2bf(expf(coeff * df * df));
}

__global__ __launch_bounds__(256) void k_emb(
    const float* __restrict__ src_emb, const float* __restrict__ tgt_emb,
    const int* __restrict__ anum, const int* __restrict__ eidx,
    const float* __restrict__ xd, ushort_t* __restrict__ out)
{
  int id = blockIdx.x * 256 + threadIdx.x;
  if (id >= EN * 128) return;
  int e = id >> 7, c = id & 127;
  int a0 = anum[eidx[e]], a1 = anum[eidx[EN + e]];
  out[id] = f2bf(siluf(src_emb[a0 * 128 + c] + tgt_emb[a1 * 128 + c] + xd[id]));
}

// ---------------------------------------------------------------------------
// MFMA Wigner rotation with coalesced (repacked) output
// ---------------------------------------------------------------------------
__global__ __launch_bounds__(256) void k_rot2(
    const float* __restrict__ wig, const ushort_t* __restrict__ xbT,
    const int* __restrict__ srcl, const int* __restrict__ tgtl,
    ushort_t* __restrict__ osrc, ushort_t* __restrict__ otgt)
{
  __shared__ short Ws[4096];
  __shared__ short Xs[8192];
  __shared__ short Xt[8192];
  const int e = blockIdx.x, tid = threadIdx.x;
  const int lane = tid & 63, wave = tid >> 6;
  const float* wge = wig + (long long)e * 2401;
  #pragma unroll
  for (int t = 0; t < 2; ++t) {
    int ci = (t << 8) + tid;
    int row = ci >> 3, g = ci & 7;
    bf16x8 v = (bf16x8)0;
    if (row < 49) {
      const float* wr = wge + c_perm[row] * 49;
      #pragma unroll
      for (int j = 0; j < 8; ++j) {
        int col = (g << 3) + j;
        if (col < 49) v[j] = (short)f2bf(wr[col]);
      }
    }
    *(bf16x8*)&Ws[(row << 6) + ((g ^ (row & 7)) << 3)] = v;
  }
  const int as = srcl[e], at = tgtl[e];
  const ushort_t* xsg = xbT + (long long)as * 8192;
  const ushort_t* xtg = xbT + (long long)at * 8192;
  #pragma unroll
  for (int t = 0; t < 4; ++t) {
    int ci = (t << 8) + tid;
    int row = ci >> 3, g = ci & 7;
    int ofs = (row << 6) + ((g ^ (row & 7)) << 3);
    *(bf16x8*)&Xs[ofs] = *(const bf16x8*)&xsg[ci << 3];
    *(bf16x8*)&Xt[ofs] = *(const bf16x8*)&xtg[ci << 3];
  }
  __syncthreads();
  const short* Xb = (wave >> 1) ? Xt : Xs;
  const int ch = (wave & 1) << 6;
  const int fr = lane & 15, g = lane >> 4;
  f32x4 acc[4][4];
  #pragma unroll
  for (int i = 0; i < 4; ++i)
    #pragma unroll
    for (int j = 0; j < 4; ++j) acc[i][j] = (f32x4){0.f, 0.f, 0.f, 0.f};
  #pragma unroll
  for (int ks = 0; ks < 2; ++ks) {
    bf16x8 af[4], bfv[4];
    int lc = (ks << 2) + g;
    #pragma unroll
    for (int i = 0; i < 4; ++i) {
      int ra = (i << 4) + fr;
      af[i] = *(const bf16x8*)&Ws[(ra << 6) + ((lc ^ (ra & 7)) << 3)];
      int rb = ch + (i << 4) + fr;
      bfv[i] = *(const bf16x8*)&Xb[(rb << 6) + ((lc ^ (rb & 7)) << 3)];
    }
    #pragma unroll
    for (int i = 0; i < 4; ++i)
      #pragma unroll
      for (int j = 0; j < 4; ++j)
        acc[i][j] = __builtin_amdgcn_mfma_f32_16x16x32_bf16(af[i], bfv[j], acc[i][j], 0, 0, 0);
  }
  const int crl = (lane >> 4) << 2, ccl = lane & 15;
  __syncthreads();
  short* Ob = (wave >> 1) ? Xt : Xs;
  #pragma unroll
  for (int i = 0; i < 4; ++i)
    #pragma unroll
    for (int r = 0; r < 4; ++r) {
      int q = (i << 4) + crl + r;
      if (q < 49) {
        #pragma unroll
        for (int j = 0; j < 4; ++j) {
          int col = ch + (j << 4) + ccl;
          Ob[(q << 7) + (((col >> 3) ^ (q & 15)) << 3) + (col & 7)] =
              (short)f2bf(acc[i][j][r]);
        }
      }
    }
  __syncthreads();
  for (int gid = tid; gid < 1568; gid += 256) {
    int half = gid >= 784;
    int c784 = half ? gid - 784 : gid;
    int row = c784 >> 4, cc = c784 & 15;
    const short* Sb = half ? Xt : Xs;
    bf16x8 v = *(const bf16x8*)&Sb[(row << 7) + ((cc ^ (row & 15)) << 3)];
    ushort_t* dst = (half ? otgt : osrc) + (long long)e * 6272 + (row << 7) + (cc << 3);
    *(bf16x8*)dst = v;
  }
}

// ---------------------------------------------------------------------------
// Grouped MFMA GEMM with optional FUSED GATE (in-LDS mini-GEMM).
// ---------------------------------------------------------------------------
struct GemmP {
  const ushort_t* A; const ushort_t* A2; const ushort_t* B;
  const float* bias; const ushort_t* gate; void* C;
  const ushort_t* gxe;   // fused-gate: x_edge chunk base (pair-dup A)
  const ushort_t* gw;    // fused-gate: bgcw base
  const float* gb;       // fused-gate: bgcb base
  int a_se, a_si, pair, asplit;
  int ldb;
  int gate_ofs, gse;
  int c_se, c_si, c_ofs;
  int ihalf, act, c_bf16;
  int M, N, K;
  int ngx, wg_base;
};
struct Grouped { GemmP d[14]; int nd; int nwg; };

__global__ __launch_bounds__(256) void gemm_g(Grouped G) {
  __shared__ short SH[16384];   // staging dbuf + epilogue C repack
  __shared__ short GH[8192];    // fused-gate staging / gate tile
  short* As = SH;
  short* Bs = SH + 8192;
  int bid;
  {
    int n = G.nwg, orig = blockIdx.x;
    int q = n >> 3, r = n & 7;
    int xcd = orig & 7, pos = orig >> 3;
    bid = (xcd < r ? xcd * (q + 1) : r * (q + 1) + (xcd - r) * q) + pos;
  }
  int di = G.nd - 1;
  for (int i = 1; i < G.nd; ++i) if (bid < G.d[i].wg_base) { di = i - 1; break; }
  const GemmP p = G.d[di];
  const int local = bid - p.wg_base;
  const int bx = local % p.ngx, by = local / p.ngx;
  const int m0 = bx << 7, n0 = by << 7;

  const int tid = threadIdx.x;
  const int lane = tid & 63, wave = tid >> 6;
  const int gl = ((lane & 3) ^ ((lane >> 3) & 3)) << 3;
  const int grow = (wave << 4) + (lane >> 2);
  const int fr = lane & 15, fkg = lane >> 4;
  const int sxor = (fr >> 1) & 3;
  const int wm = (wave >> 1) << 6, wn = (wave & 1) << 6;

  f32x4 acc[4][4];
  #pragma unroll
  for (int i = 0; i < 4; ++i)
    #pragma unroll
    for (int j = 0; j < 4; ++j) acc[i][j] = (f32x4){0.f, 0.f, 0.f, 0.f};

  long long abase;
  {
    int r0 = m0 + grow;
    abase = p.pair
        ? (long long)(r0 >> 1) * p.a_se + (long long)(r0 & 1) * p.a_si
        : (long long)r0 * p.a_se;
  }
  long long abase2;
  {
    int r1 = m0 + 64 + grow;
    abase2 = p.pair
        ? (long long)(r1 >> 1) * p.a_se + (long long)(r1 & 1) * p.a_si
        : (long long)r1 * p.a_se;
  }
  const long long bbase  = (long long)(n0 + grow) * p.ldb;
  const long long bbase2 = (long long)(n0 + 64 + grow) * p.ldb;

  const int nt = p.K >> 5;

  auto STAGE = [&](int buf, int k0) {
    const ushort_t* Ap = p.A;
    int kk = k0;
    if (p.A2 && k0 >= p.asplit) { Ap = p.A2; kk = k0 - p.asplit; }
    const int lofs = (buf << 12) + (wave << 9);
    gld16(Ap + abase + kk + gl,   &As[lofs]);
    gld16(p.B + bbase + k0 + gl,  &Bs[lofs]);
    gld16(Ap + abase2 + kk + gl,  &As[lofs + 2048]);
    gld16(p.B + bbase2 + k0 + gl, &Bs[lofs + 2048]);
  };

  STAGE(0, 0);
  int cur = 0;
  for (int t = 0; t < nt; ++t) {
    if (t + 1 < nt) {
      STAGE(cur ^ 1, (t + 1) << 5);
      asm volatile("s_waitcnt vmcnt(4)" ::: "memory");
    } else {
      asm volatile("s_waitcnt vmcnt(0)" ::: "memory");
    }
    __builtin_amdgcn_sched_barrier(0);
    __builtin_amdgcn_s_barrier();
    {
      const int bofs = cur << 12;
      bf16x8 af[4], bfv[4];
      #pragma unroll
      for (int i = 0; i < 4; ++i) {
        int ra = wm + (i << 4) + fr;
        int rb = wn + (i << 4) + fr;
        af[i]  = *(const bf16x8*)&As[bofs + (ra << 5) + ((fkg ^ sxor) << 3)];
        bfv[i] = *(const bf16x8*)&Bs[bofs + (rb << 5) + ((fkg ^ sxor) << 3)];
      }
      #pragma unroll
      for (int i = 0; i < 4; ++i)
        #pragma unroll
        for (int j = 0; j < 4; ++j)
          acc[i][j] = __builtin_amdgcn_mfma_f32_16x16x32_bf16(af[i], bfv[j], acc[i][j], 0, 0, 0);
    }
    __builtin_amdgcn_s_barrier();
    cur ^= 1;
  }

  const int crl = (lane >> 4) << 2, ccl = lane & 15;
  if (p.c_bf16) {
    // 1) acc (+bias/act) -> SH[128][128] bf16 swizzled
    #pragma unroll
    for (int mi = 0; mi < 4; ++mi)
      #pragma unroll
      for (int r = 0; r < 4; ++r) {
        int lrow = wm + mi * 16 + crl + r;
        #pragma unroll
        for (int ni = 0; ni < 4; ++ni) {
          int lcol = wn + ni * 16 + ccl;
          float v = acc[mi][ni][r];
          int gc = n0 + lcol;
          if (p.bias) v += p.bias[gc];
          if (p.act)  v = siluf(v);
          SH[(lrow << 7) + (((lcol >> 3) ^ (lrow & 15)) << 3) + (lcol & 7)] =
              (short)f2bf(v);
        }
      }
    __syncthreads();

    // 2) fused gate mini-GEMM (K=128, 4 steps) into GH gate tile [64][128]
    if (p.gxe) {
      f32x4 gacc[4][4];
      #pragma unroll
      for (int i = 0; i < 4; ++i)
        #pragma unroll
        for (int j = 0; j < 4; ++j) gacc[i][j] = (f32x4){0.f, 0.f, 0.f, 0.f};
      #pragma unroll
      for (int ks = 0; ks < 4; ++ks) {
        #pragma unroll
        for (int t = 0; t < 2; ++t) {
          int row = (t << 6) + grow;
          int ar = m0 + row;
          int eidx = p.pair ? (ar >> 1) : ar;
          bf16x8 av = *(const bf16x8*)&p.gxe[(long long)eidx * 128 + (ks << 5) + gl];
          *(bf16x8*)&GH[(row << 5) + ((lane & 3) << 3)] = av;
          bf16x8 bv = *(const bf16x8*)&p.gw[
              (long long)(p.gate_ofs + n0 + row) * 128 + (ks << 5) + gl];
          *(bf16x8*)&GH[4096 + (row << 5) + ((lane & 3) << 3)] = bv;
        }
        __syncthreads();
        bf16x8 af[4], bfv[4];
        #pragma unroll
        for (int i = 0; i < 4; ++i) {
          int ra = wm + (i << 4) + fr;
          int rb = wn + (i << 4) + fr;
          af[i]  = *(const bf16x8*)&GH[(ra << 5) + ((fkg ^ sxor) << 3)];
          bfv[i] = *(const bf16x8*)&GH[4096 + (rb << 5) + ((fkg ^ sxor) << 3)];
        }
        #pragma unroll
        for (int i = 0; i < 4; ++i)
          #pragma unroll
          for (int j = 0; j < 4; ++j)
            gacc[i][j] = __builtin_amdgcn_mfma_f32_16x16x32_bf16(af[i], bfv[j], gacc[i][j], 0, 0, 0);
        __syncthreads();
      }
      // bias + silu, write gate tile (pair rows write identical values)
      #pragma unroll
      for (int mi = 0; mi < 4; ++mi)
        #pragma unroll
        for (int r = 0; r < 4; ++r) {
          int lrow = wm + mi * 16 + crl + r;
          int gr = p.pair ? (lrow >> 1) : (lrow & 63);
          #pragma unroll
          for (int ni = 0; ni < 4; ++ni) {
            int lcol = wn + ni * 16 + ccl;
            float gv = siluf(gacc[mi][ni][r] + p.gb[p.gate_ofs + n0 + lcol]);
            GH[(gr << 7) + lcol] = (short)f2bf(gv);
          }
        }
      __syncthreads();
    }

    // 3) coalesced output: 1 row, 64 cols per thread
    const int lr = tid >> 1, chalf = (tid & 1) << 6;
    int gr = m0 + lr;
    if (gr < p.M) {
      long long e; int ii;
      if (p.pair) { e = gr >> 1; ii = gr & 1; } else { e = gr; ii = 0; }
      const ushort_t* grw = p.gate ? p.gate + e * p.gse + p.gate_ofs : nullptr;
      #pragma unroll
      for (int j = 0; j < 8; ++j) {
        int lcol = chalf + (j << 3);
        bf16x8 v = *(const bf16x8*)&SH[(lr << 7) + (((lcol >> 3) ^ (lr & 15)) << 3)];
        int gc = n0 + lcol;
        if (p.gxe) {
          int gr2 = p.pair ? (lr >> 1) : lr;
          bf16x8 g8 = *(const bf16x8*)&GH[(gr2 << 7) + lcol];
          #pragma unroll
          for (int q2 = 0; q2 < 8; ++q2)
            v[q2] = (short)f2bf(bf2f((ushort_t)v[q2]) * bf2f((ushort_t)g8[q2]));
        } else if (grw) {
          bf16x8 g8 = *(const bf16x8*)&grw[gc];
          #pragma unroll
          for (int q2 = 0; q2 < 8; ++q2)
            v[q2] = (short)f2bf(bf2f((ushort_t)v[q2]) * bf2f((ushort_t)g8[q2]));
        }
        int par = (p.ihalf && gc >= 256) ? (1 - ii) : ii;
        long long co = e * (long long)p.c_se + (long long)par * p.c_si + p.c_ofs + gc;
        *(bf16x8*)&((ushort_t*)p.C)[co] = v;
      }
    }
  } else {
    #pragma unroll
    for (int mi = 0; mi < 4; ++mi) {
      #pragma unroll
      for (int r = 0; r < 4; ++r) {
        int gr = m0 + wm + mi * 16 + crl + r;
        if (gr >= p.M) continue;
        long long e = gr;
        float* crow = (float*)p.C + e * (long long)p.c_se + p.c_ofs;
        #pragma unroll
        for (int ni = 0; ni < 4; ++ni) {
          int gc = n0 + wn + ni * 16 + ccl;
          if (gc >= p.N) continue;
          float v = acc[mi][ni][r];
          if (p.bias) v += p.bias[gc];
          if (p.act)  v = siluf(v);
          crow[gc] = v;
        }
      }
    }
  }
}

// ---------------------------------------------------------------------------
// gridmm (atom phase)
// ---------------------------------------------------------------------------
struct GridP {
  const float* A; const ushort_t* B; void* C; const float* bias;
  int b_ib, c_ib;
  int M, K, permA, act, c_bf16;
};

#define LDW 40

__global__ __launch_bounds__(256) void gridmm(GridP p) {
  __shared__ short As[128 * LDW];
  __shared__ short Bs[128 * LDW];
  const int e = blockIdx.x;
  const int tid = threadIdx.x;
  const int srow = tid >> 1, sk = (tid & 1) << 4;
  const int lane = tid & 63, wave = tid >> 6;
  const int wm = (wave >> 1) << 6, wn = (wave & 1) << 6;
  const int fr = lane & 15, fk = (lane >> 4) << 3;

  f32x4 acc[4][4];
  #pragma unroll
  for (int i = 0; i < 4; ++i)
    #pragma unroll
    for (int j = 0; j < 4; ++j) acc[i][j] = (f32x4){0.f, 0.f, 0.f, 0.f};

  const ushort_t* bp0 = p.B + (long long)e * p.b_ib;

  for (int k0 = 0; k0 < p.K; k0 += 32) {
    {
      bf16x8 lo = (bf16x8)0, hi = (bf16x8)0;
      if (srow < p.M) {
        const float* ar = p.A + srow * p.K;
        #pragma unroll
        for (int j = 0; j < 8; ++j) {
          int col = k0 + sk + j;
          float v = 0.f;
          if (col < p.K) v = ar[p.permA ? c_perm[col] : col];
          lo[j] = (short)f2bf(v);
        }
        #pragma unroll
        for (int j = 0; j < 8; ++j) {
          int col = k0 + sk + 8 + j;
          float v = 0.f;
          if (col < p.K) v = ar[p.permA ? c_perm[col] : col];
          hi[j] = (short)f2bf(v);
        }
      }
      *(bf16x8*)&As[srow * LDW + sk] = lo;
      *(bf16x8*)&As[srow * LDW + sk + 8] = hi;
    }
    {
      const int c = tid & 127, kq = tid >> 7;
      #pragma unroll
      for (int i = 0; i < 8; ++i) {
        int kk = kq * 16 + i * 2;
        int k1 = k0 + kk, k2 = k1 + 1;
        uint32 v0 = (k1 < p.K) ? (uint32)bp0[(long long)k1 * 128 + c] : 0u;
        uint32 v1 = (k2 < p.K) ? (uint32)bp0[(long long)k2 * 128 + c] : 0u;
        *(uint32*)&Bs[c * LDW + kk] = v0 | (v1 << 16);
      }
    }
    __syncthreads();
    bf16x8 af[4], bfv[4];
    #pragma unroll
    for (int i = 0; i < 4; ++i) {
      af[i]  = *(const bf16x8*)(&As[(wm + i * 16 + fr) * LDW + fk]);
      bfv[i] = *(const bf16x8*)(&Bs[(wn + i * 16 + fr) * LDW + fk]);
    }
    #pragma unroll
    for (int i = 0; i < 4; ++i)
      #pragma unroll
      for (int j = 0; j < 4; ++j)
        acc[i][j] = __builtin_amdgcn_mfma_f32_16x16x32_bf16(af[i], bfv[j], acc[i][j], 0, 0, 0);
    __syncthreads();
  }

  const int crl = (lane >> 4) << 2, ccl = lane & 15;
  #pragma unroll
  for (int mi = 0; mi < 4; ++mi) {
    #pragma unroll
    for (int r = 0; r < 4; ++r) {
      int gr = wm + mi * 16 + crl + r;
      if (gr >= p.M) continue;
      #pragma unroll
      for (int ni = 0; ni < 4; ++ni) {
        int c = wn + ni * 16 + ccl;
        float v = acc[mi][ni][r];
        if (p.bias) v += p.bias[c];
        if (p.act)  v = siluf(v);
        long long co = (long long)e * p.c_ib + gr * 128 + c;
        if (p.c_bf16) ((ushort_t*)p.C)[co] = f2bf(v);
        else          ((float*)p.C)[co] = v;
      }
    }
  }
}

// ---------------------------------------------------------------------------
// Fused grid pipeline per edge: msg3 = WI @ (FG @ silu(TGp @ msgp))
// ---------------------------------------------------------------------------
#define SWZ8(cg, r) (((cg) ^ ((r) & 7)) & 7)
#define SWZ16(cg, r) (((cg) & 8) | (((cg) ^ (r)) & 7))

__global__ __launch_bounds__(256, 2) void k_grid(
    const ushort_t* __restrict__ tgb, const ushort_t* __restrict__ fgb,
    const float* __restrict__ wigv, const ushort_t* __restrict__ msgp,
    ushort_t* __restrict__ msg3)
{
  __shared__ short Abuf[8192];
  __shared__ short Bsh[8192];
  __shared__ short Ps[16384];
  const int e = blockIdx.x, tid = threadIdx.x;
  const int lane = tid & 63, wv = tid >> 6;
  const int fr = lane & 15, fk = (lane >> 4) << 3;
  const int crl = (lane >> 4) << 2, ccl = lane & 15;
  const ushort_t* me = msgp + (long long)e * 6272;

  for (int gid = tid; gid < 896; gid += 256) {
    int r = gid >> 3, cg = gid & 7;
    bf16x8 v = (bf16x8)0;
    if (r < 98) {
      #pragma unroll
      for (int j = 0; j < 8; ++j) {
        int col = (cg << 3) + j;
        if (col < 49) v[j] = (short)tgb[r * 49 + col];
      }
    }
    *(bf16x8*)&Abuf[(r << 6) + (SWZ8(cg, r) << 3)] = v;
  }
  for (int gid = tid; gid < 1024; gid += 256) {
    int kg = gid >> 7, c = gid & 127;
    bf16x8 v = (bf16x8)0;
    #pragma unroll
    for (int j = 0; j < 8; ++j) {
      int k = (kg << 3) + j;
      if (k < 49) v[j] = (short)me[k * 128 + c];
    }
    *(bf16x8*)&Bsh[(c << 6) + (SWZ8(kg, c) << 3)] = v;
  }
  {
    int c = tid >> 1, gg = 14 + (tid & 1);
    *(bf16x8*)&Ps[(c << 7) + (SWZ16(gg, c) << 3)] = (bf16x8)0;
  }
  __syncthreads();

  {
    f32x4 acc[7][2];
    #pragma unroll
    for (int i = 0; i < 7; ++i) { acc[i][0] = (f32x4){0,0,0,0}; acc[i][1] = (f32x4){0,0,0,0}; }
    #pragma unroll
    for (int k0 = 0; k0 < 64; k0 += 32) {
      int cg = (k0 + fk) >> 3;
      int br0 = ((2 * wv) << 4) + fr, br1 = ((2 * wv + 1) << 4) + fr;
      bf16x8 bf0 = *(const bf16x8*)&Bsh[(br0 << 6) + (SWZ8(cg, br0) << 3)];
      bf16x8 bf1 = *(const bf16x8*)&Bsh[(br1 << 6) + (SWZ8(cg, br1) << 3)];
      #pragma unroll
      for (int rt = 0; rt < 7; ++rt) {
        int ar = (rt << 4) + fr;
        bf16x8 af = *(const bf16x8*)&Abuf[(ar << 6) + (SWZ8(cg, ar) << 3)];
        acc[rt][0] = __builtin_amdgcn_mfma_f32_16x16x32_bf16(af, bf0, acc[rt][0], 0, 0, 0);
        acc[rt][1] = __builtin_amdgcn_mfma_f32_16x16x32_bf16(af, bf1, acc[rt][1], 0, 0, 0);
      }
    }
    #pragma unroll
    for (int rt = 0; rt < 7; ++rt)
      #pragma unroll
      for (int cj = 0; cj < 2; ++cj) {
        int c = ((2 * wv + cj) << 4) + ccl;
        #pragma unroll
        for (int r = 0; r < 4; ++r) {
          int g = (rt << 4) + crl + r;
          Ps[(c << 7) + (SWZ16(g >> 3, c) << 3) + (g & 7)] =
              (short)f2bf(siluf(acc[rt][cj][r]));
        }
      }
  }
  __syncthreads();
  for (int gid = tid; gid < 1024; gid += 256) {
    int r = gid >> 4, cg = gid & 15;
    bf16x8 v = (bf16x8)0;
    if (r < 49) {
      #pragma unroll
      for (int j = 0; j < 8; ++j) {
        int col = (cg << 3) + j;
        if (col < 98) v[j] = (short)fgb[r * 98 + col];
      }
    }
    *(bf16x8*)&Abuf[(r << 7) + (SWZ16(cg, r) << 3)] = v;
  }
  __syncthreads();

  {
    f32x4 acc[4][2];
    #pragma unroll
    for (int i = 0; i < 4; ++i) { acc[i][0] = (f32x4){0,0,0,0}; acc[i][1] = (f32x4){0,0,0,0}; }
    #pragma unroll
    for (int k0 = 0; k0 < 128; k0 += 32) {
      int cg = (k0 + fk) >> 3;
      int br0 = ((2 * wv) << 4) + fr, br1 = ((2 * wv + 1) << 4) + fr;
      bf16x8 bf0 = *(const bf16x8*)&Ps[(br0 << 7) + (SWZ16(cg, br0) << 3)];
      bf16x8 bf1 = *(const bf16x8*)&Ps[(br1 << 7) + (SWZ16(cg, br1) << 3)];
      #pragma unroll
      for (int rt = 0; rt < 4; ++rt) {
        int ar = (rt << 4) + fr;
        bf16x8 af = *(const bf16x8*)&Abuf[(ar << 7) + (SWZ16(cg, ar) << 3)];
        acc[rt][0] = __builtin_amdgcn_mfma_f32_16x16x32_bf16(af, bf0, acc[rt][0], 0, 0, 0);
        acc[rt][1] = __builtin_amdgcn_mfma_f32_16x16x32_bf16(af, bf1, acc[rt][1], 0, 0, 0);
      }
    }
    #pragma unroll
    for (int rt = 0; rt < 4; ++rt)
      #pragma unroll
      for (int cj = 0; cj < 2; ++cj) {
        int c = ((2 * wv + cj) << 4) + ccl;
        #pragma unroll
        for (int r = 0; r < 4; ++r) {
          int q = (rt << 4) + crl + r;
          Bsh[(c << 6) + (SWZ8(q >> 3, c) << 3) + (q & 7)] = (short)f2bf(acc[rt][cj][r]);
        }
      }
  }
  __syncthreads();
  {
    const float* we = wigv + (long long)e * 2401;
    for (int gid = tid; gid < 512; gid += 256) {
      int r = gid >> 3, cg = gid & 7;
      bf16x8 v = (bf16x8)0;
      if (r < 49) {
        #pragma unroll
        for (int j = 0; j < 8; ++j) {
          int col = (cg << 3) + j;
          if (col < 49) v[j] = (short)f2bf(we[r * 49 + col]);
        }
      }
      *(bf16x8*)&Abuf[(r << 6) + (SWZ8(cg, r) << 3)] = v;
    }
  }
  __syncthreads();

  {
    f32x4 acc[4][2];
    #pragma unroll
    for (int i = 0; i < 4; ++i) { acc[i][0] = (f32x4){0,0,0,0}; acc[i][1] = (f32x4){0,0,0,0}; }
    #pragma unroll
    for (int k0 = 0; k0 < 64; k0 += 32) {
      int cg = (k0 + fk) >> 3;
      int br0 = ((2 * wv) << 4) + fr, br1 = ((2 * wv + 1) << 4) + fr;
      bf16x8 bf0 = *(const bf16x8*)&Bsh[(br0 << 6) + (SWZ8(cg, br0) << 3)];
      bf16x8 bf1 = *(const bf16x8*)&Bsh[(br1 << 6) + (SWZ8(cg, br1) << 3)];
      #pragma unroll
      for (int rt = 0; rt < 4; ++rt) {
        int ar = (rt << 4) + fr;
        bf16x8 af = *(const bf16x8*)&Abuf[(ar << 6) + (SWZ8(cg, ar) << 3)];
        acc[rt][0] = __builtin_amdgcn_mfma_f32_16x16x32_bf16(af, bf0, acc[rt][0], 0, 0, 0);
        acc[rt][1] = __builtin_amdgcn_mfma_f32_16x16x32_bf16(af, bf1, acc[rt][1], 0, 0, 0);
      }
    }
    #pragma unroll
    for (int rt = 0; rt < 4; ++rt)
      #pragma unroll
      for (int r = 0; r < 4; ++r) {
        int gi = (rt << 4) + crl + r;
        if (gi < 49) {
          #pragma unroll
          for (int cj = 0; cj < 2; ++cj) {
            int c = ((2 * wv + cj) << 4) + ccl;
            Ps[(gi << 7) + (((c >> 3) ^ (gi & 15)) << 3) + (c & 7)] =
                (short)f2bf(acc[rt][cj][r]);
          }
        }
      }
    __syncthreads();
    ushort_t* oe = msg3 + (long long)e * 6272;
    for (int gid = tid; gid < 784; gid += 256) {
      int row = gid >> 4, cc = gid & 15;
      bf16x8 v = *(const bf16x8*)&Ps[(row << 7) + ((cc ^ (row & 15)) << 3)];
      *(bf16x8*)&oe[(row << 7) + (cc << 3)] = v;
    }
  }
}

// ---------------------------------------------------------------------------
// Segment-sum via per-atom edge lists (vectorized bf16x8 gather)
// ---------------------------------------------------------------------------
__global__ __launch_bounds__(256) void k_zeroi(int* __restrict__ p, int n) {
  int id = blockIdx.x * 256 + threadIdx.x;
  if (id < n) p[id] = 0;
}

__global__ __launch_bounds__(256) void k_deg(
    const int* __restrict__ tgt, int* __restrict__ deg) {
  int e = blockIdx.x * 256 + threadIdx.x;
  if (e < EN) atomicAdd(&deg[tgt[e]], 1);
}

__global__ __launch_bounds__(1024) void k_prefix(
    const int* __restrict__ deg, int* __restrict__ base) {
  __shared__ int s[1024];
  int t = threadIdx.x;
  s[t] = (t < AN) ? deg[t] : 0;
  __syncthreads();
  for (int ofs = 1; ofs < 1024; ofs <<= 1) {
    int u = (t >= ofs) ? s[t - ofs] : 0;
    __syncthreads();
    s[t] += u;
    __syncthreads();
  }
  if (t < AN) base[t + 1] = s[t];
  if (t == 0) base[0] = 0;
}

__global__ __launch_bounds__(256) void k_fill(
    const int* __restrict__ tgt, const int* __restrict__ base,
    int* __restrict__ list) {
  const int a = blockIdx.x, t = threadIdx.x;
  const int lane = t & 63, w = t >> 6;
  __shared__ int wtot[4];
  __shared__ int runbase;
  if (t == 0) runbase = base[a];
  __syncthreads();
  for (int i0 = 0; i0 < EN; i0 += 256) {
    int e = i0 + t;
    bool m = (e < EN) && (tgt[e] == a);
    unsigned long long bal = __ballot(m);
    if (lane == 0) wtot[w] = __popcll(bal);
    __syncthreads();
    int wbase = 0;
    for (int j = 0; j < w; ++j) wbase += wtot[j];
    int tot = wtot[0] + wtot[1] + wtot[2] + wtot[3];
    if (m) {
      int off = __popcll(bal & ((1ull << lane) - 1ull));
      list[runbase + wbase + off] = e;
    }
    __syncthreads();
    if (t == 0) runbase += tot;
    __syncthreads();
  }
}

__global__ __launch_bounds__(256) void k_gather4(
    const ushort_t* __restrict__ msg3, const int* __restrict__ base,
    const int* __restrict__ list, float* __restrict__ xmsg,
    int e0, int ce, int accum)
{
  const int a = blockIdx.x, part = blockIdx.y, t = threadIdx.x;
  if (t >= 196) return;
  const int b0 = base[a], b1 = base[a + 1];
  const int co = part * 1568 + t * 8;
  float a8[8];
  #pragma unroll
  for (int u = 0; u < 8; ++u) a8[u] = 0.f;
  for (int i = b0; i < b1; ++i) {
    int e = list[i];
    if (e < e0 || e >= e0 + ce) continue;
    bf16x8 v = *(const bf16x8*)&msg3[(long long)(e - e0) * 6272 + co];
    #pragma unroll
    for (int u = 0; u < 8; ++u) a8[u] += bf2f((ushort_t)v[u]);
  }
  float* o = xmsg + (long long)a * 6272 + co;
  if (accum) {
    #pragma unroll
    for (int u = 0; u < 8; ++u) o[u] += a8[u];
  } else {
    float4 lo = make_float4(a8[0], a8[1], a8[2], a8[3]);
    float4 hi = make_float4(a8[4], a8[5], a8[6], a8[7]);
    *(float4*)o = lo;
    *(float4*)(o + 4) = hi;
  }
}

// ---------------------------------------------------------------------------
// Host orchestration
// ---------------------------------------------------------------------------
extern "C" void kernel_launch(void* const* d_in, const int* in_sizes, int n_in,
                              void* d_out, int out_size, void* d_ws, size_t ws_size,
                              hipStream_t stream) {
  const float* x         = (const float*)d_in[0];
  const float* edist     = (const float*)d_in[1];
  const float* wigner    = (const float*)d_in[2];
  const float* wiginv    = (const float*)d_in[3];
  const float* to_grid   = (const float*)d_in[4];
  const float* from_grid = (const float*)d_in[5];
  const float* w_dist1   = (const float*)d_in[6];
  const float* b_dist1   = (const float*)d_in[7];
  const float* src_emb   = (const float*)d_in[8];
  const float* tgt_emb   = (const float*)d_in[9];
  const float* w_edge1   = (const float*)d_in[10];
  const float* b_edge1   = (const float*)d_in[11];
  const float* ws1       = (const float*)d_in[12];
  const float* bs1       = (const float*)d_in[13];
  const float* ws2       = (const float*)d_in[14];
  const float* bs2       = (const float*)d_in[15];
  const float* ws3       = (const float*)d_in[16];
  const float* bs3       = (const float*)d_in[17];
  const int*   anum      = (const int*)d_in[18];
  const int*   eidx      = (const int*)d_in[19];
  const float* sw[10]; const float* tw[10];
  for (int i = 0; i < 10; ++i) {
    sw[i] = (const float*)d_in[20 + i];
    tw[i] = (const float*)d_in[30 + i];
  }
  float* outp = (float*)d_out;

  // ---- workspace ----
  char* wsb = (char*)d_ws;
  size_t off = 0;
  auto alloc = [&](long long nbytes) {
    char* p = wsb + off; off += (size_t)((nbytes + 63) & ~63LL); return p;
  };
  ushort_t* x_edge  = (ushort_t*)alloc((8000LL + 128) * 128 * 2);
  ushort_t* b2ab    = (ushort_t*)alloc(5505024LL * 2);
  ushort_t* bgcw    = (ushort_t*)alloc(851968LL * 2);
  float*    bgcb    = (float*)alloc(6656 * 4);
  ushort_t* b20b    = (ushort_t*)alloc(458752LL * 2);
  ushort_t* s1m0b   = (ushort_t*)alloc(458752LL * 2);
  ushort_t* s1mb    = (ushort_t*)alloc(2752512LL * 2);
  ushort_t* wd1b    = (ushort_t*)alloc(65536 * 2);
  ushort_t* we1b    = (ushort_t*)alloc(16384 * 2);
  ushort_t* ws1b    = (ushort_t*)alloc(32768 * 2);
  ushort_t* ws2b    = (ushort_t*)alloc(16384 * 2);
  ushort_t* ws3b    = (ushort_t*)alloc(16384 * 2);
  ushort_t* tgb     = (ushort_t*)alloc(4802 * 2);
  ushort_t* fgb     = (ushort_t*)alloc(4802 * 2);
  float*    xmsg    = (float*)alloc(5017600LL * 4);
  ushort_t* xmsgb   = (ushort_t*)alloc((5017600LL + 16384) * 2);
  ushort_t* xb      = (ushort_t*)alloc((5017600LL + 16384) * 2);
  ushort_t* xbT     = (ushort_t*)alloc(6553600LL * 2);
  ushort_t* basis   = (ushort_t*)alloc((8000LL + 128) * 512 * 2);
  float*    x_dist  = (float*)alloc(1024000LL * 4);
  ushort_t* x_distb = (ushort_t*)alloc((8000LL + 128) * 128 * 2);
  int*      deg     = (int*)alloc(800 * 4);
  int*      sbase   = (int*)alloc(801 * 4);
  int*      elist   = (int*)alloc(8000 * 4);
  const size_t fixedB = off;
  char* arena = wsb + off;

  static const int ces[6] = {8000, 4000, 2000, 1000, 500, 250};
  static const int cas[6] = {800, 800, 800, 400, 200, 100};
  int ce = 250, ca = 100;
  for (int i = 0; i < 6; ++i) {
    long long ne = (long long)ces[i] * 66048 + 64LL * 50688;
    long long na = (long long)cas[i] * 87808 + 64LL * 512;
    long long need = (long long)fixedB + (ne > na ? ne : na);
    if (need <= (long long)ws_size) { ce = ces[i]; ca = cas[i]; break; }
  }

  // edge-phase arena (padded A-sources)
  char* ap = arena;
  ushort_t* xrot_s = (ushort_t*)ap;  ap += (long long)(ce + 64) * 12544;
  ushort_t* xrot_t = (ushort_t*)ap;  ap += (long long)(ce + 64) * 12544;
  ushort_t* tb0    = (ushort_t*)ap;  ap += (long long)(ce + 64) * 1024;
  ushort_t* tbm    = (ushort_t*)ap;  ap += (long long)(ce + 64) * 24576;
  ushort_t* msgp   = (ushort_t*)ap;  ap += (long long)ce * 12544;
  ushort_t* gate   = (ushort_t*)ap;  // m0 gate only: ce x 512 bf16
  ushort_t* msg3   = (ushort_t*)arena;
  // atom-phase arena
  char* bp = arena;
  ushort_t* hb = (ushort_t*)bp;  bp += (long long)ca * 49 * 256;
  ushort_t* g1 = (ushort_t*)bp;  bp += ((long long)ca * 98 + 64) * 256;
  ushort_t* g2 = (ushort_t*)bp;  bp += ((long long)ca * 98 + 64) * 256;
  ushort_t* g3 = (ushort_t*)bp;

  long long ofs2[7][2], s1ofs[7][2];
  { long long cur = 0, cur1 = 0;
    for (int m = 1; m <= 6; ++m) {
      int k = (7 - m) * 128;
      ofs2[m][0] = cur; cur += (long long)k * 1024;
      ofs2[m][1] = cur; cur += (long long)k * 1024;
      s1ofs[m][0] = cur1; cur1 += 512LL * k;
      s1ofs[m][1] = cur1; cur1 += 512LL * k;
    } }

  auto D0 = []() { GemmP p; memset(&p, 0, sizeof(p)); p.asplit = 1 << 30; return p; };
  auto finalize = [&](Grouped& G) {
    int base = 0;
    for (int i = 0; i < G.nd; ++i) {
      GemmP& p = G.d[i];
      p.ngx = (p.M + 127) >> 7;
      int ngy = (p.N + 127) >> 7;
      p.wg_base = base;
      base += p.ngx * ngy;
    }
    G.nwg = base;
    gemm_g<<<base, 256, 0, stream>>>(G);
  };
  auto run1 = [&](GemmP p) { Grouped G; G.d[0] = p; G.nd = 1; finalize(G); };
  auto rungrid = [&](const float* A, int M, int K, int permA,
                     const ushort_t* B, int b_ib, void* C, int c_ib,
                     const float* bias, int act, int c_bf16, int nb) {
    GridP p;
    p.A = A; p.B = B; p.C = C; p.bias = bias;
    p.b_ib = b_ib; p.c_ib = c_ib;
    p.M = M; p.K = K; p.permA = permA; p.act = act; p.c_bf16 = c_bf16;
    gridmm<<<nb, 256, 0, stream>>>(p);
  };

  // 0) builds
  k_build_b2b<<<(5505024 + 255) / 256, 256, 0, stream>>>(sw[7], sw[9], tw[7], tw[9], b2ab);
  k_build_bgcat<<<(858624 + 255) / 256, 256, 0, stream>>>(
      sw[0], tw[0], sw[4], tw[4], sw[1], tw[1], sw[5], tw[5], bgcw, bgcb);
  k_build_b20b<<<(458752 + 255) / 256, 256, 0, stream>>>(sw[3], tw[3], b20b);
  k_build_s1m<<<(2752512 + 255) / 256, 256, 0, stream>>>(sw[6], sw[8], tw[6], tw[8], s1mb);
  { // merged conversions
    CvtM P;
    const float* ss[9] = { sw[2], tw[2], w_dist1, w_edge1, ws1, ws2, ws3, from_grid, x };
    ushort_t* dd[9] = { s1m0b, s1m0b + 229376, wd1b, we1b, ws1b, ws2b, ws3b, fgb, xb };
    long long nn[9] = { 229376, 229376, 65536, 16384, 32768, 16384, 16384, 4802, 5017600 };
    long long cur = 0;
    for (int i = 0; i < 9; ++i) { P.s[i] = ss[i]; P.d[i] = dd[i]; P.start[i] = cur; cur += nn[i]; }
    P.start[9] = cur;
    k_cvt_multi<<<(int)((cur + 255) / 256), 256, 0, stream>>>(P);
  }
  k_build_tg<<<(4802 + 255) / 256, 256, 0, stream>>>(to_grid, tgb);
  k_xT<<<AN, 256, 0, stream>>>(x, xbT);

  // scatter lists
  k_zeroi<<<4, 256, 0, stream>>>(deg, 800);
  k_deg<<<(EN + 255) / 256, 256, 0, stream>>>(eidx + EN, deg);
  k_prefix<<<1, 1024, 0, stream>>>(deg, sbase);
  k_fill<<<AN, 256, 0, stream>>>(eidx + EN, sbase, elist);

  // 1) edge features
  k_basis<<<(EN * 512 + 255) / 256, 256, 0, stream>>>(edist, basis);
  { GemmP p = D0();
    p.A = basis; p.a_se = 512; p.B = wd1b; p.ldb = 512; p.bias = b_dist1;
    p.C = x_dist; p.c_se = 128; p.M = EN; p.N = 128; p.K = 512;
    run1(p); }
  k_emb<<<(EN * 128 + 255) / 256, 256, 0, stream>>>(src_emb, tgt_emb, anum, eidx,
                                                    x_dist, x_distb);
  { GemmP p = D0();
    p.A = x_distb; p.a_se = 128; p.B = we1b; p.ldb = 128; p.bias = b_edge1;
    p.act = 1; p.C = x_edge; p.c_se = 128; p.c_bf16 = 1;
    p.M = EN; p.N = 128; p.K = 128;
    run1(p); }

  static const int offq[7] = {0, 7, 19, 29, 37, 43, 47};

  // 2) edge chunks
  for (int e0 = 0; e0 < EN; e0 += ce) {
    const int c = ce;
    k_rot2<<<c, 256, 0, stream>>>(wigner + (long long)e0 * 2401, xbT,
                                  eidx + e0, eidx + EN + e0, xrot_s, xrot_t);
    // m0 gates only (N=512)
    { GemmP p = D0();
      p.A = x_edge + (long long)e0 * 128; p.a_se = 128;
      p.B = bgcw; p.ldb = 128; p.bias = bgcb; p.act = 1;
      p.C = gate; p.c_se = 512; p.c_bf16 = 1;
      p.M = c; p.N = 512; p.K = 128;
      run1(p); }
    // stage 1 grouped (m>=1 with fused gate)
    { Grouped G; G.nd = 14;
      for (int s = 0; s < 2; ++s) {
        GemmP p = D0();
        p.A = s ? xrot_t : xrot_s; p.a_se = 6272;
        p.B = s1m0b + (long long)s * 229376; p.ldb = 896;
        p.gate = gate; p.gate_ofs = s * 256; p.gse = 512;
        p.C = tb0; p.c_se = 512; p.c_ofs = s * 256; p.c_bf16 = 1;
        p.M = c; p.N = 256; p.K = 896;
        G.d[s] = p;
      }
      int di = 2;
      for (int m = 1; m <= 6; ++m) {
        const int k = (7 - m) * 128, off2 = offq[m];
        for (int s = 0; s < 2; ++s) {
          GemmP p = D0();
          p.A = (s ? xrot_t : xrot_s) + off2 * 128;
          p.a_se = 6272; p.a_si = k; p.pair = 1;
          p.B = s1mb + s1ofs[m][s]; p.ldb = k;
          p.gxe = x_edge + (long long)e0 * 128;
          p.gw = bgcw; p.gb = bgcb;
          p.gate_ofs = 512 + (m - 1) * 1024 + s * 512;
          p.C = tbm; p.c_se = 12288; p.c_si = 1024;
          p.c_ofs = (m - 1) * 2048 + s * 512;
          p.ihalf = 1; p.c_bf16 = 1;
          p.M = 2 * c; p.N = 512; p.K = k;
          G.d[di++] = p;
        }
      }
      finalize(G); }
    // stage 2 grouped
    { Grouped G; G.nd = 13;
      { GemmP p = D0();
        p.A = tb0; p.a_se = 512;
        p.B = b20b; p.ldb = 512;
        p.C = msgp; p.c_se = 6272; p.c_bf16 = 1;
        p.M = c; p.N = 896; p.K = 512;
        G.d[0] = p; }
      int di = 1;
      for (int m = 1; m <= 6; ++m) {
        const int n = 7 - m, k = n * 128, off2 = offq[m];
        for (int pp = 0; pp < 2; ++pp) {
          GemmP p = D0();
          p.A = tbm + (m - 1) * 2048 + pp * 1024; p.a_se = 12288;
          p.B = b2ab + ofs2[m][pp]; p.ldb = 1024;
          p.C = msgp; p.c_se = 6272; p.c_ofs = (off2 + (pp ? n : 0)) * 128; p.c_bf16 = 1;
          p.M = c; p.N = k; p.K = 1024;
          G.d[di++] = p;
        }
      }
      finalize(G); }
    // fused grid pipeline + gather
    k_grid<<<c, 256, 0, stream>>>(tgb, fgb, wiginv + (long long)e0 * 2401, msgp, msg3);
    k_gather4<<<dim3(AN, 4), 256, 0, stream>>>(msg3, sbase, elist, xmsg, e0, c, e0 > 0);
  }

  // xmsg -> bf16 for atom GEMM
  k_cvt<<<(5017600 + 255) / 256, 256, 0, stream>>>(xmsg, xmsgb, 5017600);

  // 3) atom phase
  for (int a0 = 0; a0 < AN; a0 += ca) {
    { GemmP p = D0();
      p.A = xb + (long long)a0 * 6272; p.A2 = xmsgb + (long long)a0 * 6272;
      p.a_se = 128; p.asplit = 128;
      p.B = ws1b; p.ldb = 256;
      p.C = hb; p.c_se = 128; p.c_bf16 = 1;
      p.M = ca * 49; p.N = 128; p.K = 256;
      run1(p); }
    rungrid(to_grid, 98, 49, 0, hb, 6272, g1, 12544, bs1, 1, 1, ca);
    { GemmP p = D0();
      p.A = g1; p.a_se = 128;
      p.B = ws2b; p.ldb = 128; p.bias = bs2; p.act = 1;
      p.C = g2; p.c_se = 128; p.c_bf16 = 1;
      p.M = ca * 98; p.N = 128; p.K = 128;
      run1(p); }
    { GemmP p = D0();
      p.A = g2; p.a_se = 128;
      p.B = ws3b; p.ldb = 128; p.bias = bs3;
      p.C = g3; p.c_se = 128; p.c_bf16 = 1;
      p.M = ca * 98; p.N = 128; p.K = 128;
      run1(p); }
    rungrid(from_grid, 49, 98, 0, g3, 12544, outp + (long long)a0 * 6272, 6272,
            nullptr, 0, 0, ca);
  }
}

// Round 10
// 1628.639 us; speedup vs baseline: 1.4364x; 1.4364x over previous
//
#include <hip/hip_runtime.h>
#include <string.h>

#define EN 8000
#define AN 800

typedef __attribute__((ext_vector_type(8))) short bf16x8;
typedef __attribute__((ext_vector_type(4))) float f32x4;
typedef unsigned short ushort_t;
typedef unsigned int uint32;

__constant__ int c_perm[49] = {
  0,2,6,12,20,30,42,
  1,5,11,19,29,41,
  3,7,13,21,31,43,
  4,10,18,28,40,
  8,14,22,32,44,
  9,17,27,39,
  15,23,33,45,
  16,26,38,
  24,34,46,
  25,37,
  35,47,
  36,
  48
};

__device__ __forceinline__ float siluf(float x) { return x / (1.0f + __expf(-x)); }
__device__ __forceinline__ ushort_t f2bf(float f) {
  uint32 u = __float_as_uint(f);
  u += 0x7fff + ((u >> 16) & 1);
  return (ushort_t)(u >> 16);
}
__device__ __forceinline__ float bf2f(ushort_t h) {
  return __uint_as_float(((uint32)h) << 16);
}
__device__ __forceinline__ void gld16(const void* g, void* l) {
  __builtin_amdgcn_global_load_lds(
      (const __attribute__((address_space(1))) void*)g,
      (__attribute__((address_space(3))) void*)l, 16, 0, 0);
}

// ---------------------------------------------------------------------------
// Weight builders (bf16 outputs)
// ---------------------------------------------------------------------------
__global__ __launch_bounds__(256) void k_build_b2b(
    const float* __restrict__ sw2r, const float* __restrict__ sw2i,
    const float* __restrict__ tw2r, const float* __restrict__ tw2i,
    ushort_t* __restrict__ dst)
{
  long long id = (long long)blockIdx.x * 256 + threadIdx.x;
  if (id >= 5505024LL) return;
  long long base = 0; int m = 1, k = 768;
  for (; m <= 6; ++m) {
    k = (7 - m) * 128;
    long long sz = 2LL * k * 1024;
    if (id < base + sz) break;
    base += sz;
  }
  long long rem = id - base;
  int p = (int)(rem / ((long long)k * 1024));
  int cj = (int)(rem - (long long)p * k * 1024);
  int c = cj >> 10, j = cj & 1023;
  int q = j >> 8, jj = j & 255;
  const float sgn = (q & 1) ? (p ? 1.f : -1.f) : 1.f;
  const float* src = (q < 2) ? (q == 0 ? sw2r : sw2i) : (q == 2 ? tw2r : tw2i);
  dst[id] = f2bf(sgn * src[(long long)(m - 1) * 196608 + c * 256 + jj]);
}

__global__ __launch_bounds__(256) void k_build_bgcat(
    const float* __restrict__ sw0, const float* __restrict__ tw0,
    const float* __restrict__ sw4, const float* __restrict__ tw4,
    const float* __restrict__ sb0, const float* __restrict__ tb0b,
    const float* __restrict__ sbd, const float* __restrict__ tbd,
    ushort_t* __restrict__ w, float* __restrict__ b)
{
  int id = blockIdx.x * 256 + threadIdx.x;
  if (id < 851968) {
    int r = id >> 7, c = id & 127;
    float v;
    if (r < 256) v = sw0[r * 128 + c];
    else if (r < 512) v = tw0[(r - 256) * 128 + c];
    else {
      int rr = r - 512, m = rr >> 10, q = rr & 1023;
      v = (q < 512) ? sw4[m * 65536 + q * 128 + c] : tw4[m * 65536 + (q - 512) * 128 + c];
    }
    w[id] = f2bf(v);
    return;
  }
  id -= 851968;
  if (id < 6656) {
    float v;
    if (id < 256) v = sb0[id];
    else if (id < 512) v = tb0b[id - 256];
    else {
      int rr = id - 512, m = rr >> 10, q = rr & 1023;
      v = (q < 512) ? sbd[m * 512 + q] : tbd[m * 512 + (q - 512)];
    }
    b[id] = v;
  }
}

__global__ __launch_bounds__(256) void k_build_b20b(
    const float* __restrict__ sw3, const float* __restrict__ tw3,
    ushort_t* __restrict__ b20)
{
  int id = blockIdx.x * 256 + threadIdx.x;
  if (id >= 458752) return;
  int cc = id >> 9, j = id & 511;
  b20[id] = f2bf((j < 256) ? sw3[cc * 256 + j] : tw3[cc * 256 + (j - 256)]);
}

__global__ __launch_bounds__(256) void k_build_s1m(
    const float* __restrict__ sw6, const float* __restrict__ sw8,
    const float* __restrict__ tw6, const float* __restrict__ tw8,
    ushort_t* __restrict__ dst)
{
  long long id = (long long)blockIdx.x * 256 + threadIdx.x;
  if (id >= 2752512LL) return;
  long long base = 0; int m = 1, k = 768;
  for (; m <= 6; ++m) {
    k = (7 - m) * 128;
    long long sz = 1024LL * k;
    if (id < base + sz) break;
    base += sz;
  }
  long long rem = id - base;
  int s = (int)(rem / (512LL * k));
  int rr = (int)(rem - (long long)s * 512 * k);
  int r = rr / k, c = rr - r * k;
  const float* src = (r < 256) ? (s ? tw6 : sw6) : (s ? tw8 : sw8);
  int r0 = (r < 256) ? r : r - 256;
  dst[id] = f2bf(src[(long long)(m - 1) * 196608 + r0 * 768 + c]);
}

// merged f32->bf16 conversions (up to 9 segments)
struct CvtM {
  const float* s[9];
  ushort_t* d[9];
  long long start[10];
};
__global__ __launch_bounds__(256) void k_cvt_multi(CvtM P) {
  long long id = (long long)blockIdx.x * 256 + threadIdx.x;
  if (id >= P.start[9]) return;
  int seg = 0;
  #pragma unroll
  for (int i = 1; i < 9; ++i) if (id >= P.start[i]) seg = i;
  long long o = id - P.start[seg];
  P.d[seg][o] = f2bf(P.s[seg][o]);
}

__global__ __launch_bounds__(256) void k_cvt(
    const float* __restrict__ src, ushort_t* __restrict__ dst, int n)
{
  int id = blockIdx.x * 256 + threadIdx.x;
  if (id < n) dst[id] = f2bf(src[id]);
}

__global__ __launch_bounds__(256) void k_build_tg(
    const float* __restrict__ tg, ushort_t* __restrict__ dst)
{
  int id = blockIdx.x * 256 + threadIdx.x;
  if (id >= 98 * 49) return;
  int r = id / 49, s = id - r * 49;
  dst[id] = f2bf(tg[r * 49 + c_perm[s]]);
}

// transpose x (f32 [49][128]) -> xbT (bf16 [128][64], j-padded)
__global__ __launch_bounds__(256) void k_xT(
    const float* __restrict__ x, ushort_t* __restrict__ xbT)
{
  __shared__ __align__(16) float xs[49 * 128];
  const int a = blockIdx.x, t = threadIdx.x;
  const float4* src = (const float4*)(x + (long long)a * 6272);
  float4* d = (float4*)xs;
  for (int i = t; i < 1568; i += 256) d[i] = src[i];
  __syncthreads();
  ushort_t* o = xbT + (long long)a * 8192;
  int c = t >> 1;
  int jg = (t & 1) << 2;
  #pragma unroll
  for (int u = 0; u < 4; ++u) {
    int g = jg + u;
    bf16x8 v = (bf16x8)0;
    #pragma unroll
    for (int j = 0; j < 8; ++j) {
      int jj = (g << 3) + j;
      if (jj < 49) v[j] = (short)f2bf(xs[jj * 128 + c]);
    }
    *(bf16x8*)&o[(c << 6) + (g << 3)] = v;
  }
}

// ---------------------------------------------------------------------------
// Edge features
// ---------------------------------------------------------------------------
__global__ __launch_bounds__(256) void k_basis(
    const float* __restrict__ dist, ushort_t* __restrict__ basis)
{
  int id = blockIdx.x * 256 + threadIdx.x;
  if (id >= EN * 512) return;
  int e = id >> 9, g = id & 511;
  const float step = 8.0f / 511.0f;
  const float coeff = -2040.0078125f;
  float df = dist[e] - (float)g * step;
  basis[id] = f2bf(expf(coeff * df * df));
}

__global__ __launch_bounds__(256) void k_emb(
    const float* __restrict__ src_emb, const float* __restrict__ tgt_emb,
    const int* __restrict__ anum, const int* __restrict__ eidx,
    const float* __restrict__ xd, ushort_t* __restrict__ out)
{
  int id = blockIdx.x * 256 + threadIdx.x;
  if (id >= EN * 128) return;
  int e = id >> 7, c = id & 127;
  int a0 = anum[eidx[e]], a1 = anum[eidx[EN + e]];
  out[id] = f2bf(siluf(src_emb[a0 * 128 + c] + tgt_emb[a1 * 128 + c] + xd[id]));
}

// ---------------------------------------------------------------------------
// MFMA Wigner rotation with coalesced (repacked) output
// ---------------------------------------------------------------------------
__global__ __launch_bounds__(256) void k_rot2(
    const float* __restrict__ wig, const ushort_t* __restrict__ xbT,
    const int* __restrict__ srcl, const int* __restrict__ tgtl,
    ushort_t* __restrict__ osrc, ushort_t* __restrict__ otgt)
{
  __shared__ short Ws[4096];
  __shared__ short Xs[8192];
  __shared__ short Xt[8192];
  const int e = blockIdx.x, tid = threadIdx.x;
  const int lane = tid & 63, wave = tid >> 6;
  const float* wge = wig + (long long)e * 2401;
  #pragma unroll
  for (int t = 0; t < 2; ++t) {
    int ci = (t << 8) + tid;
    int row = ci >> 3, g = ci & 7;
    bf16x8 v = (bf16x8)0;
    if (row < 49) {
      const float* wr = wge + c_perm[row] * 49;
      #pragma unroll
      for (int j = 0; j < 8; ++j) {
        int col = (g << 3) + j;
        if (col < 49) v[j] = (short)f2bf(wr[col]);
      }
    }
    *(bf16x8*)&Ws[(row << 6) + ((g ^ (row & 7)) << 3)] = v;
  }
  const int as = srcl[e], at = tgtl[e];
  const ushort_t* xsg = xbT + (long long)as * 8192;
  const ushort_t* xtg = xbT + (long long)at * 8192;
  #pragma unroll
  for (int t = 0; t < 4; ++t) {
    int ci = (t << 8) + tid;
    int row = ci >> 3, g = ci & 7;
    int ofs = (row << 6) + ((g ^ (row & 7)) << 3);
    *(bf16x8*)&Xs[ofs] = *(const bf16x8*)&xsg[ci << 3];
    *(bf16x8*)&Xt[ofs] = *(const bf16x8*)&xtg[ci << 3];
  }
  __syncthreads();
  const short* Xb = (wave >> 1) ? Xt : Xs;
  const int ch = (wave & 1) << 6;
  const int fr = lane & 15, g = lane >> 4;
  f32x4 acc[4][4];
  #pragma unroll
  for (int i = 0; i < 4; ++i)
    #pragma unroll
    for (int j = 0; j < 4; ++j) acc[i][j] = (f32x4){0.f, 0.f, 0.f, 0.f};
  #pragma unroll
  for (int ks = 0; ks < 2; ++ks) {
    bf16x8 af[4], bfv[4];
    int lc = (ks << 2) + g;
    #pragma unroll
    for (int i = 0; i < 4; ++i) {
      int ra = (i << 4) + fr;
      af[i] = *(const bf16x8*)&Ws[(ra << 6) + ((lc ^ (ra & 7)) << 3)];
      int rb = ch + (i << 4) + fr;
      bfv[i] = *(const bf16x8*)&Xb[(rb << 6) + ((lc ^ (rb & 7)) << 3)];
    }
    #pragma unroll
    for (int i = 0; i < 4; ++i)
      #pragma unroll
      for (int j = 0; j < 4; ++j)
        acc[i][j] = __builtin_amdgcn_mfma_f32_16x16x32_bf16(af[i], bfv[j], acc[i][j], 0, 0, 0);
  }
  const int crl = (lane >> 4) << 2, ccl = lane & 15;
  __syncthreads();
  short* Ob = (wave >> 1) ? Xt : Xs;
  #pragma unroll
  for (int i = 0; i < 4; ++i)
    #pragma unroll
    for (int r = 0; r < 4; ++r) {
      int q = (i << 4) + crl + r;
      if (q < 49) {
        #pragma unroll
        for (int j = 0; j < 4; ++j) {
          int col = ch + (j << 4) + ccl;
          Ob[(q << 7) + (((col >> 3) ^ (q & 15)) << 3) + (col & 7)] =
              (short)f2bf(acc[i][j][r]);
        }
      }
    }
  __syncthreads();
  for (int gid = tid; gid < 1568; gid += 256) {
    int half = gid >= 784;
    int c784 = half ? gid - 784 : gid;
    int row = c784 >> 4, cc = c784 & 15;
    const short* Sb = half ? Xt : Xs;
    bf16x8 v = *(const bf16x8*)&Sb[(row << 7) + ((cc ^ (row & 15)) << 3)];
    ushort_t* dst = (half ? otgt : osrc) + (long long)e * 6272 + (row << 7) + (cc << 3);
    *(bf16x8*)dst = v;
  }
}

// ---------------------------------------------------------------------------
// Grouped MFMA GEMM (round-8 structure: 84 VGPR / 32KB LDS, occupancy-safe).
// bf16, global_load_lds + swizzle, dbuf + counted vmcnt, XCD swizzle,
// LDS-repacked coalesced epilogue (16B C-stores, 16B gate loads).
// NOTE: epilogue extensions must stay under ~96 VGPR / 32KB LDS — round 9's
// fused-gate variant (172 VGPR, 48KB) collapsed occupancy to 8.5% (-43%).
// ---------------------------------------------------------------------------
struct GemmP {
  const ushort_t* A; const ushort_t* A2; const ushort_t* B;
  const float* bias; const ushort_t* gate; void* C;
  int a_se, a_si, pair, asplit;
  int ldb;
  int gate_ofs, gse;
  int c_se, c_si, c_ofs;
  int ihalf, act, c_bf16;
  int M, N, K;
  int ngx, wg_base;
};
struct Grouped { GemmP d[14]; int nd; int nwg; };

__global__ __launch_bounds__(256) void gemm_g(Grouped G) {
  __shared__ short SH[16384];       // staging (2x dbuf A|B) and epilogue repack
  short* As = SH;
  short* Bs = SH + 8192;
  int bid;
  { // bijective XCD chunk swizzle
    int n = G.nwg, orig = blockIdx.x;
    int q = n >> 3, r = n & 7;
    int xcd = orig & 7, pos = orig >> 3;
    bid = (xcd < r ? xcd * (q + 1) : r * (q + 1) + (xcd - r) * q) + pos;
  }
  int di = G.nd - 1;
  for (int i = 1; i < G.nd; ++i) if (bid < G.d[i].wg_base) { di = i - 1; break; }
  const GemmP p = G.d[di];
  const int local = bid - p.wg_base;
  const int bx = local % p.ngx, by = local / p.ngx;
  const int m0 = bx << 7, n0 = by << 7;

  const int tid = threadIdx.x;
  const int lane = tid & 63, wave = tid >> 6;
  const int gl = ((lane & 3) ^ ((lane >> 3) & 3)) << 3;
  const int grow = (wave << 4) + (lane >> 2);
  const int fr = lane & 15, fkg = lane >> 4;
  const int sxor = (fr >> 1) & 3;
  const int wm = (wave >> 1) << 6, wn = (wave & 1) << 6;

  f32x4 acc[4][4];
  #pragma unroll
  for (int i = 0; i < 4; ++i)
    #pragma unroll
    for (int j = 0; j < 4; ++j) acc[i][j] = (f32x4){0.f, 0.f, 0.f, 0.f};

  long long abase;
  {
    int r0 = m0 + grow;
    abase = p.pair
        ? (long long)(r0 >> 1) * p.a_se + (long long)(r0 & 1) * p.a_si
        : (long long)r0 * p.a_se;
  }
  long long abase2;
  {
    int r1 = m0 + 64 + grow;
    abase2 = p.pair
        ? (long long)(r1 >> 1) * p.a_se + (long long)(r1 & 1) * p.a_si
        : (long long)r1 * p.a_se;
  }
  const long long bbase  = (long long)(n0 + grow) * p.ldb;
  const long long bbase2 = (long long)(n0 + 64 + grow) * p.ldb;

  const int nt = p.K >> 5;

  auto STAGE = [&](int buf, int k0) {
    const ushort_t* Ap = p.A;
    int kk = k0;
    if (p.A2 && k0 >= p.asplit) { Ap = p.A2; kk = k0 - p.asplit; }
    const int lofs = (buf << 12) + (wave << 9);
    gld16(Ap + abase + kk + gl,   &As[lofs]);
    gld16(p.B + bbase + k0 + gl,  &Bs[lofs]);
    gld16(Ap + abase2 + kk + gl,  &As[lofs + 2048]);
    gld16(p.B + bbase2 + k0 + gl, &Bs[lofs + 2048]);
  };

  STAGE(0, 0);
  int cur = 0;
  for (int t = 0; t < nt; ++t) {
    if (t + 1 < nt) {
      STAGE(cur ^ 1, (t + 1) << 5);
      asm volatile("s_waitcnt vmcnt(4)" ::: "memory");
    } else {
      asm volatile("s_waitcnt vmcnt(0)" ::: "memory");
    }
    __builtin_amdgcn_sched_barrier(0);
    __builtin_amdgcn_s_barrier();
    {
      const int bofs = cur << 12;
      bf16x8 af[4], bfv[4];
      #pragma unroll
      for (int i = 0; i < 4; ++i) {
        int ra = wm + (i << 4) + fr;
        int rb = wn + (i << 4) + fr;
        af[i]  = *(const bf16x8*)&As[bofs + (ra << 5) + ((fkg ^ sxor) << 3)];
        bfv[i] = *(const bf16x8*)&Bs[bofs + (rb << 5) + ((fkg ^ sxor) << 3)];
      }
      #pragma unroll
      for (int i = 0; i < 4; ++i)
        #pragma unroll
        for (int j = 0; j < 4; ++j)
          acc[i][j] = __builtin_amdgcn_mfma_f32_16x16x32_bf16(af[i], bfv[j], acc[i][j], 0, 0, 0);
    }
    __builtin_amdgcn_s_barrier();
    cur ^= 1;
  }

  const int crl = (lane >> 4) << 2, ccl = lane & 15;
  if (p.c_bf16) {
    // 1) acc (+bias/act) -> SH[128][128] bf16 swizzled
    #pragma unroll
    for (int mi = 0; mi < 4; ++mi)
      #pragma unroll
      for (int r = 0; r < 4; ++r) {
        int lrow = wm + mi * 16 + crl + r;
        #pragma unroll
        for (int ni = 0; ni < 4; ++ni) {
          int lcol = wn + ni * 16 + ccl;
          float v = acc[mi][ni][r];
          int gc = n0 + lcol;
          if (p.bias) v += p.bias[gc];
          if (p.act)  v = siluf(v);
          SH[(lrow << 7) + (((lcol >> 3) ^ (lrow & 15)) << 3) + (lcol & 7)] =
              (short)f2bf(v);
        }
      }
    __syncthreads();
    // 2) coalesced output: 1 row, 64 cols per thread (8 x 16B)
    const int lr = tid >> 1, chalf = (tid & 1) << 6;
    int gr = m0 + lr;
    if (gr < p.M) {
      long long e; int ii;
      if (p.pair) { e = gr >> 1; ii = gr & 1; } else { e = gr; ii = 0; }
      const ushort_t* grw = p.gate ? p.gate + e * p.gse + p.gate_ofs : nullptr;
      #pragma unroll
      for (int j = 0; j < 8; ++j) {
        int lcol = chalf + (j << 3);
        bf16x8 v = *(const bf16x8*)&SH[(lr << 7) + (((lcol >> 3) ^ (lr & 15)) << 3)];
        int gc = n0 + lcol;
        if (grw) {
          bf16x8 g8 = *(const bf16x8*)&grw[gc];
          #pragma unroll
          for (int q2 = 0; q2 < 8; ++q2)
            v[q2] = (short)f2bf(bf2f((ushort_t)v[q2]) * bf2f((ushort_t)g8[q2]));
        }
        int par = (p.ihalf && gc >= 256) ? (1 - ii) : ii;
        long long co = e * (long long)p.c_se + (long long)par * p.c_si + p.c_ofs + gc;
        *(bf16x8*)&((ushort_t*)p.C)[co] = v;
      }
    }
  } else {
    // f32-C scalar path (x_dist only)
    #pragma unroll
    for (int mi = 0; mi < 4; ++mi) {
      #pragma unroll
      for (int r = 0; r < 4; ++r) {
        int gr = m0 + wm + mi * 16 + crl + r;
        if (gr >= p.M) continue;
        long long e = gr;
        float* crow = (float*)p.C + e * (long long)p.c_se + p.c_ofs;
        #pragma unroll
        for (int ni = 0; ni < 4; ++ni) {
          int gc = n0 + wn + ni * 16 + ccl;
          if (gc >= p.N) continue;
          float v = acc[mi][ni][r];
          if (p.bias) v += p.bias[gc];
          if (p.act)  v = siluf(v);
          crow[gc] = v;
        }
      }
    }
  }
}

// ---------------------------------------------------------------------------
// gridmm (atom phase)
// ---------------------------------------------------------------------------
struct GridP {
  const float* A; const ushort_t* B; void* C; const float* bias;
  int b_ib, c_ib;
  int M, K, permA, act, c_bf16;
};

#define LDW 40

__global__ __launch_bounds__(256) void gridmm(GridP p) {
  __shared__ short As[128 * LDW];
  __shared__ short Bs[128 * LDW];
  const int e = blockIdx.x;
  const int tid = threadIdx.x;
  const int srow = tid >> 1, sk = (tid & 1) << 4;
  const int lane = tid & 63, wave = tid >> 6;
  const int wm = (wave >> 1) << 6, wn = (wave & 1) << 6;
  const int fr = lane & 15, fk = (lane >> 4) << 3;

  f32x4 acc[4][4];
  #pragma unroll
  for (int i = 0; i < 4; ++i)
    #pragma unroll
    for (int j = 0; j < 4; ++j) acc[i][j] = (f32x4){0.f, 0.f, 0.f, 0.f};

  const ushort_t* bp0 = p.B + (long long)e * p.b_ib;

  for (int k0 = 0; k0 < p.K; k0 += 32) {
    {
      bf16x8 lo = (bf16x8)0, hi = (bf16x8)0;
      if (srow < p.M) {
        const float* ar = p.A + srow * p.K;
        #pragma unroll
        for (int j = 0; j < 8; ++j) {
          int col = k0 + sk + j;
          float v = 0.f;
          if (col < p.K) v = ar[p.permA ? c_perm[col] : col];
          lo[j] = (short)f2bf(v);
        }
        #pragma unroll
        for (int j = 0; j < 8; ++j) {
          int col = k0 + sk + 8 + j;
          float v = 0.f;
          if (col < p.K) v = ar[p.permA ? c_perm[col] : col];
          hi[j] = (short)f2bf(v);
        }
      }
      *(bf16x8*)&As[srow * LDW + sk] = lo;
      *(bf16x8*)&As[srow * LDW + sk + 8] = hi;
    }
    {
      const int c = tid & 127, kq = tid >> 7;
      #pragma unroll
      for (int i = 0; i < 8; ++i) {
        int kk = kq * 16 + i * 2;
        int k1 = k0 + kk, k2 = k1 + 1;
        uint32 v0 = (k1 < p.K) ? (uint32)bp0[(long long)k1 * 128 + c] : 0u;
        uint32 v1 = (k2 < p.K) ? (uint32)bp0[(long long)k2 * 128 + c] : 0u;
        *(uint32*)&Bs[c * LDW + kk] = v0 | (v1 << 16);
      }
    }
    __syncthreads();
    bf16x8 af[4], bfv[4];
    #pragma unroll
    for (int i = 0; i < 4; ++i) {
      af[i]  = *(const bf16x8*)(&As[(wm + i * 16 + fr) * LDW + fk]);
      bfv[i] = *(const bf16x8*)(&Bs[(wn + i * 16 + fr) * LDW + fk]);
    }
    #pragma unroll
    for (int i = 0; i < 4; ++i)
      #pragma unroll
      for (int j = 0; j < 4; ++j)
        acc[i][j] = __builtin_amdgcn_mfma_f32_16x16x32_bf16(af[i], bfv[j], acc[i][j], 0, 0, 0);
    __syncthreads();
  }

  const int crl = (lane >> 4) << 2, ccl = lane & 15;
  #pragma unroll
  for (int mi = 0; mi < 4; ++mi) {
    #pragma unroll
    for (int r = 0; r < 4; ++r) {
      int gr = wm + mi * 16 + crl + r;
      if (gr >= p.M) continue;
      #pragma unroll
      for (int ni = 0; ni < 4; ++ni) {
        int c = wn + ni * 16 + ccl;
        float v = acc[mi][ni][r];
        if (p.bias) v += p.bias[c];
        if (p.act)  v = siluf(v);
        long long co = (long long)e * p.c_ib + gr * 128 + c;
        if (p.c_bf16) ((ushort_t*)p.C)[co] = f2bf(v);
        else          ((float*)p.C)[co] = v;
      }
    }
  }
}

// ---------------------------------------------------------------------------
// Fused grid pipeline per edge: msg3 = WI @ (FG @ silu(TGp @ msgp))
// ---------------------------------------------------------------------------
#define SWZ8(cg, r) (((cg) ^ ((r) & 7)) & 7)
#define SWZ16(cg, r) (((cg) & 8) | (((cg) ^ (r)) & 7))

__global__ __launch_bounds__(256, 2) void k_grid(
    const ushort_t* __restrict__ tgb, const ushort_t* __restrict__ fgb,
    const float* __restrict__ wigv, const ushort_t* __restrict__ msgp,
    ushort_t* __restrict__ msg3)
{
  __shared__ short Abuf[8192];
  __shared__ short Bsh[8192];
  __shared__ short Ps[16384];
  const int e = blockIdx.x, tid = threadIdx.x;
  const int lane = tid & 63, wv = tid >> 6;
  const int fr = lane & 15, fk = (lane >> 4) << 3;
  const int crl = (lane >> 4) << 2, ccl = lane & 15;
  const ushort_t* me = msgp + (long long)e * 6272;

  for (int gid = tid; gid < 896; gid += 256) {
    int r = gid >> 3, cg = gid & 7;
    bf16x8 v = (bf16x8)0;
    if (r < 98) {
      #pragma unroll
      for (int j = 0; j < 8; ++j) {
        int col = (cg << 3) + j;
        if (col < 49) v[j] = (short)tgb[r * 49 + col];
      }
    }
    *(bf16x8*)&Abuf[(r << 6) + (SWZ8(cg, r) << 3)] = v;
  }
  for (int gid = tid; gid < 1024; gid += 256) {
    int kg = gid >> 7, c = gid & 127;
    bf16x8 v = (bf16x8)0;
    #pragma unroll
    for (int j = 0; j < 8; ++j) {
      int k = (kg << 3) + j;
      if (k < 49) v[j] = (short)me[k * 128 + c];
    }
    *(bf16x8*)&Bsh[(c << 6) + (SWZ8(kg, c) << 3)] = v;
  }
  {
    int c = tid >> 1, gg = 14 + (tid & 1);
    *(bf16x8*)&Ps[(c << 7) + (SWZ16(gg, c) << 3)] = (bf16x8)0;
  }
  __syncthreads();

  {
    f32x4 acc[7][2];
    #pragma unroll
    for (int i = 0; i < 7; ++i) { acc[i][0] = (f32x4){0,0,0,0}; acc[i][1] = (f32x4){0,0,0,0}; }
    #pragma unroll
    for (int k0 = 0; k0 < 64; k0 += 32) {
      int cg = (k0 + fk) >> 3;
      int br0 = ((2 * wv) << 4) + fr, br1 = ((2 * wv + 1) << 4) + fr;
      bf16x8 bf0 = *(const bf16x8*)&Bsh[(br0 << 6) + (SWZ8(cg, br0) << 3)];
      bf16x8 bf1 = *(const bf16x8*)&Bsh[(br1 << 6) + (SWZ8(cg, br1) << 3)];
      #pragma unroll
      for (int rt = 0; rt < 7; ++rt) {
        int ar = (rt << 4) + fr;
        bf16x8 af = *(const bf16x8*)&Abuf[(ar << 6) + (SWZ8(cg, ar) << 3)];
        acc[rt][0] = __builtin_amdgcn_mfma_f32_16x16x32_bf16(af, bf0, acc[rt][0], 0, 0, 0);
        acc[rt][1] = __builtin_amdgcn_mfma_f32_16x16x32_bf16(af, bf1, acc[rt][1], 0, 0, 0);
      }
    }
    #pragma unroll
    for (int rt = 0; rt < 7; ++rt)
      #pragma unroll
      for (int cj = 0; cj < 2; ++cj) {
        int c = ((2 * wv + cj) << 4) + ccl;
        #pragma unroll
        for (int r = 0; r < 4; ++r) {
          int g = (rt << 4) + crl + r;
          Ps[(c << 7) + (SWZ16(g >> 3, c) << 3) + (g & 7)] =
              (short)f2bf(siluf(acc[rt][cj][r]));
        }
      }
  }
  __syncthreads();
  for (int gid = tid; gid < 1024; gid += 256) {
    int r = gid >> 4, cg = gid & 15;
    bf16x8 v = (bf16x8)0;
    if (r < 49) {
      #pragma unroll
      for (int j = 0; j < 8; ++j) {
        int col = (cg << 3) + j;
        if (col < 98) v[j] = (short)fgb[r * 98 + col];
      }
    }
    *(bf16x8*)&Abuf[(r << 7) + (SWZ16(cg, r) << 3)] = v;
  }
  __syncthreads();

  {
    f32x4 acc[4][2];
    #pragma unroll
    for (int i = 0; i < 4; ++i) { acc[i][0] = (f32x4){0,0,0,0}; acc[i][1] = (f32x4){0,0,0,0}; }
    #pragma unroll
    for (int k0 = 0; k0 < 128; k0 += 32) {
      int cg = (k0 + fk) >> 3;
      int br0 = ((2 * wv) << 4) + fr, br1 = ((2 * wv + 1) << 4) + fr;
      bf16x8 bf0 = *(const bf16x8*)&Ps[(br0 << 7) + (SWZ16(cg, br0) << 3)];
      bf16x8 bf1 = *(const bf16x8*)&Ps[(br1 << 7) + (SWZ16(cg, br1) << 3)];
      #pragma unroll
      for (int rt = 0; rt < 4; ++rt) {
        int ar = (rt << 4) + fr;
        bf16x8 af = *(const bf16x8*)&Abuf[(ar << 7) + (SWZ16(cg, ar) << 3)];
        acc[rt][0] = __builtin_amdgcn_mfma_f32_16x16x32_bf16(af, bf0, acc[rt][0], 0, 0, 0);
        acc[rt][1] = __builtin_amdgcn_mfma_f32_16x16x32_bf16(af, bf1, acc[rt][1], 0, 0, 0);
      }
    }
    #pragma unroll
    for (int rt = 0; rt < 4; ++rt)
      #pragma unroll
      for (int cj = 0; cj < 2; ++cj) {
        int c = ((2 * wv + cj) << 4) + ccl;
        #pragma unroll
        for (int r = 0; r < 4; ++r) {
          int q = (rt << 4) + crl + r;
          Bsh[(c << 6) + (SWZ8(q >> 3, c) << 3) + (q & 7)] = (short)f2bf(acc[rt][cj][r]);
        }
      }
  }
  __syncthreads();
  {
    const float* we = wigv + (long long)e * 2401;
    for (int gid = tid; gid < 512; gid += 256) {
      int r = gid >> 3, cg = gid & 7;
      bf16x8 v = (bf16x8)0;
      if (r < 49) {
        #pragma unroll
        for (int j = 0; j < 8; ++j) {
          int col = (cg << 3) + j;
          if (col < 49) v[j] = (short)f2bf(we[r * 49 + col]);
        }
      }
      *(bf16x8*)&Abuf[(r << 6) + (SWZ8(cg, r) << 3)] = v;
    }
  }
  __syncthreads();

  {
    f32x4 acc[4][2];
    #pragma unroll
    for (int i = 0; i < 4; ++i) { acc[i][0] = (f32x4){0,0,0,0}; acc[i][1] = (f32x4){0,0,0,0}; }
    #pragma unroll
    for (int k0 = 0; k0 < 64; k0 += 32) {
      int cg = (k0 + fk) >> 3;
      int br0 = ((2 * wv) << 4) + fr, br1 = ((2 * wv + 1) << 4) + fr;
      bf16x8 bf0 = *(const bf16x8*)&Bsh[(br0 << 6) + (SWZ8(cg, br0) << 3)];
      bf16x8 bf1 = *(const bf16x8*)&Bsh[(br1 << 6) + (SWZ8(cg, br1) << 3)];
      #pragma unroll
      for (int rt = 0; rt < 4; ++rt) {
        int ar = (rt << 4) + fr;
        bf16x8 af = *(const bf16x8*)&Abuf[(ar << 6) + (SWZ8(cg, ar) << 3)];
        acc[rt][0] = __builtin_amdgcn_mfma_f32_16x16x32_bf16(af, bf0, acc[rt][0], 0, 0, 0);
        acc[rt][1] = __builtin_amdgcn_mfma_f32_16x16x32_bf16(af, bf1, acc[rt][1], 0, 0, 0);
      }
    }
    #pragma unroll
    for (int rt = 0; rt < 4; ++rt)
      #pragma unroll
      for (int r = 0; r < 4; ++r) {
        int gi = (rt << 4) + crl + r;
        if (gi < 49) {
          #pragma unroll
          for (int cj = 0; cj < 2; ++cj) {
            int c = ((2 * wv + cj) << 4) + ccl;
            Ps[(gi << 7) + (((c >> 3) ^ (gi & 15)) << 3) + (c & 7)] =
                (short)f2bf(acc[rt][cj][r]);
          }
        }
      }
    __syncthreads();
    ushort_t* oe = msg3 + (long long)e * 6272;
    for (int gid = tid; gid < 784; gid += 256) {
      int row = gid >> 4, cc = gid & 15;
      bf16x8 v = *(const bf16x8*)&Ps[(row << 7) + ((cc ^ (row & 15)) << 3)];
      *(bf16x8*)&oe[(row << 7) + (cc << 3)] = v;
    }
  }
}

// ---------------------------------------------------------------------------
// Segment-sum via per-atom edge lists (vectorized bf16x8 gather)
// ---------------------------------------------------------------------------
__global__ __launch_bounds__(256) void k_zeroi(int* __restrict__ p, int n) {
  int id = blockIdx.x * 256 + threadIdx.x;
  if (id < n) p[id] = 0;
}

__global__ __launch_bounds__(256) void k_deg(
    const int* __restrict__ tgt, int* __restrict__ deg) {
  int e = blockIdx.x * 256 + threadIdx.x;
  if (e < EN) atomicAdd(&deg[tgt[e]], 1);
}

__global__ __launch_bounds__(1024) void k_prefix(
    const int* __restrict__ deg, int* __restrict__ base) {
  __shared__ int s[1024];
  int t = threadIdx.x;
  s[t] = (t < AN) ? deg[t] : 0;
  __syncthreads();
  for (int ofs = 1; ofs < 1024; ofs <<= 1) {
    int u = (t >= ofs) ? s[t - ofs] : 0;
    __syncthreads();
    s[t] += u;
    __syncthreads();
  }
  if (t < AN) base[t + 1] = s[t];
  if (t == 0) base[0] = 0;
}

__global__ __launch_bounds__(256) void k_fill(
    const int* __restrict__ tgt, const int* __restrict__ base,
    int* __restrict__ list) {
  const int a = blockIdx.x, t = threadIdx.x;
  const int lane = t & 63, w = t >> 6;
  __shared__ int wtot[4];
  __shared__ int runbase;
  if (t == 0) runbase = base[a];
  __syncthreads();
  for (int i0 = 0; i0 < EN; i0 += 256) {
    int e = i0 + t;
    bool m = (e < EN) && (tgt[e] == a);
    unsigned long long bal = __ballot(m);
    if (lane == 0) wtot[w] = __popcll(bal);
    __syncthreads();
    int wbase = 0;
    for (int j = 0; j < w; ++j) wbase += wtot[j];
    int tot = wtot[0] + wtot[1] + wtot[2] + wtot[3];
    if (m) {
      int off = __popcll(bal & ((1ull << lane) - 1ull));
      list[runbase + wbase + off] = e;
    }
    __syncthreads();
    if (t == 0) runbase += tot;
    __syncthreads();
  }
}

__global__ __launch_bounds__(256) void k_gather4(
    const ushort_t* __restrict__ msg3, const int* __restrict__ base,
    const int* __restrict__ list, float* __restrict__ xmsg,
    int e0, int ce, int accum)
{
  const int a = blockIdx.x, part = blockIdx.y, t = threadIdx.x;
  if (t >= 196) return;
  const int b0 = base[a], b1 = base[a + 1];
  const int co = part * 1568 + t * 8;
  float a8[8];
  #pragma unroll
  for (int u = 0; u < 8; ++u) a8[u] = 0.f;
  for (int i = b0; i < b1; ++i) {
    int e = list[i];
    if (e < e0 || e >= e0 + ce) continue;
    bf16x8 v = *(const bf16x8*)&msg3[(long long)(e - e0) * 6272 + co];
    #pragma unroll
    for (int u = 0; u < 8; ++u) a8[u] += bf2f((ushort_t)v[u]);
  }
  float* o = xmsg + (long long)a * 6272 + co;
  if (accum) {
    #pragma unroll
    for (int u = 0; u < 8; ++u) o[u] += a8[u];
  } else {
    float4 lo = make_float4(a8[0], a8[1], a8[2], a8[3]);
    float4 hi = make_float4(a8[4], a8[5], a8[6], a8[7]);
    *(float4*)o = lo;
    *(float4*)(o + 4) = hi;
  }
}

// ---------------------------------------------------------------------------
// Host orchestration
// ---------------------------------------------------------------------------
extern "C" void kernel_launch(void* const* d_in, const int* in_sizes, int n_in,
                              void* d_out, int out_size, void* d_ws, size_t ws_size,
                              hipStream_t stream) {
  const float* x         = (const float*)d_in[0];
  const float* edist     = (const float*)d_in[1];
  const float* wigner    = (const float*)d_in[2];
  const float* wiginv    = (const float*)d_in[3];
  const float* to_grid   = (const float*)d_in[4];
  const float* from_grid = (const float*)d_in[5];
  const float* w_dist1   = (const float*)d_in[6];
  const float* b_dist1   = (const float*)d_in[7];
  const float* src_emb   = (const float*)d_in[8];
  const float* tgt_emb   = (const float*)d_in[9];
  const float* w_edge1   = (const float*)d_in[10];
  const float* b_edge1   = (const float*)d_in[11];
  const float* ws1       = (const float*)d_in[12];
  const float* bs1       = (const float*)d_in[13];
  const float* ws2       = (const float*)d_in[14];
  const float* bs2       = (const float*)d_in[15];
  const float* ws3       = (const float*)d_in[16];
  const float* bs3       = (const float*)d_in[17];
  const int*   anum      = (const int*)d_in[18];
  const int*   eidx      = (const int*)d_in[19];
  const float* sw[10]; const float* tw[10];
  for (int i = 0; i < 10; ++i) {
    sw[i] = (const float*)d_in[20 + i];
    tw[i] = (const float*)d_in[30 + i];
  }
  float* outp = (float*)d_out;

  // ---- workspace ----
  char* wsb = (char*)d_ws;
  size_t off = 0;
  auto alloc = [&](long long nbytes) {
    char* p = wsb + off; off += (size_t)((nbytes + 63) & ~63LL); return p;
  };
  ushort_t* x_edge  = (ushort_t*)alloc((8000LL + 128) * 128 * 2);
  ushort_t* b2ab    = (ushort_t*)alloc(5505024LL * 2);
  ushort_t* bgcw    = (ushort_t*)alloc(851968LL * 2);
  float*    bgcb    = (float*)alloc(6656 * 4);
  ushort_t* b20b    = (ushort_t*)alloc(458752LL * 2);
  ushort_t* s1m0b   = (ushort_t*)alloc(458752LL * 2);
  ushort_t* s1mb    = (ushort_t*)alloc(2752512LL * 2);
  ushort_t* wd1b    = (ushort_t*)alloc(65536 * 2);
  ushort_t* we1b    = (ushort_t*)alloc(16384 * 2);
  ushort_t* ws1b    = (ushort_t*)alloc(32768 * 2);
  ushort_t* ws2b    = (ushort_t*)alloc(16384 * 2);
  ushort_t* ws3b    = (ushort_t*)alloc(16384 * 2);
  ushort_t* tgb     = (ushort_t*)alloc(4802 * 2);
  ushort_t* fgb     = (ushort_t*)alloc(4802 * 2);
  float*    xmsg    = (float*)alloc(5017600LL * 4);
  ushort_t* xmsgb   = (ushort_t*)alloc((5017600LL + 16384) * 2);
  ushort_t* xb      = (ushort_t*)alloc((5017600LL + 16384) * 2);
  ushort_t* xbT     = (ushort_t*)alloc(6553600LL * 2);
  ushort_t* basis   = (ushort_t*)alloc((8000LL + 128) * 512 * 2);
  float*    x_dist  = (float*)alloc(1024000LL * 4);
  ushort_t* x_distb = (ushort_t*)alloc((8000LL + 128) * 128 * 2);
  int*      deg     = (int*)alloc(800 * 4);
  int*      sbase   = (int*)alloc(801 * 4);
  int*      elist   = (int*)alloc(8000 * 4);
  const size_t fixedB = off;
  char* arena = wsb + off;

  static const int ces[6] = {8000, 4000, 2000, 1000, 500, 250};
  static const int cas[6] = {800, 800, 800, 400, 200, 100};
  int ce = 250, ca = 100;
  for (int i = 0; i < 6; ++i) {
    long long ne = (long long)ces[i] * 76544 + 64LL * 50688;
    long long na = (long long)cas[i] * 87808 + 64LL * 512;
    long long need = (long long)fixedB + (ne > na ? ne : na);
    if (need <= (long long)ws_size) { ce = ces[i]; ca = cas[i]; break; }
  }

  // edge-phase arena (padded A-sources)
  char* ap = arena;
  ushort_t* xrot_s = (ushort_t*)ap;  ap += (long long)(ce + 64) * 12544;
  ushort_t* xrot_t = (ushort_t*)ap;  ap += (long long)(ce + 64) * 12544;
  ushort_t* tb0    = (ushort_t*)ap;  ap += (long long)(ce + 64) * 1024;
  ushort_t* tbm    = (ushort_t*)ap;  ap += (long long)(ce + 64) * 24576;
  ushort_t* msgp   = (ushort_t*)ap;  ap += (long long)ce * 12544;
  ushort_t* gate   = (ushort_t*)ap;  // ce x 6656 bf16
  ushort_t* msg3   = (ushort_t*)arena;
  // atom-phase arena
  char* bp = arena;
  ushort_t* hb = (ushort_t*)bp;  bp += (long long)ca * 49 * 256;
  ushort_t* g1 = (ushort_t*)bp;  bp += ((long long)ca * 98 + 64) * 256;
  ushort_t* g2 = (ushort_t*)bp;  bp += ((long long)ca * 98 + 64) * 256;
  ushort_t* g3 = (ushort_t*)bp;

  long long ofs2[7][2], s1ofs[7][2];
  { long long cur = 0, cur1 = 0;
    for (int m = 1; m <= 6; ++m) {
      int k = (7 - m) * 128;
      ofs2[m][0] = cur; cur += (long long)k * 1024;
      ofs2[m][1] = cur; cur += (long long)k * 1024;
      s1ofs[m][0] = cur1; cur1 += 512LL * k;
      s1ofs[m][1] = cur1; cur1 += 512LL * k;
    } }

  auto D0 = []() { GemmP p; memset(&p, 0, sizeof(p)); p.asplit = 1 << 30; p.gse = 6656; return p; };
  auto finalize = [&](Grouped& G) {
    int base = 0;
    for (int i = 0; i < G.nd; ++i) {
      GemmP& p = G.d[i];
      p.ngx = (p.M + 127) >> 7;
      int ngy = (p.N + 127) >> 7;
      p.wg_base = base;
      base += p.ngx * ngy;
    }
    G.nwg = base;
    gemm_g<<<base, 256, 0, stream>>>(G);
  };
  auto run1 = [&](GemmP p) { Grouped G; G.d[0] = p; G.nd = 1; finalize(G); };
  auto rungrid = [&](const float* A, int M, int K, int permA,
                     const ushort_t* B, int b_ib, void* C, int c_ib,
                     const float* bias, int act, int c_bf16, int nb) {
    GridP p;
    p.A = A; p.B = B; p.C = C; p.bias = bias;
    p.b_ib = b_ib; p.c_ib = c_ib;
    p.M = M; p.K = K; p.permA = permA; p.act = act; p.c_bf16 = c_bf16;
    gridmm<<<nb, 256, 0, stream>>>(p);
  };

  // 0) builds
  k_build_b2b<<<(5505024 + 255) / 256, 256, 0, stream>>>(sw[7], sw[9], tw[7], tw[9], b2ab);
  k_build_bgcat<<<(858624 + 255) / 256, 256, 0, stream>>>(
      sw[0], tw[0], sw[4], tw[4], sw[1], tw[1], sw[5], tw[5], bgcw, bgcb);
  k_build_b20b<<<(458752 + 255) / 256, 256, 0, stream>>>(sw[3], tw[3], b20b);
  k_build_s1m<<<(2752512 + 255) / 256, 256, 0, stream>>>(sw[6], sw[8], tw[6], tw[8], s1mb);
  { // merged conversions
    CvtM P;
    const float* ss[9] = { sw[2], tw[2], w_dist1, w_edge1, ws1, ws2, ws3, from_grid, x };
    ushort_t* dd[9] = { s1m0b, s1m0b + 229376, wd1b, we1b, ws1b, ws2b, ws3b, fgb, xb };
    long long nn[9] = { 229376, 229376, 65536, 16384, 32768, 16384, 16384, 4802, 5017600 };
    long long cur = 0;
    for (int i = 0; i < 9; ++i) { P.s[i] = ss[i]; P.d[i] = dd[i]; P.start[i] = cur; cur += nn[i]; }
    P.start[9] = cur;
    k_cvt_multi<<<(int)((cur + 255) / 256), 256, 0, stream>>>(P);
  }
  k_build_tg<<<(4802 + 255) / 256, 256, 0, stream>>>(to_grid, tgb);
  k_xT<<<AN, 256, 0, stream>>>(x, xbT);

  // scatter lists
  k_zeroi<<<4, 256, 0, stream>>>(deg, 800);
  k_deg<<<(EN + 255) / 256, 256, 0, stream>>>(eidx + EN, deg);
  k_prefix<<<1, 1024, 0, stream>>>(deg, sbase);
  k_fill<<<AN, 256, 0, stream>>>(eidx + EN, sbase, elist);

  // 1) edge features
  k_basis<<<(EN * 512 + 255) / 256, 256, 0, stream>>>(edist, basis);
  { GemmP p = D0();
    p.A = basis; p.a_se = 512; p.B = wd1b; p.ldb = 512; p.bias = b_dist1;
    p.C = x_dist; p.c_se = 128; p.M = EN; p.N = 128; p.K = 512;
    run1(p); }
  k_emb<<<(EN * 128 + 255) / 256, 256, 0, stream>>>(src_emb, tgt_emb, anum, eidx,
                                                    x_dist, x_distb);
  { GemmP p = D0();
    p.A = x_distb; p.a_se = 128; p.B = we1b; p.ldb = 128; p.bias = b_edge1;
    p.act = 1; p.C = x_edge; p.c_se = 128; p.c_bf16 = 1;
    p.M = EN; p.N = 128; p.K = 128;
    run1(p); }

  static const int offq[7] = {0, 7, 19, 29, 37, 43, 47};

  // 2) edge chunks
  for (int e0 = 0; e0 < EN; e0 += ce) {
    const int c = ce;
    k_rot2<<<c, 256, 0, stream>>>(wigner + (long long)e0 * 2401, xbT,
                                  eidx + e0, eidx + EN + e0, xrot_s, xrot_t);
    // gates (N=6656)
    { GemmP p = D0();
      p.A = x_edge + (long long)e0 * 128; p.a_se = 128;
      p.B = bgcw; p.ldb = 128; p.bias = bgcb; p.act = 1;
      p.C = gate; p.c_se = 6656; p.c_bf16 = 1;
      p.M = c; p.N = 6656; p.K = 128;
      run1(p); }
    // stage 1 grouped
    { Grouped G; G.nd = 14;
      for (int s = 0; s < 2; ++s) {
        GemmP p = D0();
        p.A = s ? xrot_t : xrot_s; p.a_se = 6272;
        p.B = s1m0b + (long long)s * 229376; p.ldb = 896;
        p.gate = gate; p.gate_ofs = s * 256;
        p.C = tb0; p.c_se = 512; p.c_ofs = s * 256; p.c_bf16 = 1;
        p.M = c; p.N = 256; p.K = 896;
        G.d[s] = p;
      }
      int di = 2;
      for (int m = 1; m <= 6; ++m) {
        const int k = (7 - m) * 128, off2 = offq[m];
        for (int s = 0; s < 2; ++s) {
          GemmP p = D0();
          p.A = (s ? xrot_t : xrot_s) + off2 * 128;
          p.a_se = 6272; p.a_si = k; p.pair = 1;
          p.B = s1mb + s1ofs[m][s]; p.ldb = k;
          p.gate = gate; p.gate_ofs = 512 + (m - 1) * 1024 + s * 512;
          p.C = tbm; p.c_se = 12288; p.c_si = 1024;
          p.c_ofs = (m - 1) * 2048 + s * 512;
          p.ihalf = 1; p.c_bf16 = 1;
          p.M = 2 * c; p.N = 512; p.K = k;
          G.d[di++] = p;
        }
      }
      finalize(G); }
    // stage 2 grouped
    { Grouped G; G.nd = 13;
      { GemmP p = D0();
        p.A = tb0; p.a_se = 512;
        p.B = b20b; p.ldb = 512;
        p.C = msgp; p.c_se = 6272; p.c_bf16 = 1;
        p.M = c; p.N = 896; p.K = 512;
        G.d[0] = p; }
      int di = 1;
      for (int m = 1; m <= 6; ++m) {
        const int n = 7 - m, k = n * 128, off2 = offq[m];
        for (int pp = 0; pp < 2; ++pp) {
          GemmP p = D0();
          p.A = tbm + (m - 1) * 2048 + pp * 1024; p.a_se = 12288;
          p.B = b2ab + ofs2[m][pp]; p.ldb = 1024;
          p.C = msgp; p.c_se = 6272; p.c_ofs = (off2 + (pp ? n : 0)) * 128; p.c_bf16 = 1;
          p.M = c; p.N = k; p.K = 1024;
          G.d[di++] = p;
        }
      }
      finalize(G); }
    // fused grid pipeline + gather
    k_grid<<<c, 256, 0, stream>>>(tgb, fgb, wiginv + (long long)e0 * 2401, msgp, msg3);
    k_gather4<<<dim3(AN, 4), 256, 0, stream>>>(msg3, sbase, elist, xmsg, e0, c, e0 > 0);
  }

  // xmsg -> bf16 for atom GEMM
  k_cvt<<<(5017600 + 255) / 256, 256, 0, stream>>>(xmsg, xmsgb, 5017600);

  // 3) atom phase
  for (int a0 = 0; a0 < AN; a0 += ca) {
    { GemmP p = D0();
      p.A = xb + (long long)a0 * 6272; p.A2 = xmsgb + (long long)a0 * 6272;
      p.a_se = 128; p.asplit = 128;
      p.B = ws1b; p.ldb = 256;
      p.C = hb; p.c_se = 128; p.c_bf16 = 1;
      p.M = ca * 49; p.N = 128; p.K = 256;
      run1(p); }
    rungrid(to_grid, 98, 49, 0, hb, 6272, g1, 12544, bs1, 1, 1, ca);
    { GemmP p = D0();
      p.A = g1; p.a_se = 128;
      p.B = ws2b; p.ldb = 128; p.bias = bs2; p.act = 1;
      p.C = g2; p.c_se = 128; p.c_bf16 = 1;
      p.M = ca * 98; p.N = 128; p.K = 128;
      run1(p); }
    { GemmP p = D0();
      p.A = g2; p.a_se = 128;
      p.B = ws3b; p.ldb = 128; p.bias = bs3;
      p.C = g3; p.c_se = 128; p.c_bf16 = 1;
      p.M = ca * 98; p.N = 128; p.K = 128;
      run1(p); }
    rungrid(from_grid, 49, 98, 0, g3, 12544, outp + (long long)a0 * 6272, 6272,
            nullptr, 0, 0, ca);
  }
}

// Round 11
// 1594.814 us; speedup vs baseline: 1.4668x; 1.0212x over previous
//
#include <hip/hip_runtime.h>
#include <string.h>

#define EN 8000
#define AN 800

typedef __attribute__((ext_vector_type(8))) short bf16x8;
typedef __attribute__((ext_vector_type(4))) float f32x4;
typedef unsigned short ushort_t;
typedef unsigned int uint32;

__constant__ int c_perm[49] = {
  0,2,6,12,20,30,42,
  1,5,11,19,29,41,
  3,7,13,21,31,43,
  4,10,18,28,40,
  8,14,22,32,44,
  9,17,27,39,
  15,23,33,45,
  16,26,38,
  24,34,46,
  25,37,
  35,47,
  36,
  48
};

__device__ __forceinline__ float siluf(float x) { return x / (1.0f + __expf(-x)); }
__device__ __forceinline__ ushort_t f2bf(float f) {
  uint32 u = __float_as_uint(f);
  u += 0x7fff + ((u >> 16) & 1);
  return (ushort_t)(u >> 16);
}
__device__ __forceinline__ float bf2f(ushort_t h) {
  return __uint_as_float(((uint32)h) << 16);
}
__device__ __forceinline__ void gld16(const void* g, void* l) {
  __builtin_amdgcn_global_load_lds(
      (const __attribute__((address_space(1))) void*)g,
      (__attribute__((address_space(3))) void*)l, 16, 0, 0);
}

// ---------------------------------------------------------------------------
// Weight builders (bf16 outputs)
// ---------------------------------------------------------------------------
__global__ __launch_bounds__(256) void k_build_b2b(
    const float* __restrict__ sw2r, const float* __restrict__ sw2i,
    const float* __restrict__ tw2r, const float* __restrict__ tw2i,
    ushort_t* __restrict__ dst)
{
  long long id = (long long)blockIdx.x * 256 + threadIdx.x;
  if (id >= 5505024LL) return;
  long long base = 0; int m = 1, k = 768;
  for (; m <= 6; ++m) {
    k = (7 - m) * 128;
    long long sz = 2LL * k * 1024;
    if (id < base + sz) break;
    base += sz;
  }
  long long rem = id - base;
  int p = (int)(rem / ((long long)k * 1024));
  int cj = (int)(rem - (long long)p * k * 1024);
  int c = cj >> 10, j = cj & 1023;
  int q = j >> 8, jj = j & 255;
  const float sgn = (q & 1) ? (p ? 1.f : -1.f) : 1.f;
  const float* src = (q < 2) ? (q == 0 ? sw2r : sw2i) : (q == 2 ? tw2r : tw2i);
  dst[id] = f2bf(sgn * src[(long long)(m - 1) * 196608 + c * 256 + jj]);
}

__global__ __launch_bounds__(256) void k_build_bgcat(
    const float* __restrict__ sw0, const float* __restrict__ tw0,
    const float* __restrict__ sw4, const float* __restrict__ tw4,
    const float* __restrict__ sb0, const float* __restrict__ tb0b,
    const float* __restrict__ sbd, const float* __restrict__ tbd,
    ushort_t* __restrict__ w, float* __restrict__ b)
{
  int id = blockIdx.x * 256 + threadIdx.x;
  if (id < 851968) {
    int r = id >> 7, c = id & 127;
    float v;
    if (r < 256) v = sw0[r * 128 + c];
    else if (r < 512) v = tw0[(r - 256) * 128 + c];
    else {
      int rr = r - 512, m = rr >> 10, q = rr & 1023;
      v = (q < 512) ? sw4[m * 65536 + q * 128 + c] : tw4[m * 65536 + (q - 512) * 128 + c];
    }
    w[id] = f2bf(v);
    return;
  }
  id -= 851968;
  if (id < 6656) {
    float v;
    if (id < 256) v = sb0[id];
    else if (id < 512) v = tb0b[id - 256];
    else {
      int rr = id - 512, m = rr >> 10, q = rr & 1023;
      v = (q < 512) ? sbd[m * 512 + q] : tbd[m * 512 + (q - 512)];
    }
    b[id] = v;
  }
}

__global__ __launch_bounds__(256) void k_build_b20b(
    const float* __restrict__ sw3, const float* __restrict__ tw3,
    ushort_t* __restrict__ b20)
{
  int id = blockIdx.x * 256 + threadIdx.x;
  if (id >= 458752) return;
  int cc = id >> 9, j = id & 511;
  b20[id] = f2bf((j < 256) ? sw3[cc * 256 + j] : tw3[cc * 256 + (j - 256)]);
}

__global__ __launch_bounds__(256) void k_build_s1m(
    const float* __restrict__ sw6, const float* __restrict__ sw8,
    const float* __restrict__ tw6, const float* __restrict__ tw8,
    ushort_t* __restrict__ dst)
{
  long long id = (long long)blockIdx.x * 256 + threadIdx.x;
  if (id >= 2752512LL) return;
  long long base = 0; int m = 1, k = 768;
  for (; m <= 6; ++m) {
    k = (7 - m) * 128;
    long long sz = 1024LL * k;
    if (id < base + sz) break;
    base += sz;
  }
  long long rem = id - base;
  int s = (int)(rem / (512LL * k));
  int rr = (int)(rem - (long long)s * 512 * k);
  int r = rr / k, c = rr - r * k;
  const float* src = (r < 256) ? (s ? tw6 : sw6) : (s ? tw8 : sw8);
  int r0 = (r < 256) ? r : r - 256;
  dst[id] = f2bf(src[(long long)(m - 1) * 196608 + r0 * 768 + c]);
}

// merged f32->bf16 conversions (up to 9 segments)
struct CvtM {
  const float* s[9];
  ushort_t* d[9];
  long long start[10];
};
__global__ __launch_bounds__(256) void k_cvt_multi(CvtM P) {
  long long id = (long long)blockIdx.x * 256 + threadIdx.x;
  if (id >= P.start[9]) return;
  int seg = 0;
  #pragma unroll
  for (int i = 1; i < 9; ++i) if (id >= P.start[i]) seg = i;
  long long o = id - P.start[seg];
  P.d[seg][o] = f2bf(P.s[seg][o]);
}

__global__ __launch_bounds__(256) void k_cvt(
    const float* __restrict__ src, ushort_t* __restrict__ dst, int n)
{
  int id = blockIdx.x * 256 + threadIdx.x;
  if (id < n) dst[id] = f2bf(src[id]);
}

__global__ __launch_bounds__(256) void k_build_tg(
    const float* __restrict__ tg, ushort_t* __restrict__ dst)
{
  int id = blockIdx.x * 256 + threadIdx.x;
  if (id >= 98 * 49) return;
  int r = id / 49, s = id - r * 49;
  dst[id] = f2bf(tg[r * 49 + c_perm[s]]);
}

// transpose x (f32 [49][128]) -> xbT (bf16 [128][64], j-padded)
__global__ __launch_bounds__(256) void k_xT(
    const float* __restrict__ x, ushort_t* __restrict__ xbT)
{
  __shared__ __align__(16) float xs[49 * 128];
  const int a = blockIdx.x, t = threadIdx.x;
  const float4* src = (const float4*)(x + (long long)a * 6272);
  float4* d = (float4*)xs;
  for (int i = t; i < 1568; i += 256) d[i] = src[i];
  __syncthreads();
  ushort_t* o = xbT + (long long)a * 8192;
  int c = t >> 1;
  int jg = (t & 1) << 2;
  #pragma unroll
  for (int u = 0; u < 4; ++u) {
    int g = jg + u;
    bf16x8 v = (bf16x8)0;
    #pragma unroll
    for (int j = 0; j < 8; ++j) {
      int jj = (g << 3) + j;
      if (jj < 49) v[j] = (short)f2bf(xs[jj * 128 + c]);
    }
    *(bf16x8*)&o[(c << 6) + (g << 3)] = v;
  }
}

// ---------------------------------------------------------------------------
// Edge features
// ---------------------------------------------------------------------------
__global__ __launch_bounds__(256) void k_basis(
    const float* __restrict__ dist, ushort_t* __restrict__ basis)
{
  int id = blockIdx.x * 256 + threadIdx.x;
  if (id >= EN * 512) return;
  int e = id >> 9, g = id & 511;
  const float step = 8.0f / 511.0f;
  const float coeff = -2040.0078125f;
  float df = dist[e] - (float)g * step;
  basis[id] = f2bf(expf(coeff * df * df));
}

__global__ __launch_bounds__(256) void k_emb(
    const float* __restrict__ src_emb, const float* __restrict__ tgt_emb,
    const int* __restrict__ anum, const int* __restrict__ eidx,
    const float* __restrict__ xd, ushort_t* __restrict__ out)
{
  int id = blockIdx.x * 256 + threadIdx.x;
  if (id >= EN * 128) return;
  int e = id >> 7, c = id & 127;
  int a0 = anum[eidx[e]], a1 = anum[eidx[EN + e]];
  out[id] = f2bf(siluf(src_emb[a0 * 128 + c] + tgt_emb[a1 * 128 + c] + xd[id]));
}

// ---------------------------------------------------------------------------
// MFMA Wigner rotation with coalesced (repacked) output
// ---------------------------------------------------------------------------
__global__ __launch_bounds__(256) void k_rot2(
    const float* __restrict__ wig, const ushort_t* __restrict__ xbT,
    const int* __restrict__ srcl, const int* __restrict__ tgtl,
    ushort_t* __restrict__ osrc, ushort_t* __restrict__ otgt)
{
  __shared__ short Ws[4096];
  __shared__ short Xs[8192];
  __shared__ short Xt[8192];
  const int e = blockIdx.x, tid = threadIdx.x;
  const int lane = tid & 63, wave = tid >> 6;
  const float* wge = wig + (long long)e * 2401;
  #pragma unroll
  for (int t = 0; t < 2; ++t) {
    int ci = (t << 8) + tid;
    int row = ci >> 3, g = ci & 7;
    bf16x8 v = (bf16x8)0;
    if (row < 49) {
      const float* wr = wge + c_perm[row] * 49;
      #pragma unroll
      for (int j = 0; j < 8; ++j) {
        int col = (g << 3) + j;
        if (col < 49) v[j] = (short)f2bf(wr[col]);
      }
    }
    *(bf16x8*)&Ws[(row << 6) + ((g ^ (row & 7)) << 3)] = v;
  }
  const int as = srcl[e], at = tgtl[e];
  const ushort_t* xsg = xbT + (long long)as * 8192;
  const ushort_t* xtg = xbT + (long long)at * 8192;
  #pragma unroll
  for (int t = 0; t < 4; ++t) {
    int ci = (t << 8) + tid;
    int row = ci >> 3, g = ci & 7;
    int ofs = (row << 6) + ((g ^ (row & 7)) << 3);
    *(bf16x8*)&Xs[ofs] = *(const bf16x8*)&xsg[ci << 3];
    *(bf16x8*)&Xt[ofs] = *(const bf16x8*)&xtg[ci << 3];
  }
  __syncthreads();
  const short* Xb = (wave >> 1) ? Xt : Xs;
  const int ch = (wave & 1) << 6;
  const int fr = lane & 15, g = lane >> 4;
  f32x4 acc[4][4];
  #pragma unroll
  for (int i = 0; i < 4; ++i)
    #pragma unroll
    for (int j = 0; j < 4; ++j) acc[i][j] = (f32x4){0.f, 0.f, 0.f, 0.f};
  #pragma unroll
  for (int ks = 0; ks < 2; ++ks) {
    bf16x8 af[4], bfv[4];
    int lc = (ks << 2) + g;
    #pragma unroll
    for (int i = 0; i < 4; ++i) {
      int ra = (i << 4) + fr;
      af[i] = *(const bf16x8*)&Ws[(ra << 6) + ((lc ^ (ra & 7)) << 3)];
      int rb = ch + (i << 4) + fr;
      bfv[i] = *(const bf16x8*)&Xb[(rb << 6) + ((lc ^ (rb & 7)) << 3)];
    }
    #pragma unroll
    for (int i = 0; i < 4; ++i)
      #pragma unroll
      for (int j = 0; j < 4; ++j)
        acc[i][j] = __builtin_amdgcn_mfma_f32_16x16x32_bf16(af[i], bfv[j], acc[i][j], 0, 0, 0);
  }
  const int crl = (lane >> 4) << 2, ccl = lane & 15;
  __syncthreads();
  short* Ob = (wave >> 1) ? Xt : Xs;
  #pragma unroll
  for (int i = 0; i < 4; ++i)
    #pragma unroll
    for (int r = 0; r < 4; ++r) {
      int q = (i << 4) + crl + r;
      if (q < 49) {
        #pragma unroll
        for (int j = 0; j < 4; ++j) {
          int col = ch + (j << 4) + ccl;
          Ob[(q << 7) + (((col >> 3) ^ (q & 15)) << 3) + (col & 7)] =
              (short)f2bf(acc[i][j][r]);
        }
      }
    }
  __syncthreads();
  for (int gid = tid; gid < 1568; gid += 256) {
    int half = gid >= 784;
    int c784 = half ? gid - 784 : gid;
    int row = c784 >> 4, cc = c784 & 15;
    const short* Sb = half ? Xt : Xs;
    bf16x8 v = *(const bf16x8*)&Sb[(row << 7) + ((cc ^ (row & 15)) << 3)];
    ushort_t* dst = (half ? otgt : osrc) + (long long)e * 6272 + (row << 7) + (cc << 3);
    *(bf16x8*)dst = v;
  }
}

// ---------------------------------------------------------------------------
// Grouped MFMA GEMM (84 VGPR / 32KB LDS, occupancy-safe).
// bf16, global_load_lds + swizzle, dbuf + counted vmcnt, XCD swizzle,
// LDS-repacked coalesced epilogue.
// wg decomposition is N-FASTEST (by = local % ngy): consecutive blocks share
// the A-panel so the bijective XCD chunking puts A-sharers on one L2.
// NOTE: epilogue extensions must stay under ~96 VGPR / 32KB LDS (round-9
// fused-gate at 172 VGPR/48KB collapsed occupancy to 8.5%, -43%).
// ---------------------------------------------------------------------------
struct GemmP {
  const ushort_t* A; const ushort_t* A2; const ushort_t* B;
  const float* bias; const ushort_t* gate; void* C;
  int a_se, a_si, pair, asplit;
  int ldb;
  int gate_ofs, gse;
  int c_se, c_si, c_ofs;
  int ihalf, act, c_bf16;
  int M, N, K;
  int ngx, ngy, wg_base;
};
struct Grouped { GemmP d[14]; int nd; int nwg; };

__global__ __launch_bounds__(256) void gemm_g(Grouped G) {
  __shared__ short SH[16384];       // staging (2x dbuf A|B) and epilogue repack
  short* As = SH;
  short* Bs = SH + 8192;
  int bid;
  { // bijective XCD chunk swizzle
    int n = G.nwg, orig = blockIdx.x;
    int q = n >> 3, r = n & 7;
    int xcd = orig & 7, pos = orig >> 3;
    bid = (xcd < r ? xcd * (q + 1) : r * (q + 1) + (xcd - r) * q) + pos;
  }
  int di = G.nd - 1;
  for (int i = 1; i < G.nd; ++i) if (bid < G.d[i].wg_base) { di = i - 1; break; }
  const GemmP p = G.d[di];
  const int local = bid - p.wg_base;
  const int by = local % p.ngy, bx = local / p.ngy;   // N-fastest: A-panel reuse
  const int m0 = bx << 7, n0 = by << 7;

  const int tid = threadIdx.x;
  const int lane = tid & 63, wave = tid >> 6;
  const int gl = ((lane & 3) ^ ((lane >> 3) & 3)) << 3;
  const int grow = (wave << 4) + (lane >> 2);
  const int fr = lane & 15, fkg = lane >> 4;
  const int sxor = (fr >> 1) & 3;
  const int wm = (wave >> 1) << 6, wn = (wave & 1) << 6;

  f32x4 acc[4][4];
  #pragma unroll
  for (int i = 0; i < 4; ++i)
    #pragma unroll
    for (int j = 0; j < 4; ++j) acc[i][j] = (f32x4){0.f, 0.f, 0.f, 0.f};

  long long abase;
  {
    int r0 = m0 + grow;
    abase = p.pair
        ? (long long)(r0 >> 1) * p.a_se + (long long)(r0 & 1) * p.a_si
        : (long long)r0 * p.a_se;
  }
  long long abase2;
  {
    int r1 = m0 + 64 + grow;
    abase2 = p.pair
        ? (long long)(r1 >> 1) * p.a_se + (long long)(r1 & 1) * p.a_si
        : (long long)r1 * p.a_se;
  }
  const long long bbase  = (long long)(n0 + grow) * p.ldb;
  const long long bbase2 = (long long)(n0 + 64 + grow) * p.ldb;

  const int nt = p.K >> 5;

  auto STAGE = [&](int buf, int k0) {
    const ushort_t* Ap = p.A;
    int kk = k0;
    if (p.A2 && k0 >= p.asplit) { Ap = p.A2; kk = k0 - p.asplit; }
    const int lofs = (buf << 12) + (wave << 9);
    gld16(Ap + abase + kk + gl,   &As[lofs]);
    gld16(p.B + bbase + k0 + gl,  &Bs[lofs]);
    gld16(Ap + abase2 + kk + gl,  &As[lofs + 2048]);
    gld16(p.B + bbase2 + k0 + gl, &Bs[lofs + 2048]);
  };

  STAGE(0, 0);
  int cur = 0;
  for (int t = 0; t < nt; ++t) {
    if (t + 1 < nt) {
      STAGE(cur ^ 1, (t + 1) << 5);
      asm volatile("s_waitcnt vmcnt(4)" ::: "memory");
    } else {
      asm volatile("s_waitcnt vmcnt(0)" ::: "memory");
    }
    __builtin_amdgcn_sched_barrier(0);
    __builtin_amdgcn_s_barrier();
    {
      const int bofs = cur << 12;
      bf16x8 af[4], bfv[4];
      #pragma unroll
      for (int i = 0; i < 4; ++i) {
        int ra = wm + (i << 4) + fr;
        int rb = wn + (i << 4) + fr;
        af[i]  = *(const bf16x8*)&As[bofs + (ra << 5) + ((fkg ^ sxor) << 3)];
        bfv[i] = *(const bf16x8*)&Bs[bofs + (rb << 5) + ((fkg ^ sxor) << 3)];
      }
      #pragma unroll
      for (int i = 0; i < 4; ++i)
        #pragma unroll
        for (int j = 0; j < 4; ++j)
          acc[i][j] = __builtin_amdgcn_mfma_f32_16x16x32_bf16(af[i], bfv[j], acc[i][j], 0, 0, 0);
    }
    __builtin_amdgcn_s_barrier();
    cur ^= 1;
  }

  const int crl = (lane >> 4) << 2, ccl = lane & 15;
  if (p.c_bf16) {
    // 1) acc (+bias/act) -> SH[128][128] bf16 swizzled
    #pragma unroll
    for (int mi = 0; mi < 4; ++mi)
      #pragma unroll
      for (int r = 0; r < 4; ++r) {
        int lrow = wm + mi * 16 + crl + r;
        #pragma unroll
        for (int ni = 0; ni < 4; ++ni) {
          int lcol = wn + ni * 16 + ccl;
          float v = acc[mi][ni][r];
          int gc = n0 + lcol;
          if (p.bias) v += p.bias[gc];
          if (p.act)  v = siluf(v);
          SH[(lrow << 7) + (((lcol >> 3) ^ (lrow & 15)) << 3) + (lcol & 7)] =
              (short)f2bf(v);
        }
      }
    __syncthreads();
    // 2) coalesced output: 1 row, 64 cols per thread (8 x 16B)
    const int lr = tid >> 1, chalf = (tid & 1) << 6;
    int gr = m0 + lr;
    if (gr < p.M) {
      long long e; int ii;
      if (p.pair) { e = gr >> 1; ii = gr & 1; } else { e = gr; ii = 0; }
      const ushort_t* grw = p.gate ? p.gate + e * p.gse + p.gate_ofs : nullptr;
      #pragma unroll
      for (int j = 0; j < 8; ++j) {
        int lcol = chalf + (j << 3);
        bf16x8 v = *(const bf16x8*)&SH[(lr << 7) + (((lcol >> 3) ^ (lr & 15)) << 3)];
        int gc = n0 + lcol;
        if (grw) {
          bf16x8 g8 = *(const bf16x8*)&grw[gc];
          #pragma unroll
          for (int q2 = 0; q2 < 8; ++q2)
            v[q2] = (short)f2bf(bf2f((ushort_t)v[q2]) * bf2f((ushort_t)g8[q2]));
        }
        int par = (p.ihalf && gc >= 256) ? (1 - ii) : ii;
        long long co = e * (long long)p.c_se + (long long)par * p.c_si + p.c_ofs + gc;
        *(bf16x8*)&((ushort_t*)p.C)[co] = v;
      }
    }
  } else {
    // f32-C scalar path (x_dist only)
    #pragma unroll
    for (int mi = 0; mi < 4; ++mi) {
      #pragma unroll
      for (int r = 0; r < 4; ++r) {
        int gr = m0 + wm + mi * 16 + crl + r;
        if (gr >= p.M) continue;
        long long e = gr;
        float* crow = (float*)p.C + e * (long long)p.c_se + p.c_ofs;
        #pragma unroll
        for (int ni = 0; ni < 4; ++ni) {
          int gc = n0 + wn + ni * 16 + ccl;
          if (gc >= p.N) continue;
          float v = acc[mi][ni][r];
          if (p.bias) v += p.bias[gc];
          if (p.act)  v = siluf(v);
          crow[gc] = v;
        }
      }
    }
  }
}

// ---------------------------------------------------------------------------
// gridmm (atom phase)
// ---------------------------------------------------------------------------
struct GridP {
  const float* A; const ushort_t* B; void* C; const float* bias;
  int b_ib, c_ib;
  int M, K, permA, act, c_bf16;
};

#define LDW 40

__global__ __launch_bounds__(256) void gridmm(GridP p) {
  __shared__ short As[128 * LDW];
  __shared__ short Bs[128 * LDW];
  const int e = blockIdx.x;
  const int tid = threadIdx.x;
  const int srow = tid >> 1, sk = (tid & 1) << 4;
  const int lane = tid & 63, wave = tid >> 6;
  const int wm = (wave >> 1) << 6, wn = (wave & 1) << 6;
  const int fr = lane & 15, fk = (lane >> 4) << 3;

  f32x4 acc[4][4];
  #pragma unroll
  for (int i = 0; i < 4; ++i)
    #pragma unroll
    for (int j = 0; j < 4; ++j) acc[i][j] = (f32x4){0.f, 0.f, 0.f, 0.f};

  const ushort_t* bp0 = p.B + (long long)e * p.b_ib;

  for (int k0 = 0; k0 < p.K; k0 += 32) {
    {
      bf16x8 lo = (bf16x8)0, hi = (bf16x8)0;
      if (srow < p.M) {
        const float* ar = p.A + srow * p.K;
        #pragma unroll
        for (int j = 0; j < 8; ++j) {
          int col = k0 + sk + j;
          float v = 0.f;
          if (col < p.K) v = ar[p.permA ? c_perm[col] : col];
          lo[j] = (short)f2bf(v);
        }
        #pragma unroll
        for (int j = 0; j < 8; ++j) {
          int col = k0 + sk + 8 + j;
          float v = 0.f;
          if (col < p.K) v = ar[p.permA ? c_perm[col] : col];
          hi[j] = (short)f2bf(v);
        }
      }
      *(bf16x8*)&As[srow * LDW + sk] = lo;
      *(bf16x8*)&As[srow * LDW + sk + 8] = hi;
    }
    {
      const int c = tid & 127, kq = tid >> 7;
      #pragma unroll
      for (int i = 0; i < 8; ++i) {
        int kk = kq * 16 + i * 2;
        int k1 = k0 + kk, k2 = k1 + 1;
        uint32 v0 = (k1 < p.K) ? (uint32)bp0[(long long)k1 * 128 + c] : 0u;
        uint32 v1 = (k2 < p.K) ? (uint32)bp0[(long long)k2 * 128 + c] : 0u;
        *(uint32*)&Bs[c * LDW + kk] = v0 | (v1 << 16);
      }
    }
    __syncthreads();
    bf16x8 af[4], bfv[4];
    #pragma unroll
    for (int i = 0; i < 4; ++i) {
      af[i]  = *(const bf16x8*)(&As[(wm + i * 16 + fr) * LDW + fk]);
      bfv[i] = *(const bf16x8*)(&Bs[(wn + i * 16 + fr) * LDW + fk]);
    }
    #pragma unroll
    for (int i = 0; i < 4; ++i)
      #pragma unroll
      for (int j = 0; j < 4; ++j)
        acc[i][j] = __builtin_amdgcn_mfma_f32_16x16x32_bf16(af[i], bfv[j], acc[i][j], 0, 0, 0);
    __syncthreads();
  }

  const int crl = (lane >> 4) << 2, ccl = lane & 15;
  #pragma unroll
  for (int mi = 0; mi < 4; ++mi) {
    #pragma unroll
    for (int r = 0; r < 4; ++r) {
      int gr = wm + mi * 16 + crl + r;
      if (gr >= p.M) continue;
      #pragma unroll
      for (int ni = 0; ni < 4; ++ni) {
        int c = wn + ni * 16 + ccl;
        float v = acc[mi][ni][r];
        if (p.bias) v += p.bias[c];
        if (p.act)  v = siluf(v);
        long long co = (long long)e * p.c_ib + gr * 128 + c;
        if (p.c_bf16) ((ushort_t*)p.C)[co] = f2bf(v);
        else          ((float*)p.C)[co] = v;
      }
    }
  }
}

// ---------------------------------------------------------------------------
// Fused grid pipeline per edge: msg3 = WI @ (FG @ silu(TGp @ msgp))
// ---------------------------------------------------------------------------
#define SWZ8(cg, r) (((cg) ^ ((r) & 7)) & 7)
#define SWZ16(cg, r) (((cg) & 8) | (((cg) ^ (r)) & 7))

__global__ __launch_bounds__(256, 2) void k_grid(
    const ushort_t* __restrict__ tgb, const ushort_t* __restrict__ fgb,
    const float* __restrict__ wigv, const ushort_t* __restrict__ msgp,
    ushort_t* __restrict__ msg3)
{
  __shared__ short Abuf[8192];
  __shared__ short Bsh[8192];
  __shared__ short Ps[16384];
  const int e = blockIdx.x, tid = threadIdx.x;
  const int lane = tid & 63, wv = tid >> 6;
  const int fr = lane & 15, fk = (lane >> 4) << 3;
  const int crl = (lane >> 4) << 2, ccl = lane & 15;
  const ushort_t* me = msgp + (long long)e * 6272;

  for (int gid = tid; gid < 896; gid += 256) {
    int r = gid >> 3, cg = gid & 7;
    bf16x8 v = (bf16x8)0;
    if (r < 98) {
      #pragma unroll
      for (int j = 0; j < 8; ++j) {
        int col = (cg << 3) + j;
        if (col < 49) v[j] = (short)tgb[r * 49 + col];
      }
    }
    *(bf16x8*)&Abuf[(r << 6) + (SWZ8(cg, r) << 3)] = v;
  }
  for (int gid = tid; gid < 1024; gid += 256) {
    int kg = gid >> 7, c = gid & 127;
    bf16x8 v = (bf16x8)0;
    #pragma unroll
    for (int j = 0; j < 8; ++j) {
      int k = (kg << 3) + j;
      if (k < 49) v[j] = (short)me[k * 128 + c];
    }
    *(bf16x8*)&Bsh[(c << 6) + (SWZ8(kg, c) << 3)] = v;
  }
  {
    int c = tid >> 1, gg = 14 + (tid & 1);
    *(bf16x8*)&Ps[(c << 7) + (SWZ16(gg, c) << 3)] = (bf16x8)0;
  }
  __syncthreads();

  {
    f32x4 acc[7][2];
    #pragma unroll
    for (int i = 0; i < 7; ++i) { acc[i][0] = (f32x4){0,0,0,0}; acc[i][1] = (f32x4){0,0,0,0}; }
    #pragma unroll
    for (int k0 = 0; k0 < 64; k0 += 32) {
      int cg = (k0 + fk) >> 3;
      int br0 = ((2 * wv) << 4) + fr, br1 = ((2 * wv + 1) << 4) + fr;
      bf16x8 bf0 = *(const bf16x8*)&Bsh[(br0 << 6) + (SWZ8(cg, br0) << 3)];
      bf16x8 bf1 = *(const bf16x8*)&Bsh[(br1 << 6) + (SWZ8(cg, br1) << 3)];
      #pragma unroll
      for (int rt = 0; rt < 7; ++rt) {
        int ar = (rt << 4) + fr;
        bf16x8 af = *(const bf16x8*)&Abuf[(ar << 6) + (SWZ8(cg, ar) << 3)];
        acc[rt][0] = __builtin_amdgcn_mfma_f32_16x16x32_bf16(af, bf0, acc[rt][0], 0, 0, 0);
        acc[rt][1] = __builtin_amdgcn_mfma_f32_16x16x32_bf16(af, bf1, acc[rt][1], 0, 0, 0);
      }
    }
    #pragma unroll
    for (int rt = 0; rt < 7; ++rt)
      #pragma unroll
      for (int cj = 0; cj < 2; ++cj) {
        int c = ((2 * wv + cj) << 4) + ccl;
        #pragma unroll
        for (int r = 0; r < 4; ++r) {
          int g = (rt << 4) + crl + r;
          Ps[(c << 7) + (SWZ16(g >> 3, c) << 3) + (g & 7)] =
              (short)f2bf(siluf(acc[rt][cj][r]));
        }
      }
  }
  __syncthreads();
  for (int gid = tid; gid < 1024; gid += 256) {
    int r = gid >> 4, cg = gid & 15;
    bf16x8 v = (bf16x8)0;
    if (r < 49) {
      #pragma unroll
      for (int j = 0; j < 8; ++j) {
        int col = (cg << 3) + j;
        if (col < 98) v[j] = (short)fgb[r * 98 + col];
      }
    }
    *(bf16x8*)&Abuf[(r << 7) + (SWZ16(cg, r) << 3)] = v;
  }
  __syncthreads();

  {
    f32x4 acc[4][2];
    #pragma unroll
    for (int i = 0; i < 4; ++i) { acc[i][0] = (f32x4){0,0,0,0}; acc[i][1] = (f32x4){0,0,0,0}; }
    #pragma unroll
    for (int k0 = 0; k0 < 128; k0 += 32) {
      int cg = (k0 + fk) >> 3;
      int br0 = ((2 * wv) << 4) + fr, br1 = ((2 * wv + 1) << 4) + fr;
      bf16x8 bf0 = *(const bf16x8*)&Ps[(br0 << 7) + (SWZ16(cg, br0) << 3)];
      bf16x8 bf1 = *(const bf16x8*)&Ps[(br1 << 7) + (SWZ16(cg, br1) << 3)];
      #pragma unroll
      for (int rt = 0; rt < 4; ++rt) {
        int ar = (rt << 4) + fr;
        bf16x8 af = *(const bf16x8*)&Abuf[(ar << 7) + (SWZ16(cg, ar) << 3)];
        acc[rt][0] = __builtin_amdgcn_mfma_f32_16x16x32_bf16(af, bf0, acc[rt][0], 0, 0, 0);
        acc[rt][1] = __builtin_amdgcn_mfma_f32_16x16x32_bf16(af, bf1, acc[rt][1], 0, 0, 0);
      }
    }
    #pragma unroll
    for (int rt = 0; rt < 4; ++rt)
      #pragma unroll
      for (int cj = 0; cj < 2; ++cj) {
        int c = ((2 * wv + cj) << 4) + ccl;
        #pragma unroll
        for (int r = 0; r < 4; ++r) {
          int q = (rt << 4) + crl + r;
          Bsh[(c << 6) + (SWZ8(q >> 3, c) << 3) + (q & 7)] = (short)f2bf(acc[rt][cj][r]);
        }
      }
  }
  __syncthreads();
  {
    const float* we = wigv + (long long)e * 2401;
    for (int gid = tid; gid < 512; gid += 256) {
      int r = gid >> 3, cg = gid & 7;
      bf16x8 v = (bf16x8)0;
      if (r < 49) {
        #pragma unroll
        for (int j = 0; j < 8; ++j) {
          int col = (cg << 3) + j;
          if (col < 49) v[j] = (short)f2bf(we[r * 49 + col]);
        }
      }
      *(bf16x8*)&Abuf[(r << 6) + (SWZ8(cg, r) << 3)] = v;
    }
  }
  __syncthreads();

  {
    f32x4 acc[4][2];
    #pragma unroll
    for (int i = 0; i < 4; ++i) { acc[i][0] = (f32x4){0,0,0,0}; acc[i][1] = (f32x4){0,0,0,0}; }
    #pragma unroll
    for (int k0 = 0; k0 < 64; k0 += 32) {
      int cg = (k0 + fk) >> 3;
      int br0 = ((2 * wv) << 4) + fr, br1 = ((2 * wv + 1) << 4) + fr;
      bf16x8 bf0 = *(const bf16x8*)&Bsh[(br0 << 6) + (SWZ8(cg, br0) << 3)];
      bf16x8 bf1 = *(const bf16x8*)&Bsh[(br1 << 6) + (SWZ8(cg, br1) << 3)];
      #pragma unroll
      for (int rt = 0; rt < 4; ++rt) {
        int ar = (rt << 4) + fr;
        bf16x8 af = *(const bf16x8*)&Abuf[(ar << 6) + (SWZ8(cg, ar) << 3)];
        acc[rt][0] = __builtin_amdgcn_mfma_f32_16x16x32_bf16(af, bf0, acc[rt][0], 0, 0, 0);
        acc[rt][1] = __builtin_amdgcn_mfma_f32_16x16x32_bf16(af, bf1, acc[rt][1], 0, 0, 0);
      }
    }
    #pragma unroll
    for (int rt = 0; rt < 4; ++rt)
      #pragma unroll
      for (int r = 0; r < 4; ++r) {
        int gi = (rt << 4) + crl + r;
        if (gi < 49) {
          #pragma unroll
          for (int cj = 0; cj < 2; ++cj) {
            int c = ((2 * wv + cj) << 4) + ccl;
            Ps[(gi << 7) + (((c >> 3) ^ (gi & 15)) << 3) + (c & 7)] =
                (short)f2bf(acc[rt][cj][r]);
          }
        }
      }
    __syncthreads();
    ushort_t* oe = msg3 + (long long)e * 6272;
    for (int gid = tid; gid < 784; gid += 256) {
      int row = gid >> 4, cc = gid & 15;
      bf16x8 v = *(const bf16x8*)&Ps[(row << 7) + ((cc ^ (row & 15)) << 3)];
      *(bf16x8*)&oe[(row << 7) + (cc << 3)] = v;
    }
  }
}

// ---------------------------------------------------------------------------
// Segment-sum via per-atom edge lists (vectorized bf16x8 gather)
// ---------------------------------------------------------------------------
__global__ __launch_bounds__(256) void k_zeroi(int* __restrict__ p, int n) {
  int id = blockIdx.x * 256 + threadIdx.x;
  if (id < n) p[id] = 0;
}

__global__ __launch_bounds__(256) void k_deg(
    const int* __restrict__ tgt, int* __restrict__ deg) {
  int e = blockIdx.x * 256 + threadIdx.x;
  if (e < EN) atomicAdd(&deg[tgt[e]], 1);
}

__global__ __launch_bounds__(1024) void k_prefix(
    const int* __restrict__ deg, int* __restrict__ base) {
  __shared__ int s[1024];
  int t = threadIdx.x;
  s[t] = (t < AN) ? deg[t] : 0;
  __syncthreads();
  for (int ofs = 1; ofs < 1024; ofs <<= 1) {
    int u = (t >= ofs) ? s[t - ofs] : 0;
    __syncthreads();
    s[t] += u;
    __syncthreads();
  }
  if (t < AN) base[t + 1] = s[t];
  if (t == 0) base[0] = 0;
}

__global__ __launch_bounds__(256) void k_fill(
    const int* __restrict__ tgt, const int* __restrict__ base,
    int* __restrict__ list) {
  const int a = blockIdx.x, t = threadIdx.x;
  const int lane = t & 63, w = t >> 6;
  __shared__ int wtot[4];
  __shared__ int runbase;
  if (t == 0) runbase = base[a];
  __syncthreads();
  for (int i0 = 0; i0 < EN; i0 += 256) {
    int e = i0 + t;
    bool m = (e < EN) && (tgt[e] == a);
    unsigned long long bal = __ballot(m);
    if (lane == 0) wtot[w] = __popcll(bal);
    __syncthreads();
    int wbase = 0;
    for (int j = 0; j < w; ++j) wbase += wtot[j];
    int tot = wtot[0] + wtot[1] + wtot[2] + wtot[3];
    if (m) {
      int off = __popcll(bal & ((1ull << lane) - 1ull));
      list[runbase + wbase + off] = e;
    }
    __syncthreads();
    if (t == 0) runbase += tot;
    __syncthreads();
  }
}

__global__ __launch_bounds__(256) void k_gather4(
    const ushort_t* __restrict__ msg3, const int* __restrict__ base,
    const int* __restrict__ list, float* __restrict__ xmsg,
    int e0, int ce, int accum)
{
  const int a = blockIdx.x, part = blockIdx.y, t = threadIdx.x;
  if (t >= 196) return;
  const int b0 = base[a], b1 = base[a + 1];
  const int co = part * 1568 + t * 8;
  float a8[8];
  #pragma unroll
  for (int u = 0; u < 8; ++u) a8[u] = 0.f;
  for (int i = b0; i < b1; ++i) {
    int e = list[i];
    if (e < e0 || e >= e0 + ce) continue;
    bf16x8 v = *(const bf16x8*)&msg3[(long long)(e - e0) * 6272 + co];
    #pragma unroll
    for (int u = 0; u < 8; ++u) a8[u] += bf2f((ushort_t)v[u]);
  }
  float* o = xmsg + (long long)a * 6272 + co;
  if (accum) {
    #pragma unroll
    for (int u = 0; u < 8; ++u) o[u] += a8[u];
  } else {
    float4 lo = make_float4(a8[0], a8[1], a8[2], a8[3]);
    float4 hi = make_float4(a8[4], a8[5], a8[6], a8[7]);
    *(float4*)o = lo;
    *(float4*)(o + 4) = hi;
  }
}

// ---------------------------------------------------------------------------
// Host orchestration
// ---------------------------------------------------------------------------
extern "C" void kernel_launch(void* const* d_in, const int* in_sizes, int n_in,
                              void* d_out, int out_size, void* d_ws, size_t ws_size,
                              hipStream_t stream) {
  const float* x         = (const float*)d_in[0];
  const float* edist     = (const float*)d_in[1];
  const float* wigner    = (const float*)d_in[2];
  const float* wiginv    = (const float*)d_in[3];
  const float* to_grid   = (const float*)d_in[4];
  const float* from_grid = (const float*)d_in[5];
  const float* w_dist1   = (const float*)d_in[6];
  const float* b_dist1   = (const float*)d_in[7];
  const float* src_emb   = (const float*)d_in[8];
  const float* tgt_emb   = (const float*)d_in[9];
  const float* w_edge1   = (const float*)d_in[10];
  const float* b_edge1   = (const float*)d_in[11];
  const float* ws1       = (const float*)d_in[12];
  const float* bs1       = (const float*)d_in[13];
  const float* ws2       = (const float*)d_in[14];
  const float* bs2       = (const float*)d_in[15];
  const float* ws3       = (const float*)d_in[16];
  const float* bs3       = (const float*)d_in[17];
  const int*   anum      = (const int*)d_in[18];
  const int*   eidx      = (const int*)d_in[19];
  const float* sw[10]; const float* tw[10];
  for (int i = 0; i < 10; ++i) {
    sw[i] = (const float*)d_in[20 + i];
    tw[i] = (const float*)d_in[30 + i];
  }
  float* outp = (float*)d_out;

  // ---- workspace ----
  char* wsb = (char*)d_ws;
  size_t off = 0;
  auto alloc = [&](long long nbytes) {
    char* p = wsb + off; off += (size_t)((nbytes + 63) & ~63LL); return p;
  };
  ushort_t* x_edge  = (ushort_t*)alloc((8000LL + 128) * 128 * 2);
  ushort_t* b2ab    = (ushort_t*)alloc(5505024LL * 2);
  ushort_t* bgcw    = (ushort_t*)alloc(851968LL * 2);
  float*    bgcb    = (float*)alloc(6656 * 4);
  ushort_t* b20b    = (ushort_t*)alloc(458752LL * 2);
  ushort_t* s1m0b   = (ushort_t*)alloc(458752LL * 2);
  ushort_t* s1mb    = (ushort_t*)alloc(2752512LL * 2);
  ushort_t* wd1b    = (ushort_t*)alloc(65536 * 2);
  ushort_t* we1b    = (ushort_t*)alloc(16384 * 2);
  ushort_t* ws1b    = (ushort_t*)alloc(32768 * 2);
  ushort_t* ws2b    = (ushort_t*)alloc(16384 * 2);
  ushort_t* ws3b    = (ushort_t*)alloc(16384 * 2);
  ushort_t* tgb     = (ushort_t*)alloc(4802 * 2);
  ushort_t* fgb     = (ushort_t*)alloc(4802 * 2);
  float*    xmsg    = (float*)alloc(5017600LL * 4);
  ushort_t* xmsgb   = (ushort_t*)alloc((5017600LL + 16384) * 2);
  ushort_t* xb      = (ushort_t*)alloc((5017600LL + 16384) * 2);
  ushort_t* xbT     = (ushort_t*)alloc(6553600LL * 2);
  ushort_t* basis   = (ushort_t*)alloc((8000LL + 128) * 512 * 2);
  float*    x_dist  = (float*)alloc(1024000LL * 4);
  ushort_t* x_distb = (ushort_t*)alloc((8000LL + 128) * 128 * 2);
  int*      deg     = (int*)alloc(800 * 4);
  int*      sbase   = (int*)alloc(801 * 4);
  int*      elist   = (int*)alloc(8000 * 4);
  const size_t fixedB = off;
  char* arena = wsb + off;

  static const int ces[6] = {8000, 4000, 2000, 1000, 500, 250};
  static const int cas[6] = {800, 800, 800, 400, 200, 100};
  int ce = 250, ca = 100;
  for (int i = 0; i < 6; ++i) {
    long long ne = (long long)ces[i] * 76544 + 64LL * 50688;
    long long na = (long long)cas[i] * 87808 + 64LL * 512;
    long long need = (long long)fixedB + (ne > na ? ne : na);
    if (need <= (long long)ws_size) { ce = ces[i]; ca = cas[i]; break; }
  }

  // edge-phase arena (padded A-sources)
  char* ap = arena;
  ushort_t* xrot_s = (ushort_t*)ap;  ap += (long long)(ce + 64) * 12544;
  ushort_t* xrot_t = (ushort_t*)ap;  ap += (long long)(ce + 64) * 12544;
  ushort_t* tb0    = (ushort_t*)ap;  ap += (long long)(ce + 64) * 1024;
  ushort_t* tbm    = (ushort_t*)ap;  ap += (long long)(ce + 64) * 24576;
  ushort_t* msgp   = (ushort_t*)ap;  ap += (long long)ce * 12544;
  ushort_t* gate   = (ushort_t*)ap;  // ce x 6656 bf16
  ushort_t* msg3   = (ushort_t*)arena;
  // atom-phase arena
  char* bp = arena;
  ushort_t* hb = (ushort_t*)bp;  bp += (long long)ca * 49 * 256;
  ushort_t* g1 = (ushort_t*)bp;  bp += ((long long)ca * 98 + 64) * 256;
  ushort_t* g2 = (ushort_t*)bp;  bp += ((long long)ca * 98 + 64) * 256;
  ushort_t* g3 = (ushort_t*)bp;

  long long ofs2[7][2], s1ofs[7][2];
  { long long cur = 0, cur1 = 0;
    for (int m = 1; m <= 6; ++m) {
      int k = (7 - m) * 128;
      ofs2[m][0] = cur; cur += (long long)k * 1024;
      ofs2[m][1] = cur; cur += (long long)k * 1024;
      s1ofs[m][0] = cur1; cur1 += 512LL * k;
      s1ofs[m][1] = cur1; cur1 += 512LL * k;
    } }

  auto D0 = []() { GemmP p; memset(&p, 0, sizeof(p)); p.asplit = 1 << 30; p.gse = 6656; return p; };
  auto finalize = [&](Grouped& G) {
    int base = 0;
    for (int i = 0; i < G.nd; ++i) {
      GemmP& p = G.d[i];
      p.ngx = (p.M + 127) >> 7;
      p.ngy = (p.N + 127) >> 7;
      p.wg_base = base;
      base += p.ngx * p.ngy;
    }
    G.nwg = base;
    gemm_g<<<base, 256, 0, stream>>>(G);
  };
  auto run1 = [&](GemmP p) { Grouped G; G.d[0] = p; G.nd = 1; finalize(G); };
  auto rungrid = [&](const float* A, int M, int K, int permA,
                     const ushort_t* B, int b_ib, void* C, int c_ib,
                     const float* bias, int act, int c_bf16, int nb) {
    GridP p;
    p.A = A; p.B = B; p.C = C; p.bias = bias;
    p.b_ib = b_ib; p.c_ib = c_ib;
    p.M = M; p.K = K; p.permA = permA; p.act = act; p.c_bf16 = c_bf16;
    gridmm<<<nb, 256, 0, stream>>>(p);
  };

  // 0) builds
  k_build_b2b<<<(5505024 + 255) / 256, 256, 0, stream>>>(sw[7], sw[9], tw[7], tw[9], b2ab);
  k_build_bgcat<<<(858624 + 255) / 256, 256, 0, stream>>>(
      sw[0], tw[0], sw[4], tw[4], sw[1], tw[1], sw[5], tw[5], bgcw, bgcb);
  k_build_b20b<<<(458752 + 255) / 256, 256, 0, stream>>>(sw[3], tw[3], b20b);
  k_build_s1m<<<(2752512 + 255) / 256, 256, 0, stream>>>(sw[6], sw[8], tw[6], tw[8], s1mb);
  { // merged conversions
    CvtM P;
    const float* ss[9] = { sw[2], tw[2], w_dist1, w_edge1, ws1, ws2, ws3, from_grid, x };
    ushort_t* dd[9] = { s1m0b, s1m0b + 229376, wd1b, we1b, ws1b, ws2b, ws3b, fgb, xb };
    long long nn[9] = { 229376, 229376, 65536, 16384, 32768, 16384, 16384, 4802, 5017600 };
    long long cur = 0;
    for (int i = 0; i < 9; ++i) { P.s[i] = ss[i]; P.d[i] = dd[i]; P.start[i] = cur; cur += nn[i]; }
    P.start[9] = cur;
    k_cvt_multi<<<(int)((cur + 255) / 256), 256, 0, stream>>>(P);
  }
  k_build_tg<<<(4802 + 255) / 256, 256, 0, stream>>>(to_grid, tgb);
  k_xT<<<AN, 256, 0, stream>>>(x, xbT);

  // scatter lists
  k_zeroi<<<4, 256, 0, stream>>>(deg, 800);
  k_deg<<<(EN + 255) / 256, 256, 0, stream>>>(eidx + EN, deg);
  k_prefix<<<1, 1024, 0, stream>>>(deg, sbase);
  k_fill<<<AN, 256, 0, stream>>>(eidx + EN, sbase, elist);

  // 1) edge features
  k_basis<<<(EN * 512 + 255) / 256, 256, 0, stream>>>(edist, basis);
  { GemmP p = D0();
    p.A = basis; p.a_se = 512; p.B = wd1b; p.ldb = 512; p.bias = b_dist1;
    p.C = x_dist; p.c_se = 128; p.M = EN; p.N = 128; p.K = 512;
    run1(p); }
  k_emb<<<(EN * 128 + 255) / 256, 256, 0, stream>>>(src_emb, tgt_emb, anum, eidx,
                                                    x_dist, x_distb);
  { GemmP p = D0();
    p.A = x_distb; p.a_se = 128; p.B = we1b; p.ldb = 128; p.bias = b_edge1;
    p.act = 1; p.C = x_edge; p.c_se = 128; p.c_bf16 = 1;
    p.M = EN; p.N = 128; p.K = 128;
    run1(p); }

  static const int offq[7] = {0, 7, 19, 29, 37, 43, 47};

  // 2) edge chunks
  for (int e0 = 0; e0 < EN; e0 += ce) {
    const int c = ce;
    k_rot2<<<c, 256, 0, stream>>>(wigner + (long long)e0 * 2401, xbT,
                                  eidx + e0, eidx + EN + e0, xrot_s, xrot_t);
    // gates (N=6656)
    { GemmP p = D0();
      p.A = x_edge + (long long)e0 * 128; p.a_se = 128;
      p.B = bgcw; p.ldb = 128; p.bias = bgcb; p.act = 1;
      p.C = gate; p.c_se = 6656; p.c_bf16 = 1;
      p.M = c; p.N = 6656; p.K = 128;
      run1(p); }
    // stage 1 grouped
    { Grouped G; G.nd = 14;
      for (int s = 0; s < 2; ++s) {
        GemmP p = D0();
        p.A = s ? xrot_t : xrot_s; p.a_se = 6272;
        p.B = s1m0b + (long long)s * 229376; p.ldb = 896;
        p.gate = gate; p.gate_ofs = s * 256;
        p.C = tb0; p.c_se = 512; p.c_ofs = s * 256; p.c_bf16 = 1;
        p.M = c; p.N = 256; p.K = 896;
        G.d[s] = p;
      }
      int di = 2;
      for (int m = 1; m <= 6; ++m) {
        const int k = (7 - m) * 128, off2 = offq[m];
        for (int s = 0; s < 2; ++s) {
          GemmP p = D0();
          p.A = (s ? xrot_t : xrot_s) + off2 * 128;
          p.a_se = 6272; p.a_si = k; p.pair = 1;
          p.B = s1mb + s1ofs[m][s]; p.ldb = k;
          p.gate = gate; p.gate_ofs = 512 + (m - 1) * 1024 + s * 512;
          p.C = tbm; p.c_se = 12288; p.c_si = 1024;
          p.c_ofs = (m - 1) * 2048 + s * 512;
          p.ihalf = 1; p.c_bf16 = 1;
          p.M = 2 * c; p.N = 512; p.K = k;
          G.d[di++] = p;
        }
      }
      finalize(G); }
    // stage 2 grouped
    { Grouped G; G.nd = 13;
      { GemmP p = D0();
        p.A = tb0; p.a_se = 512;
        p.B = b20b; p.ldb = 512;
        p.C = msgp; p.c_se = 6272; p.c_bf16 = 1;
        p.M = c; p.N = 896; p.K = 512;
        G.d[0] = p; }
      int di = 1;
      for (int m = 1; m <= 6; ++m) {
        const int n = 7 - m, k = n * 128, off2 = offq[m];
        for (int pp = 0; pp < 2; ++pp) {
          GemmP p = D0();
          p.A = tbm + (m - 1) * 2048 + pp * 1024; p.a_se = 12288;
          p.B = b2ab + ofs2[m][pp]; p.ldb = 1024;
          p.C = msgp; p.c_se = 6272; p.c_ofs = (off2 + (pp ? n : 0)) * 128; p.c_bf16 = 1;
          p.M = c; p.N = k; p.K = 1024;
          G.d[di++] = p;
        }
      }
      finalize(G); }
    // fused grid pipeline + gather
    k_grid<<<c, 256, 0, stream>>>(tgb, fgb, wiginv + (long long)e0 * 2401, msgp, msg3);
    k_gather4<<<dim3(AN, 4), 256, 0, stream>>>(msg3, sbase, elist, xmsg, e0, c, e0 > 0);
  }

  // xmsg -> bf16 for atom GEMM
  k_cvt<<<(5017600 + 255) / 256, 256, 0, stream>>>(xmsg, xmsgb, 5017600);

  // 3) atom phase
  for (int a0 = 0; a0 < AN; a0 += ca) {
    { GemmP p = D0();
      p.A = xb + (long long)a0 * 6272; p.A2 = xmsgb + (long long)a0 * 6272;
      p.a_se = 128; p.asplit = 128;
      p.B = ws1b; p.ldb = 256;
      p.C = hb; p.c_se = 128; p.c_bf16 = 1;
      p.M = ca * 49; p.N = 128; p.K = 256;
      run1(p); }
    rungrid(to_grid, 98, 49, 0, hb, 6272, g1, 12544, bs1, 1, 1, ca);
    { GemmP p = D0();
      p.A = g1; p.a_se = 128;
      p.B = ws2b; p.ldb = 128; p.bias = bs2; p.act = 1;
      p.C = g2; p.c_se = 128; p.c_bf16 = 1;
      p.M = ca * 98; p.N = 128; p.K = 128;
      run1(p); }
    { GemmP p = D0();
      p.A = g2; p.a_se = 128;
      p.B = ws3b; p.ldb = 128; p.bias = bs3;
      p.C = g3; p.c_se = 128; p.c_bf16 = 1;
      p.M = ca * 98; p.N = 128; p.K = 128;
      run1(p); }
    rungrid(from_grid, 49, 98, 0, g3, 12544, outp + (long long)a0 * 6272, 6272,
            nullptr, 0, 0, ca);
  }
}

// Round 12
// 1585.067 us; speedup vs baseline: 1.4759x; 1.0061x over previous
//
#include <hip/hip_runtime.h>
#include <string.h>

#define EN 8000
#define AN 800

typedef __attribute__((ext_vector_type(8))) short bf16x8;
typedef __attribute__((ext_vector_type(4))) float f32x4;
typedef unsigned short ushort_t;
typedef unsigned int uint32;

__constant__ int c_perm[49] = {
  0,2,6,12,20,30,42,
  1,5,11,19,29,41,
  3,7,13,21,31,43,
  4,10,18,28,40,
  8,14,22,32,44,
  9,17,27,39,
  15,23,33,45,
  16,26,38,
  24,34,46,
  25,37,
  35,47,
  36,
  48
};

__device__ __forceinline__ float siluf(float x) { return x / (1.0f + __expf(-x)); }
__device__ __forceinline__ ushort_t f2bf(float f) {
  uint32 u = __float_as_uint(f);
  u += 0x7fff + ((u >> 16) & 1);
  return (ushort_t)(u >> 16);
}
__device__ __forceinline__ float bf2f(ushort_t h) {
  return __uint_as_float(((uint32)h) << 16);
}
__device__ __forceinline__ void gld16(const void* g, void* l) {
  __builtin_amdgcn_global_load_lds(
      (const __attribute__((address_space(1))) void*)g,
      (__attribute__((address_space(3))) void*)l, 16, 0, 0);
}

// ---------------------------------------------------------------------------
// Merged weight builder: all bf16 weight-concats in ONE launch.
// segments: [0,S0) b2a | [S0,S1) bgcat | [S1,S2) b20 | [S2,S3) s1m | [S3,S4) tg
// ---------------------------------------------------------------------------
#define BSEG0 5505024LL
#define BSEG1 6363648LL   // +858624 (851968 w + 6656 b)
#define BSEG2 6822400LL   // +458752
#define BSEG3 9574912LL   // +2752512
#define BSEG4 9579714LL   // +4802

struct BuildP {
  const float *sw7, *sw9, *tw7, *tw9;
  const float *sw0, *tw0, *sw4, *tw4, *sb1, *tb1, *sbd, *tbd;
  const float *sw3, *tw3;
  const float *sw6, *sw8, *tw6, *tw8;
  const float *tg;
  ushort_t *b2ab, *bgcw, *b20b, *s1mb, *tgb;
  float *bgcb;
};

__global__ __launch_bounds__(256) void k_build_all(BuildP P) {
  long long id = (long long)blockIdx.x * 256 + threadIdx.x;
  if (id >= BSEG4) return;
  if (id < BSEG0) {
    // b2a: per-m per-parity stage2 weights with sign folding
    long long base = 0; int m = 1, k = 768;
    for (; m <= 6; ++m) {
      k = (7 - m) * 128;
      long long sz = 2LL * k * 1024;
      if (id < base + sz) break;
      base += sz;
    }
    long long rem = id - base;
    int p = (int)(rem / ((long long)k * 1024));
    int cj = (int)(rem - (long long)p * k * 1024);
    int c = cj >> 10, j = cj & 1023;
    int q = j >> 8, jj = j & 255;
    const float sgn = (q & 1) ? (p ? 1.f : -1.f) : 1.f;
    const float* src = (q < 2) ? (q == 0 ? P.sw7 : P.sw9) : (q == 2 ? P.tw7 : P.tw9);
    P.b2ab[id] = f2bf(sgn * src[(long long)(m - 1) * 196608 + c * 256 + jj]);
    return;
  }
  if (id < BSEG1) {
    int id2 = (int)(id - BSEG0);
    if (id2 < 851968) {
      int r = id2 >> 7, c = id2 & 127;
      float v;
      if (r < 256) v = P.sw0[r * 128 + c];
      else if (r < 512) v = P.tw0[(r - 256) * 128 + c];
      else {
        int rr = r - 512, m = rr >> 10, q = rr & 1023;
        v = (q < 512) ? P.sw4[m * 65536 + q * 128 + c]
                      : P.tw4[m * 65536 + (q - 512) * 128 + c];
      }
      P.bgcw[id2] = f2bf(v);
    } else {
      int ib = id2 - 851968;
      float v;
      if (ib < 256) v = P.sb1[ib];
      else if (ib < 512) v = P.tb1[ib - 256];
      else {
        int rr = ib - 512, m = rr >> 10, q = rr & 1023;
        v = (q < 512) ? P.sbd[m * 512 + q] : P.tbd[m * 512 + (q - 512)];
      }
      P.bgcb[ib] = v;
    }
    return;
  }
  if (id < BSEG2) {
    int id2 = (int)(id - BSEG1);
    int cc = id2 >> 9, j = id2 & 511;
    P.b20b[id2] = f2bf((j < 256) ? P.sw3[cc * 256 + j] : P.tw3[cc * 256 + (j - 256)]);
    return;
  }
  if (id < BSEG3) {
    long long id2 = id - BSEG2;
    long long base = 0; int m = 1, k = 768;
    for (; m <= 6; ++m) {
      k = (7 - m) * 128;
      long long sz = 1024LL * k;
      if (id2 < base + sz) break;
      base += sz;
    }
    long long rem = id2 - base;
    int s = (int)(rem / (512LL * k));
    int rr = (int)(rem - (long long)s * 512 * k);
    int r = rr / k, c = rr - r * k;
    const float* src = (r < 256) ? (s ? P.tw6 : P.sw6) : (s ? P.tw8 : P.sw8);
    int r0 = (r < 256) ? r : r - 256;
    P.s1mb[id2] = f2bf(src[(long long)(m - 1) * 196608 + r0 * 768 + c]);
    return;
  }
  {
    int id2 = (int)(id - BSEG3);
    int r = id2 / 49, s = id2 - r * 49;
    P.tgb[id2] = f2bf(P.tg[r * 49 + c_perm[s]]);
  }
}

// merged f32->bf16 conversions (up to 9 segments)
struct CvtM {
  const float* s[9];
  ushort_t* d[9];
  long long start[10];
};
__global__ __launch_bounds__(256) void k_cvt_multi(CvtM P) {
  long long id = (long long)blockIdx.x * 256 + threadIdx.x;
  if (id >= P.start[9]) return;
  int seg = 0;
  #pragma unroll
  for (int i = 1; i < 9; ++i) if (id >= P.start[i]) seg = i;
  long long o = id - P.start[seg];
  P.d[seg][o] = f2bf(P.s[seg][o]);
}

__global__ __launch_bounds__(256) void k_cvt(
    const float* __restrict__ src, ushort_t* __restrict__ dst, int n)
{
  int id = blockIdx.x * 256 + threadIdx.x;
  if (id < n) dst[id] = f2bf(src[id]);
}

// transpose x (f32 [49][128]) -> xbT (bf16 [128][64], j-padded)
__global__ __launch_bounds__(256) void k_xT(
    const float* __restrict__ x, ushort_t* __restrict__ xbT)
{
  __shared__ __align__(16) float xs[49 * 128];
  const int a = blockIdx.x, t = threadIdx.x;
  const float4* src = (const float4*)(x + (long long)a * 6272);
  float4* d = (float4*)xs;
  for (int i = t; i < 1568; i += 256) d[i] = src[i];
  __syncthreads();
  ushort_t* o = xbT + (long long)a * 8192;
  int c = t >> 1;
  int jg = (t & 1) << 2;
  #pragma unroll
  for (int u = 0; u < 4; ++u) {
    int g = jg + u;
    bf16x8 v = (bf16x8)0;
    #pragma unroll
    for (int j = 0; j < 8; ++j) {
      int jj = (g << 3) + j;
      if (jj < 49) v[j] = (short)f2bf(xs[jj * 128 + c]);
    }
    *(bf16x8*)&o[(c << 6) + (g << 3)] = v;
  }
}

// ---------------------------------------------------------------------------
// Edge features
// ---------------------------------------------------------------------------
__global__ __launch_bounds__(256) void k_basis(
    const float* __restrict__ dist, ushort_t* __restrict__ basis)
{
  int id = blockIdx.x * 256 + threadIdx.x;
  if (id >= EN * 512) return;
  int e = id >> 9, g = id & 511;
  const float step = 8.0f / 511.0f;
  const float coeff = -2040.0078125f;
  float df = dist[e] - (float)g * step;
  basis[id] = f2bf(expf(coeff * df * df));
}

__global__ __launch_bounds__(256) void k_emb(
    const float* __restrict__ src_emb, const float* __restrict__ tgt_emb,
    const int* __restrict__ anum, const int* __restrict__ eidx,
    const float* __restrict__ xd, ushort_t* __restrict__ out)
{
  int id = blockIdx.x * 256 + threadIdx.x;
  if (id >= EN * 128) return;
  int e = id >> 7, c = id & 127;
  int a0 = anum[eidx[e]], a1 = anum[eidx[EN + e]];
  out[id] = f2bf(siluf(src_emb[a0 * 128 + c] + tgt_emb[a1 * 128 + c] + xd[id]));
}

// ---------------------------------------------------------------------------
// MFMA Wigner rotation with coalesced (repacked) output
// ---------------------------------------------------------------------------
__global__ __launch_bounds__(256) void k_rot2(
    const float* __restrict__ wig, const ushort_t* __restrict__ xbT,
    const int* __restrict__ srcl, const int* __restrict__ tgtl,
    ushort_t* __restrict__ osrc, ushort_t* __restrict__ otgt)
{
  __shared__ short Ws[4096];
  __shared__ short Xs[8192];
  __shared__ short Xt[8192];
  const int e = blockIdx.x, tid = threadIdx.x;
  const int lane = tid & 63, wave = tid >> 6;
  const float* wge = wig + (long long)e * 2401;
  #pragma unroll
  for (int t = 0; t < 2; ++t) {
    int ci = (t << 8) + tid;
    int row = ci >> 3, g = ci & 7;
    bf16x8 v = (bf16x8)0;
    if (row < 49) {
      const float* wr = wge + c_perm[row] * 49;
      #pragma unroll
      for (int j = 0; j < 8; ++j) {
        int col = (g << 3) + j;
        if (col < 49) v[j] = (short)f2bf(wr[col]);
      }
    }
    *(bf16x8*)&Ws[(row << 6) + ((g ^ (row & 7)) << 3)] = v;
  }
  const int as = srcl[e], at = tgtl[e];
  const ushort_t* xsg = xbT + (long long)as * 8192;
  const ushort_t* xtg = xbT + (long long)at * 8192;
  #pragma unroll
  for (int t = 0; t < 4; ++t) {
    int ci = (t << 8) + tid;
    int row = ci >> 3, g = ci & 7;
    int ofs = (row << 6) + ((g ^ (row & 7)) << 3);
    *(bf16x8*)&Xs[ofs] = *(const bf16x8*)&xsg[ci << 3];
    *(bf16x8*)&Xt[ofs] = *(const bf16x8*)&xtg[ci << 3];
  }
  __syncthreads();
  const short* Xb = (wave >> 1) ? Xt : Xs;
  const int ch = (wave & 1) << 6;
  const int fr = lane & 15, g = lane >> 4;
  f32x4 acc[4][4];
  #pragma unroll
  for (int i = 0; i < 4; ++i)
    #pragma unroll
    for (int j = 0; j < 4; ++j) acc[i][j] = (f32x4){0.f, 0.f, 0.f, 0.f};
  #pragma unroll
  for (int ks = 0; ks < 2; ++ks) {
    bf16x8 af[4], bfv[4];
    int lc = (ks << 2) + g;
    #pragma unroll
    for (int i = 0; i < 4; ++i) {
      int ra = (i << 4) + fr;
      af[i] = *(const bf16x8*)&Ws[(ra << 6) + ((lc ^ (ra & 7)) << 3)];
      int rb = ch + (i << 4) + fr;
      bfv[i] = *(const bf16x8*)&Xb[(rb << 6) + ((lc ^ (rb & 7)) << 3)];
    }
    #pragma unroll
    for (int i = 0; i < 4; ++i)
      #pragma unroll
      for (int j = 0; j < 4; ++j)
        acc[i][j] = __builtin_amdgcn_mfma_f32_16x16x32_bf16(af[i], bfv[j], acc[i][j], 0, 0, 0);
  }
  const int crl = (lane >> 4) << 2, ccl = lane & 15;
  __syncthreads();
  short* Ob = (wave >> 1) ? Xt : Xs;
  #pragma unroll
  for (int i = 0; i < 4; ++i)
    #pragma unroll
    for (int r = 0; r < 4; ++r) {
      int q = (i << 4) + crl + r;
      if (q < 49) {
        #pragma unroll
        for (int j = 0; j < 4; ++j) {
          int col = ch + (j << 4) + ccl;
          Ob[(q << 7) + (((col >> 3) ^ (q & 15)) << 3) + (col & 7)] =
              (short)f2bf(acc[i][j][r]);
        }
      }
    }
  __syncthreads();
  for (int gid = tid; gid < 1568; gid += 256) {
    int half = gid >= 784;
    int c784 = half ? gid - 784 : gid;
    int row = c784 >> 4, cc = c784 & 15;
    const short* Sb = half ? Xt : Xs;
    bf16x8 v = *(const bf16x8*)&Sb[(row << 7) + ((cc ^ (row & 15)) << 3)];
    ushort_t* dst = (half ? otgt : osrc) + (long long)e * 6272 + (row << 7) + (cc << 3);
    *(bf16x8*)dst = v;
  }
}

// ---------------------------------------------------------------------------
// Grouped MFMA GEMM (84 VGPR / 32KB LDS, occupancy-safe).
// N-fastest wg decomposition + bijective XCD chunk swizzle (A-panel L2 reuse).
// NOTE: epilogue extensions must stay under ~96 VGPR / 32KB LDS (round-9
// fused-gate at 172 VGPR/48KB collapsed occupancy to 8.5%, -43%).
// ---------------------------------------------------------------------------
struct GemmP {
  const ushort_t* A; const ushort_t* A2; const ushort_t* B;
  const float* bias; const ushort_t* gate; void* C;
  int a_se, a_si, pair, asplit;
  int ldb;
  int gate_ofs, gse;
  int c_se, c_si, c_ofs;
  int ihalf, act, c_bf16;
  int M, N, K;
  int ngx, ngy, wg_base;
};
struct Grouped { GemmP d[14]; int nd; int nwg; };

__global__ __launch_bounds__(256) void gemm_g(Grouped G) {
  __shared__ short SH[16384];
  short* As = SH;
  short* Bs = SH + 8192;
  int bid;
  {
    int n = G.nwg, orig = blockIdx.x;
    int q = n >> 3, r = n & 7;
    int xcd = orig & 7, pos = orig >> 3;
    bid = (xcd < r ? xcd * (q + 1) : r * (q + 1) + (xcd - r) * q) + pos;
  }
  int di = G.nd - 1;
  for (int i = 1; i < G.nd; ++i) if (bid < G.d[i].wg_base) { di = i - 1; break; }
  const GemmP p = G.d[di];
  const int local = bid - p.wg_base;
  const int by = local % p.ngy, bx = local / p.ngy;
  const int m0 = bx << 7, n0 = by << 7;

  const int tid = threadIdx.x;
  const int lane = tid & 63, wave = tid >> 6;
  const int gl = ((lane & 3) ^ ((lane >> 3) & 3)) << 3;
  const int grow = (wave << 4) + (lane >> 2);
  const int fr = lane & 15, fkg = lane >> 4;
  const int sxor = (fr >> 1) & 3;
  const int wm = (wave >> 1) << 6, wn = (wave & 1) << 6;

  f32x4 acc[4][4];
  #pragma unroll
  for (int i = 0; i < 4; ++i)
    #pragma unroll
    for (int j = 0; j < 4; ++j) acc[i][j] = (f32x4){0.f, 0.f, 0.f, 0.f};

  long long abase;
  {
    int r0 = m0 + grow;
    abase = p.pair
        ? (long long)(r0 >> 1) * p.a_se + (long long)(r0 & 1) * p.a_si
        : (long long)r0 * p.a_se;
  }
  long long abase2;
  {
    int r1 = m0 + 64 + grow;
    abase2 = p.pair
        ? (long long)(r1 >> 1) * p.a_se + (long long)(r1 & 1) * p.a_si
        : (long long)r1 * p.a_se;
  }
  const long long bbase  = (long long)(n0 + grow) * p.ldb;
  const long long bbase2 = (long long)(n0 + 64 + grow) * p.ldb;

  const int nt = p.K >> 5;

  auto STAGE = [&](int buf, int k0) {
    const ushort_t* Ap = p.A;
    int kk = k0;
    if (p.A2 && k0 >= p.asplit) { Ap = p.A2; kk = k0 - p.asplit; }
    const int lofs = (buf << 12) + (wave << 9);
    gld16(Ap + abase + kk + gl,   &As[lofs]);
    gld16(p.B + bbase + k0 + gl,  &Bs[lofs]);
    gld16(Ap + abase2 + kk + gl,  &As[lofs + 2048]);
    gld16(p.B + bbase2 + k0 + gl, &Bs[lofs + 2048]);
  };

  STAGE(0, 0);
  int cur = 0;
  for (int t = 0; t < nt; ++t) {
    if (t + 1 < nt) {
      STAGE(cur ^ 1, (t + 1) << 5);
      asm volatile("s_waitcnt vmcnt(4)" ::: "memory");
    } else {
      asm volatile("s_waitcnt vmcnt(0)" ::: "memory");
    }
    __builtin_amdgcn_sched_barrier(0);
    __builtin_amdgcn_s_barrier();
    {
      const int bofs = cur << 12;
      bf16x8 af[4], bfv[4];
      #pragma unroll
      for (int i = 0; i < 4; ++i) {
        int ra = wm + (i << 4) + fr;
        int rb = wn + (i << 4) + fr;
        af[i]  = *(const bf16x8*)&As[bofs + (ra << 5) + ((fkg ^ sxor) << 3)];
        bfv[i] = *(const bf16x8*)&Bs[bofs + (rb << 5) + ((fkg ^ sxor) << 3)];
      }
      #pragma unroll
      for (int i = 0; i < 4; ++i)
        #pragma unroll
        for (int j = 0; j < 4; ++j)
          acc[i][j] = __builtin_amdgcn_mfma_f32_16x16x32_bf16(af[i], bfv[j], acc[i][j], 0, 0, 0);
    }
    __builtin_amdgcn_s_barrier();
    cur ^= 1;
  }

  const int crl = (lane >> 4) << 2, ccl = lane & 15;
  if (p.c_bf16) {
    #pragma unroll
    for (int mi = 0; mi < 4; ++mi)
      #pragma unroll
      for (int r = 0; r < 4; ++r) {
        int lrow = wm + mi * 16 + crl + r;
        #pragma unroll
        for (int ni = 0; ni < 4; ++ni) {
          int lcol = wn + ni * 16 + ccl;
          float v = acc[mi][ni][r];
          int gc = n0 + lcol;
          if (p.bias) v += p.bias[gc];
          if (p.act)  v = siluf(v);
          SH[(lrow << 7) + (((lcol >> 3) ^ (lrow & 15)) << 3) + (lcol & 7)] =
              (short)f2bf(v);
        }
      }
    __syncthreads();
    const int lr = tid >> 1, chalf = (tid & 1) << 6;
    int gr = m0 + lr;
    if (gr < p.M) {
      long long e; int ii;
      if (p.pair) { e = gr >> 1; ii = gr & 1; } else { e = gr; ii = 0; }
      const ushort_t* grw = p.gate ? p.gate + e * p.gse + p.gate_ofs : nullptr;
      #pragma unroll
      for (int j = 0; j < 8; ++j) {
        int lcol = chalf + (j << 3);
        bf16x8 v = *(const bf16x8*)&SH[(lr << 7) + (((lcol >> 3) ^ (lr & 15)) << 3)];
        int gc = n0 + lcol;
        if (grw) {
          bf16x8 g8 = *(const bf16x8*)&grw[gc];
          #pragma unroll
          for (int q2 = 0; q2 < 8; ++q2)
            v[q2] = (short)f2bf(bf2f((ushort_t)v[q2]) * bf2f((ushort_t)g8[q2]));
        }
        int par = (p.ihalf && gc >= 256) ? (1 - ii) : ii;
        long long co = e * (long long)p.c_se + (long long)par * p.c_si + p.c_ofs + gc;
        *(bf16x8*)&((ushort_t*)p.C)[co] = v;
      }
    }
  } else {
    #pragma unroll
    for (int mi = 0; mi < 4; ++mi) {
      #pragma unroll
      for (int r = 0; r < 4; ++r) {
        int gr = m0 + wm + mi * 16 + crl + r;
        if (gr >= p.M) continue;
        long long e = gr;
        float* crow = (float*)p.C + e * (long long)p.c_se + p.c_ofs;
        #pragma unroll
        for (int ni = 0; ni < 4; ++ni) {
          int gc = n0 + wn + ni * 16 + ccl;
          if (gc >= p.N) continue;
          float v = acc[mi][ni][r];
          if (p.bias) v += p.bias[gc];
          if (p.act)  v = siluf(v);
          crow[gc] = v;
        }
      }
    }
  }
}

// ---------------------------------------------------------------------------
// gridmm (atom phase)
// ---------------------------------------------------------------------------
struct GridP {
  const float* A; const ushort_t* B; void* C; const float* bias;
  int b_ib, c_ib;
  int M, K, permA, act, c_bf16;
};

#define LDW 40

__global__ __launch_bounds__(256) void gridmm(GridP p) {
  __shared__ short As[128 * LDW];
  __shared__ short Bs[128 * LDW];
  const int e = blockIdx.x;
  const int tid = threadIdx.x;
  const int srow = tid >> 1, sk = (tid & 1) << 4;
  const int lane = tid & 63, wave = tid >> 6;
  const int wm = (wave >> 1) << 6, wn = (wave & 1) << 6;
  const int fr = lane & 15, fk = (lane >> 4) << 3;

  f32x4 acc[4][4];
  #pragma unroll
  for (int i = 0; i < 4; ++i)
    #pragma unroll
    for (int j = 0; j < 4; ++j) acc[i][j] = (f32x4){0.f, 0.f, 0.f, 0.f};

  const ushort_t* bp0 = p.B + (long long)e * p.b_ib;

  for (int k0 = 0; k0 < p.K; k0 += 32) {
    {
      bf16x8 lo = (bf16x8)0, hi = (bf16x8)0;
      if (srow < p.M) {
        const float* ar = p.A + srow * p.K;
        #pragma unroll
        for (int j = 0; j < 8; ++j) {
          int col = k0 + sk + j;
          float v = 0.f;
          if (col < p.K) v = ar[p.permA ? c_perm[col] : col];
          lo[j] = (short)f2bf(v);
        }
        #pragma unroll
        for (int j = 0; j < 8; ++j) {
          int col = k0 + sk + 8 + j;
          float v = 0.f;
          if (col < p.K) v = ar[p.permA ? c_perm[col] : col];
          hi[j] = (short)f2bf(v);
        }
      }
      *(bf16x8*)&As[srow * LDW + sk] = lo;
      *(bf16x8*)&As[srow * LDW + sk + 8] = hi;
    }
    {
      const int c = tid & 127, kq = tid >> 7;
      #pragma unroll
      for (int i = 0; i < 8; ++i) {
        int kk = kq * 16 + i * 2;
        int k1 = k0 + kk, k2 = k1 + 1;
        uint32 v0 = (k1 < p.K) ? (uint32)bp0[(long long)k1 * 128 + c] : 0u;
        uint32 v1 = (k2 < p.K) ? (uint32)bp0[(long long)k2 * 128 + c] : 0u;
        *(uint32*)&Bs[c * LDW + kk] = v0 | (v1 << 16);
      }
    }
    __syncthreads();
    bf16x8 af[4], bfv[4];
    #pragma unroll
    for (int i = 0; i < 4; ++i) {
      af[i]  = *(const bf16x8*)(&As[(wm + i * 16 + fr) * LDW + fk]);
      bfv[i] = *(const bf16x8*)(&Bs[(wn + i * 16 + fr) * LDW + fk]);
    }
    #pragma unroll
    for (int i = 0; i < 4; ++i)
      #pragma unroll
      for (int j = 0; j < 4; ++j)
        acc[i][j] = __builtin_amdgcn_mfma_f32_16x16x32_bf16(af[i], bfv[j], acc[i][j], 0, 0, 0);
    __syncthreads();
  }

  const int crl = (lane >> 4) << 2, ccl = lane & 15;
  #pragma unroll
  for (int mi = 0; mi < 4; ++mi) {
    #pragma unroll
    for (int r = 0; r < 4; ++r) {
      int gr = wm + mi * 16 + crl + r;
      if (gr >= p.M) continue;
      #pragma unroll
      for (int ni = 0; ni < 4; ++ni) {
        int c = wn + ni * 16 + ccl;
        float v = acc[mi][ni][r];
        if (p.bias) v += p.bias[c];
        if (p.act)  v = siluf(v);
        long long co = (long long)e * p.c_ib + gr * 128 + c;
        if (p.c_bf16) ((ushort_t*)p.C)[co] = f2bf(v);
        else          ((float*)p.C)[co] = v;
      }
    }
  }
}

// ---------------------------------------------------------------------------
// Fused grid pipeline per edge: msg3 = WI @ (FG @ silu(TGp @ msgp))
// ---------------------------------------------------------------------------
#define SWZ8(cg, r) (((cg) ^ ((r) & 7)) & 7)
#define SWZ16(cg, r) (((cg) & 8) | (((cg) ^ (r)) & 7))

__global__ __launch_bounds__(256, 2) void k_grid(
    const ushort_t* __restrict__ tgb, const ushort_t* __restrict__ fgb,
    const float* __restrict__ wigv, const ushort_t* __restrict__ msgp,
    ushort_t* __restrict__ msg3)
{
  __shared__ short Abuf[8192];
  __shared__ short Bsh[8192];
  __shared__ short Ps[16384];
  const int e = blockIdx.x, tid = threadIdx.x;
  const int lane = tid & 63, wv = tid >> 6;
  const int fr = lane & 15, fk = (lane >> 4) << 3;
  const int crl = (lane >> 4) << 2, ccl = lane & 15;
  const ushort_t* me = msgp + (long long)e * 6272;

  for (int gid = tid; gid < 896; gid += 256) {
    int r = gid >> 3, cg = gid & 7;
    bf16x8 v = (bf16x8)0;
    if (r < 98) {
      #pragma unroll
      for (int j = 0; j < 8; ++j) {
        int col = (cg << 3) + j;
        if (col < 49) v[j] = (short)tgb[r * 49 + col];
      }
    }
    *(bf16x8*)&Abuf[(r << 6) + (SWZ8(cg, r) << 3)] = v;
  }
  for (int gid = tid; gid < 1024; gid += 256) {
    int kg = gid >> 7, c = gid & 127;
    bf16x8 v = (bf16x8)0;
    #pragma unroll
    for (int j = 0; j < 8; ++j) {
      int k = (kg << 3) + j;
      if (k < 49) v[j] = (short)me[k * 128 + c];
    }
    *(bf16x8*)&Bsh[(c << 6) + (SWZ8(kg, c) << 3)] = v;
  }
  {
    int c = tid >> 1, gg = 14 + (tid & 1);
    *(bf16x8*)&Ps[(c << 7) + (SWZ16(gg, c) << 3)] = (bf16x8)0;
  }
  __syncthreads();

  {
    f32x4 acc[7][2];
    #pragma unroll
    for (int i = 0; i < 7; ++i) { acc[i][0] = (f32x4){0,0,0,0}; acc[i][1] = (f32x4){0,0,0,0}; }
    #pragma unroll
    for (int k0 = 0; k0 < 64; k0 += 32) {
      int cg = (k0 + fk) >> 3;
      int br0 = ((2 * wv) << 4) + fr, br1 = ((2 * wv + 1) << 4) + fr;
      bf16x8 bf0 = *(const bf16x8*)&Bsh[(br0 << 6) + (SWZ8(cg, br0) << 3)];
      bf16x8 bf1 = *(const bf16x8*)&Bsh[(br1 << 6) + (SWZ8(cg, br1) << 3)];
      #pragma unroll
      for (int rt = 0; rt < 7; ++rt) {
        int ar = (rt << 4) + fr;
        bf16x8 af = *(const bf16x8*)&Abuf[(ar << 6) + (SWZ8(cg, ar) << 3)];
        acc[rt][0] = __builtin_amdgcn_mfma_f32_16x16x32_bf16(af, bf0, acc[rt][0], 0, 0, 0);
        acc[rt][1] = __builtin_amdgcn_mfma_f32_16x16x32_bf16(af, bf1, acc[rt][1], 0, 0, 0);
      }
    }
    #pragma unroll
    for (int rt = 0; rt < 7; ++rt)
      #pragma unroll
      for (int cj = 0; cj < 2; ++cj) {
        int c = ((2 * wv + cj) << 4) + ccl;
        #pragma unroll
        for (int r = 0; r < 4; ++r) {
          int g = (rt << 4) + crl + r;
          Ps[(c << 7) + (SWZ16(g >> 3, c) << 3) + (g & 7)] =
              (short)f2bf(siluf(acc[rt][cj][r]));
        }
      }
  }
  __syncthreads();
  for (int gid = tid; gid < 1024; gid += 256) {
    int r = gid >> 4, cg = gid & 15;
    bf16x8 v = (bf16x8)0;
    if (r < 49) {
      #pragma unroll
      for (int j = 0; j < 8; ++j) {
        int col = (cg << 3) + j;
        if (col < 98) v[j] = (short)fgb[r * 98 + col];
      }
    }
    *(bf16x8*)&Abuf[(r << 7) + (SWZ16(cg, r) << 3)] = v;
  }
  __syncthreads();

  {
    f32x4 acc[4][2];
    #pragma unroll
    for (int i = 0; i < 4; ++i) { acc[i][0] = (f32x4){0,0,0,0}; acc[i][1] = (f32x4){0,0,0,0}; }
    #pragma unroll
    for (int k0 = 0; k0 < 128; k0 += 32) {
      int cg = (k0 + fk) >> 3;
      int br0 = ((2 * wv) << 4) + fr, br1 = ((2 * wv + 1) << 4) + fr;
      bf16x8 bf0 = *(const bf16x8*)&Ps[(br0 << 7) + (SWZ16(cg, br0) << 3)];
      bf16x8 bf1 = *(const bf16x8*)&Ps[(br1 << 7) + (SWZ16(cg, br1) << 3)];
      #pragma unroll
      for (int rt = 0; rt < 4; ++rt) {
        int ar = (rt << 4) + fr;
        bf16x8 af = *(const bf16x8*)&Abuf[(ar << 7) + (SWZ16(cg, ar) << 3)];
        acc[rt][0] = __builtin_amdgcn_mfma_f32_16x16x32_bf16(af, bf0, acc[rt][0], 0, 0, 0);
        acc[rt][1] = __builtin_amdgcn_mfma_f32_16x16x32_bf16(af, bf1, acc[rt][1], 0, 0, 0);
      }
    }
    #pragma unroll
    for (int rt = 0; rt < 4; ++rt)
      #pragma unroll
      for (int cj = 0; cj < 2; ++cj) {
        int c = ((2 * wv + cj) << 4) + ccl;
        #pragma unroll
        for (int r = 0; r < 4; ++r) {
          int q = (rt << 4) + crl + r;
          Bsh[(c << 6) + (SWZ8(q >> 3, c) << 3) + (q & 7)] = (short)f2bf(acc[rt][cj][r]);
        }
      }
  }
  __syncthreads();
  {
    const float* we = wigv + (long long)e * 2401;
    for (int gid = tid; gid < 512; gid += 256) {
      int r = gid >> 3, cg = gid & 7;
      bf16x8 v = (bf16x8)0;
      if (r < 49) {
        #pragma unroll
        for (int j = 0; j < 8; ++j) {
          int col = (cg << 3) + j;
          if (col < 49) v[j] = (short)f2bf(we[r * 49 + col]);
        }
      }
      *(bf16x8*)&Abuf[(r << 6) + (SWZ8(cg, r) << 3)] = v;
    }
  }
  __syncthreads();

  {
    f32x4 acc[4][2];
    #pragma unroll
    for (int i = 0; i < 4; ++i) { acc[i][0] = (f32x4){0,0,0,0}; acc[i][1] = (f32x4){0,0,0,0}; }
    #pragma unroll
    for (int k0 = 0; k0 < 64; k0 += 32) {
      int cg = (k0 + fk) >> 3;
      int br0 = ((2 * wv) << 4) + fr, br1 = ((2 * wv + 1) << 4) + fr;
      bf16x8 bf0 = *(const bf16x8*)&Bsh[(br0 << 6) + (SWZ8(cg, br0) << 3)];
      bf16x8 bf1 = *(const bf16x8*)&Bsh[(br1 << 6) + (SWZ8(cg, br1) << 3)];
      #pragma unroll
      for (int rt = 0; rt < 4; ++rt) {
        int ar = (rt << 4) + fr;
        bf16x8 af = *(const bf16x8*)&Abuf[(ar << 6) + (SWZ8(cg, ar) << 3)];
        acc[rt][0] = __builtin_amdgcn_mfma_f32_16x16x32_bf16(af, bf0, acc[rt][0], 0, 0, 0);
        acc[rt][1] = __builtin_amdgcn_mfma_f32_16x16x32_bf16(af, bf1, acc[rt][1], 0, 0, 0);
      }
    }
    #pragma unroll
    for (int rt = 0; rt < 4; ++rt)
      #pragma unroll
      for (int r = 0; r < 4; ++r) {
        int gi = (rt << 4) + crl + r;
        if (gi < 49) {
          #pragma unroll
          for (int cj = 0; cj < 2; ++cj) {
            int c = ((2 * wv + cj) << 4) + ccl;
            Ps[(gi << 7) + (((c >> 3) ^ (gi & 15)) << 3) + (c & 7)] =
                (short)f2bf(acc[rt][cj][r]);
          }
        }
      }
    __syncthreads();
    ushort_t* oe = msg3 + (long long)e * 6272;
    for (int gid = tid; gid < 784; gid += 256) {
      int row = gid >> 4, cc = gid & 15;
      bf16x8 v = *(const bf16x8*)&Ps[(row << 7) + ((cc ^ (row & 15)) << 3)];
      *(bf16x8*)&oe[(row << 7) + (cc << 3)] = v;
    }
  }
}

// ---------------------------------------------------------------------------
// Segment-sum via per-atom edge lists (vectorized bf16x8 gather)
// direct=1 (single chunk): write bf16 to xmsgb (skips f32 buffer + cvt)
// ---------------------------------------------------------------------------
__global__ __launch_bounds__(256) void k_zeroi(int* __restrict__ p, int n) {
  int id = blockIdx.x * 256 + threadIdx.x;
  if (id < n) p[id] = 0;
}

__global__ __launch_bounds__(256) void k_deg(
    const int* __restrict__ tgt, int* __restrict__ deg) {
  int e = blockIdx.x * 256 + threadIdx.x;
  if (e < EN) atomicAdd(&deg[tgt[e]], 1);
}

__global__ __launch_bounds__(1024) void k_prefix(
    const int* __restrict__ deg, int* __restrict__ base) {
  __shared__ int s[1024];
  int t = threadIdx.x;
  s[t] = (t < AN) ? deg[t] : 0;
  __syncthreads();
  for (int ofs = 1; ofs < 1024; ofs <<= 1) {
    int u = (t >= ofs) ? s[t - ofs] : 0;
    __syncthreads();
    s[t] += u;
    __syncthreads();
  }
  if (t < AN) base[t + 1] = s[t];
  if (t == 0) base[0] = 0;
}

__global__ __launch_bounds__(256) void k_fill(
    const int* __restrict__ tgt, const int* __restrict__ base,
    int* __restrict__ list) {
  const int a = blockIdx.x, t = threadIdx.x;
  const int lane = t & 63, w = t >> 6;
  __shared__ int wtot[4];
  __shared__ int runbase;
  if (t == 0) runbase = base[a];
  __syncthreads();
  for (int i0 = 0; i0 < EN; i0 += 256) {
    int e = i0 + t;
    bool m = (e < EN) && (tgt[e] == a);
    unsigned long long bal = __ballot(m);
    if (lane == 0) wtot[w] = __popcll(bal);
    __syncthreads();
    int wbase = 0;
    for (int j = 0; j < w; ++j) wbase += wtot[j];
    int tot = wtot[0] + wtot[1] + wtot[2] + wtot[3];
    if (m) {
      int off = __popcll(bal & ((1ull << lane) - 1ull));
      list[runbase + wbase + off] = e;
    }
    __syncthreads();
    if (t == 0) runbase += tot;
    __syncthreads();
  }
}

__global__ __launch_bounds__(256) void k_gather4(
    const ushort_t* __restrict__ msg3, const int* __restrict__ base,
    const int* __restrict__ list, float* __restrict__ xmsg,
    ushort_t* __restrict__ xmsgb,
    int e0, int ce, int accum, int direct)
{
  const int a = blockIdx.x, part = blockIdx.y, t = threadIdx.x;
  if (t >= 196) return;
  const int b0 = base[a], b1 = base[a + 1];
  const int co = part * 1568 + t * 8;
  float a8[8];
  #pragma unroll
  for (int u = 0; u < 8; ++u) a8[u] = 0.f;
  for (int i = b0; i < b1; ++i) {
    int e = list[i];
    if (e < e0 || e >= e0 + ce) continue;
    bf16x8 v = *(const bf16x8*)&msg3[(long long)(e - e0) * 6272 + co];
    #pragma unroll
    for (int u = 0; u < 8; ++u) a8[u] += bf2f((ushort_t)v[u]);
  }
  if (direct) {
    bf16x8 o8;
    #pragma unroll
    for (int u = 0; u < 8; ++u) o8[u] = (short)f2bf(a8[u]);
    *(bf16x8*)&xmsgb[(long long)a * 6272 + co] = o8;
    return;
  }
  float* o = xmsg + (long long)a * 6272 + co;
  if (accum) {
    #pragma unroll
    for (int u = 0; u < 8; ++u) o[u] += a8[u];
  } else {
    float4 lo = make_float4(a8[0], a8[1], a8[2], a8[3]);
    float4 hi = make_float4(a8[4], a8[5], a8[6], a8[7]);
    *(float4*)o = lo;
    *(float4*)(o + 4) = hi;
  }
}

// ---------------------------------------------------------------------------
// Host orchestration
// ---------------------------------------------------------------------------
extern "C" void kernel_launch(void* const* d_in, const int* in_sizes, int n_in,
                              void* d_out, int out_size, void* d_ws, size_t ws_size,
                              hipStream_t stream) {
  const float* x         = (const float*)d_in[0];
  const float* edist     = (const float*)d_in[1];
  const float* wigner    = (const float*)d_in[2];
  const float* wiginv    = (const float*)d_in[3];
  const float* to_grid   = (const float*)d_in[4];
  const float* from_grid = (const float*)d_in[5];
  const float* w_dist1   = (const float*)d_in[6];
  const float* b_dist1   = (const float*)d_in[7];
  const float* src_emb   = (const float*)d_in[8];
  const float* tgt_emb   = (const float*)d_in[9];
  const float* w_edge1   = (const float*)d_in[10];
  const float* b_edge1   = (const float*)d_in[11];
  const float* ws1       = (const float*)d_in[12];
  const float* bs1       = (const float*)d_in[13];
  const float* ws2       = (const float*)d_in[14];
  const float* bs2       = (const float*)d_in[15];
  const float* ws3       = (const float*)d_in[16];
  const float* bs3       = (const float*)d_in[17];
  const int*   anum      = (const int*)d_in[18];
  const int*   eidx      = (const int*)d_in[19];
  const float* sw[10]; const float* tw[10];
  for (int i = 0; i < 10; ++i) {
    sw[i] = (const float*)d_in[20 + i];
    tw[i] = (const float*)d_in[30 + i];
  }
  float* outp = (float*)d_out;

  // ---- workspace ----
  char* wsb = (char*)d_ws;
  size_t off = 0;
  auto alloc = [&](long long nbytes) {
    char* p = wsb + off; off += (size_t)((nbytes + 63) & ~63LL); return p;
  };
  ushort_t* x_edge  = (ushort_t*)alloc((8000LL + 128) * 128 * 2);
  ushort_t* b2ab    = (ushort_t*)alloc(5505024LL * 2);
  ushort_t* bgcw    = (ushort_t*)alloc(851968LL * 2);
  float*    bgcb    = (float*)alloc(6656 * 4);
  ushort_t* b20b    = (ushort_t*)alloc(458752LL * 2);
  ushort_t* s1m0b   = (ushort_t*)alloc(458752LL * 2);
  ushort_t* s1mb    = (ushort_t*)alloc(2752512LL * 2);
  ushort_t* wd1b    = (ushort_t*)alloc(65536 * 2);
  ushort_t* we1b    = (ushort_t*)alloc(16384 * 2);
  ushort_t* ws1b    = (ushort_t*)alloc(32768 * 2);
  ushort_t* ws2b    = (ushort_t*)alloc(16384 * 2);
  ushort_t* ws3b    = (ushort_t*)alloc(16384 * 2);
  ushort_t* tgb     = (ushort_t*)alloc(4802 * 2);
  ushort_t* fgb     = (ushort_t*)alloc(4802 * 2);
  float*    xmsg    = (float*)alloc(5017600LL * 4);
  ushort_t* xmsgb   = (ushort_t*)alloc((5017600LL + 16384) * 2);
  ushort_t* xb      = (ushort_t*)alloc((5017600LL + 16384) * 2);
  ushort_t* xbT     = (ushort_t*)alloc(6553600LL * 2);
  ushort_t* basis   = (ushort_t*)alloc((8000LL + 128) * 512 * 2);
  float*    x_dist  = (float*)alloc(1024000LL * 4);
  ushort_t* x_distb = (ushort_t*)alloc((8000LL + 128) * 128 * 2);
  int*      deg     = (int*)alloc(800 * 4);
  int*      sbase   = (int*)alloc(801 * 4);
  int*      elist   = (int*)alloc(8000 * 4);
  const size_t fixedB = off;
  char* arena = wsb + off;

  static const int ces[6] = {8000, 4000, 2000, 1000, 500, 250};
  static const int cas[6] = {800, 800, 800, 400, 200, 100};
  int ce = 250, ca = 100;
  for (int i = 0; i < 6; ++i) {
    long long ne = (long long)ces[i] * 76544 + 64LL * 50688;
    long long na = (long long)cas[i] * 87808 + 64LL * 512;
    long long need = (long long)fixedB + (ne > na ? ne : na);
    if (need <= (long long)ws_size) { ce = ces[i]; ca = cas[i]; break; }
  }

  // edge-phase arena (padded A-sources)
  char* ap = arena;
  ushort_t* xrot_s = (ushort_t*)ap;  ap += (long long)(ce + 64) * 12544;
  ushort_t* xrot_t = (ushort_t*)ap;  ap += (long long)(ce + 64) * 12544;
  ushort_t* tb0    = (ushort_t*)ap;  ap += (long long)(ce + 64) * 1024;
  ushort_t* tbm    = (ushort_t*)ap;  ap += (long long)(ce + 64) * 24576;
  ushort_t* msgp   = (ushort_t*)ap;  ap += (long long)ce * 12544;
  ushort_t* gate   = (ushort_t*)ap;  // ce x 6656 bf16
  ushort_t* msg3   = (ushort_t*)arena;
  // atom-phase arena
  char* bp = arena;
  ushort_t* hb = (ushort_t*)bp;  bp += (long long)ca * 49 * 256;
  ushort_t* g1 = (ushort_t*)bp;  bp += ((long long)ca * 98 + 64) * 256;
  ushort_t* g2 = (ushort_t*)bp;  bp += ((long long)ca * 98 + 64) * 256;
  ushort_t* g3 = (ushort_t*)bp;

  long long ofs2[7][2], s1ofs[7][2];
  { long long cur = 0, cur1 = 0;
    for (int m = 1; m <= 6; ++m) {
      int k = (7 - m) * 128;
      ofs2[m][0] = cur; cur += (long long)k * 1024;
      ofs2[m][1] = cur; cur += (long long)k * 1024;
      s1ofs[m][0] = cur1; cur1 += 512LL * k;
      s1ofs[m][1] = cur1; cur1 += 512LL * k;
    } }

  auto D0 = []() { GemmP p; memset(&p, 0, sizeof(p)); p.asplit = 1 << 30; p.gse = 6656; return p; };
  auto finalize = [&](Grouped& G) {
    int base = 0;
    for (int i = 0; i < G.nd; ++i) {
      GemmP& p = G.d[i];
      p.ngx = (p.M + 127) >> 7;
      p.ngy = (p.N + 127) >> 7;
      p.wg_base = base;
      base += p.ngx * p.ngy;
    }
    G.nwg = base;
    gemm_g<<<base, 256, 0, stream>>>(G);
  };
  auto run1 = [&](GemmP p) { Grouped G; G.d[0] = p; G.nd = 1; finalize(G); };
  auto rungrid = [&](const float* A, int M, int K, int permA,
                     const ushort_t* B, int b_ib, void* C, int c_ib,
                     const float* bias, int act, int c_bf16, int nb) {
    GridP p;
    p.A = A; p.B = B; p.C = C; p.bias = bias;
    p.b_ib = b_ib; p.c_ib = c_ib;
    p.M = M; p.K = K; p.permA = permA; p.act = act; p.c_bf16 = c_bf16;
    gridmm<<<nb, 256, 0, stream>>>(p);
  };

  // 0) merged weight builds (one launch)
  { BuildP P;
    P.sw7 = sw[7]; P.sw9 = sw[9]; P.tw7 = tw[7]; P.tw9 = tw[9];
    P.sw0 = sw[0]; P.tw0 = tw[0]; P.sw4 = sw[4]; P.tw4 = tw[4];
    P.sb1 = sw[1]; P.tb1 = tw[1]; P.sbd = sw[5]; P.tbd = tw[5];
    P.sw3 = sw[3]; P.tw3 = tw[3];
    P.sw6 = sw[6]; P.sw8 = sw[8]; P.tw6 = tw[6]; P.tw8 = tw[8];
    P.tg = to_grid;
    P.b2ab = b2ab; P.bgcw = bgcw; P.b20b = b20b; P.s1mb = s1mb; P.tgb = tgb;
    P.bgcb = bgcb;
    k_build_all<<<(int)((BSEG4 + 255) / 256), 256, 0, stream>>>(P);
  }
  { // merged conversions
    CvtM P;
    const float* ss[9] = { sw[2], tw[2], w_dist1, w_edge1, ws1, ws2, ws3, from_grid, x };
    ushort_t* dd[9] = { s1m0b, s1m0b + 229376, wd1b, we1b, ws1b, ws2b, ws3b, fgb, xb };
    long long nn[9] = { 229376, 229376, 65536, 16384, 32768, 16384, 16384, 4802, 5017600 };
    long long cur = 0;
    for (int i = 0; i < 9; ++i) { P.s[i] = ss[i]; P.d[i] = dd[i]; P.start[i] = cur; cur += nn[i]; }
    P.start[9] = cur;
    k_cvt_multi<<<(int)((cur + 255) / 256), 256, 0, stream>>>(P);
  }
  k_xT<<<AN, 256, 0, stream>>>(x, xbT);

  // scatter lists
  k_zeroi<<<4, 256, 0, stream>>>(deg, 800);
  k_deg<<<(EN + 255) / 256, 256, 0, stream>>>(eidx + EN, deg);
  k_prefix<<<1, 1024, 0, stream>>>(deg, sbase);
  k_fill<<<AN, 256, 0, stream>>>(eidx + EN, sbase, elist);

  // 1) edge features
  k_basis<<<(EN * 512 + 255) / 256, 256, 0, stream>>>(edist, basis);
  { GemmP p = D0();
    p.A = basis; p.a_se = 512; p.B = wd1b; p.ldb = 512; p.bias = b_dist1;
    p.C = x_dist; p.c_se = 128; p.M = EN; p.N = 128; p.K = 512;
    run1(p); }
  k_emb<<<(EN * 128 + 255) / 256, 256, 0, stream>>>(src_emb, tgt_emb, anum, eidx,
                                                    x_dist, x_distb);
  { GemmP p = D0();
    p.A = x_distb; p.a_se = 128; p.B = we1b; p.ldb = 128; p.bias = b_edge1;
    p.act = 1; p.C = x_edge; p.c_se = 128; p.c_bf16 = 1;
    p.M = EN; p.N = 128; p.K = 128;
    run1(p); }

  static const int offq[7] = {0, 7, 19, 29, 37, 43, 47};
  const int single = (ce == EN);

  // 2) edge chunks
  for (int e0 = 0; e0 < EN; e0 += ce) {
    const int c = ce;
    k_rot2<<<c, 256, 0, stream>>>(wigner + (long long)e0 * 2401, xbT,
                                  eidx + e0, eidx + EN + e0, xrot_s, xrot_t);
    // gates (N=6656)
    { GemmP p = D0();
      p.A = x_edge + (long long)e0 * 128; p.a_se = 128;
      p.B = bgcw; p.ldb = 128; p.bias = bgcb; p.act = 1;
      p.C = gate; p.c_se = 6656; p.c_bf16 = 1;
      p.M = c; p.N = 6656; p.K = 128;
      run1(p); }
    // stage 1 grouped
    { Grouped G; G.nd = 14;
      for (int s = 0; s < 2; ++s) {
        GemmP p = D0();
        p.A = s ? xrot_t : xrot_s; p.a_se = 6272;
        p.B = s1m0b + (long long)s * 229376; p.ldb = 896;
        p.gate = gate; p.gate_ofs = s * 256;
        p.C = tb0; p.c_se = 512; p.c_ofs = s * 256; p.c_bf16 = 1;
        p.M = c; p.N = 256; p.K = 896;
        G.d[s] = p;
      }
      int di = 2;
      for (int m = 1; m <= 6; ++m) {
        const int k = (7 - m) * 128, off2 = offq[m];
        for (int s = 0; s < 2; ++s) {
          GemmP p = D0();
          p.A = (s ? xrot_t : xrot_s) + off2 * 128;
          p.a_se = 6272; p.a_si = k; p.pair = 1;
          p.B = s1mb + s1ofs[m][s]; p.ldb = k;
          p.gate = gate; p.gate_ofs = 512 + (m - 1) * 1024 + s * 512;
          p.C = tbm; p.c_se = 12288; p.c_si = 1024;
          p.c_ofs = (m - 1) * 2048 + s * 512;
          p.ihalf = 1; p.c_bf16 = 1;
          p.M = 2 * c; p.N = 512; p.K = k;
          G.d[di++] = p;
        }
      }
      finalize(G); }
    // stage 2 grouped
    { Grouped G; G.nd = 13;
      { GemmP p = D0();
        p.A = tb0; p.a_se = 512;
        p.B = b20b; p.ldb = 512;
        p.C = msgp; p.c_se = 6272; p.c_bf16 = 1;
        p.M = c; p.N = 896; p.K = 512;
        G.d[0] = p; }
      int di = 1;
      for (int m = 1; m <= 6; ++m) {
        const int n = 7 - m, k = n * 128, off2 = offq[m];
        for (int pp = 0; pp < 2; ++pp) {
          GemmP p = D0();
          p.A = tbm + (m - 1) * 2048 + pp * 1024; p.a_se = 12288;
          p.B = b2ab + ofs2[m][pp]; p.ldb = 1024;
          p.C = msgp; p.c_se = 6272; p.c_ofs = (off2 + (pp ? n : 0)) * 128; p.c_bf16 = 1;
          p.M = c; p.N = k; p.K = 1024;
          G.d[di++] = p;
        }
      }
      finalize(G); }
    // fused grid pipeline + gather
    k_grid<<<c, 256, 0, stream>>>(tgb, fgb, wiginv + (long long)e0 * 2401, msgp, msg3);
    k_gather4<<<dim3(AN, 4), 256, 0, stream>>>(msg3, sbase, elist, xmsg, xmsgb,
                                               e0, c, e0 > 0, single);
  }

  // xmsg -> bf16 (only needed when chunked; single-chunk wrote bf16 directly)
  if (!single)
    k_cvt<<<(5017600 + 255) / 256, 256, 0, stream>>>(xmsg, xmsgb, 5017600);

  // 3) atom phase
  for (int a0 = 0; a0 < AN; a0 += ca) {
    { GemmP p = D0();
      p.A = xb + (long long)a0 * 6272; p.A2 = xmsgb + (long long)a0 * 6272;
      p.a_se = 128; p.asplit = 128;
      p.B = ws1b; p.ldb = 256;
      p.C = hb; p.c_se = 128; p.c_bf16 = 1;
      p.M = ca * 49; p.N = 128; p.K = 256;
      run1(p); }
    rungrid(to_grid, 98, 49, 0, hb, 6272, g1, 12544, bs1, 1, 1, ca);
    { GemmP p = D0();
      p.A = g1; p.a_se = 128;
      p.B = ws2b; p.ldb = 128; p.bias = bs2; p.act = 1;
      p.C = g2; p.c_se = 128; p.c_bf16 = 1;
      p.M = ca * 98; p.N = 128; p.K = 128;
      run1(p); }
    { GemmP p = D0();
      p.A = g2; p.a_se = 128;
      p.B = ws3b; p.ldb = 128; p.bias = bs3;
      p.C = g3; p.c_se = 128; p.c_bf16 = 1;
      p.M = ca * 98; p.N = 128; p.K = 128;
      run1(p); }
    rungrid(from_grid, 49, 98, 0, g3, 12544, outp + (long long)a0 * 6272, 6272,
            nullptr, 0, 0, ca);
  }
}

// Round 13
// 1548.218 us; speedup vs baseline: 1.5110x; 1.0238x over previous
//
#include <hip/hip_runtime.h>
#include <string.h>

#define EN 8000
#define AN 800

typedef __attribute__((ext_vector_type(8))) short bf16x8;
typedef __attribute__((ext_vector_type(4))) float f32x4;
typedef unsigned short ushort_t;
typedef unsigned int uint32;

__constant__ int c_perm[49] = {
  0,2,6,12,20,30,42,
  1,5,11,19,29,41,
  3,7,13,21,31,43,
  4,10,18,28,40,
  8,14,22,32,44,
  9,17,27,39,
  15,23,33,45,
  16,26,38,
  24,34,46,
  25,37,
  35,47,
  36,
  48
};

__device__ __forceinline__ float siluf(float x) { return x / (1.0f + __expf(-x)); }
__device__ __forceinline__ ushort_t f2bf(float f) {
  uint32 u = __float_as_uint(f);
  u += 0x7fff + ((u >> 16) & 1);
  return (ushort_t)(u >> 16);
}
__device__ __forceinline__ float bf2f(ushort_t h) {
  return __uint_as_float(((uint32)h) << 16);
}
__device__ __forceinline__ void gld16(const void* g, void* l) {
  __builtin_amdgcn_global_load_lds(
      (const __attribute__((address_space(1))) void*)g,
      (__attribute__((address_space(3))) void*)l, 16, 0, 0);
}

// ---------------------------------------------------------------------------
// Merged weight builder: all bf16 weight-concats in ONE launch.
// ---------------------------------------------------------------------------
#define BSEG0 5505024LL
#define BSEG1 6363648LL
#define BSEG2 6822400LL
#define BSEG3 9574912LL
#define BSEG4 9579714LL

struct BuildP {
  const float *sw7, *sw9, *tw7, *tw9;
  const float *sw0, *tw0, *sw4, *tw4, *sb1, *tb1, *sbd, *tbd;
  const float *sw3, *tw3;
  const float *sw6, *sw8, *tw6, *tw8;
  const float *tg;
  ushort_t *b2ab, *bgcw, *b20b, *s1mb, *tgb;
  float *bgcb;
};

__global__ __launch_bounds__(256) void k_build_all(BuildP P) {
  long long id = (long long)blockIdx.x * 256 + threadIdx.x;
  if (id >= BSEG4) return;
  if (id < BSEG0) {
    long long base = 0; int m = 1, k = 768;
    for (; m <= 6; ++m) {
      k = (7 - m) * 128;
      long long sz = 2LL * k * 1024;
      if (id < base + sz) break;
      base += sz;
    }
    long long rem = id - base;
    int p = (int)(rem / ((long long)k * 1024));
    int cj = (int)(rem - (long long)p * k * 1024);
    int c = cj >> 10, j = cj & 1023;
    int q = j >> 8, jj = j & 255;
    const float sgn = (q & 1) ? (p ? 1.f : -1.f) : 1.f;
    const float* src = (q < 2) ? (q == 0 ? P.sw7 : P.sw9) : (q == 2 ? P.tw7 : P.tw9);
    P.b2ab[id] = f2bf(sgn * src[(long long)(m - 1) * 196608 + c * 256 + jj]);
    return;
  }
  if (id < BSEG1) {
    int id2 = (int)(id - BSEG0);
    if (id2 < 851968) {
      int r = id2 >> 7, c = id2 & 127;
      float v;
      if (r < 256) v = P.sw0[r * 128 + c];
      else if (r < 512) v = P.tw0[(r - 256) * 128 + c];
      else {
        int rr = r - 512, m = rr >> 10, q = rr & 1023;
        v = (q < 512) ? P.sw4[m * 65536 + q * 128 + c]
                      : P.tw4[m * 65536 + (q - 512) * 128 + c];
      }
      P.bgcw[id2] = f2bf(v);
    } else {
      int ib = id2 - 851968;
      float v;
      if (ib < 256) v = P.sb1[ib];
      else if (ib < 512) v = P.tb1[ib - 256];
      else {
        int rr = ib - 512, m = rr >> 10, q = rr & 1023;
        v = (q < 512) ? P.sbd[m * 512 + q] : P.tbd[m * 512 + (q - 512)];
      }
      P.bgcb[ib] = v;
    }
    return;
  }
  if (id < BSEG2) {
    int id2 = (int)(id - BSEG1);
    int cc = id2 >> 9, j = id2 & 511;
    P.b20b[id2] = f2bf((j < 256) ? P.sw3[cc * 256 + j] : P.tw3[cc * 256 + (j - 256)]);
    return;
  }
  if (id < BSEG3) {
    long long id2 = id - BSEG2;
    long long base = 0; int m = 1, k = 768;
    for (; m <= 6; ++m) {
      k = (7 - m) * 128;
      long long sz = 1024LL * k;
      if (id2 < base + sz) break;
      base += sz;
    }
    long long rem = id2 - base;
    int s = (int)(rem / (512LL * k));
    int rr = (int)(rem - (long long)s * 512 * k);
    int r = rr / k, c = rr - r * k;
    const float* src = (r < 256) ? (s ? P.tw6 : P.sw6) : (s ? P.tw8 : P.sw8);
    int r0 = (r < 256) ? r : r - 256;
    P.s1mb[id2] = f2bf(src[(long long)(m - 1) * 196608 + r0 * 768 + c]);
    return;
  }
  {
    int id2 = (int)(id - BSEG3);
    int r = id2 / 49, s = id2 - r * 49;
    P.tgb[id2] = f2bf(P.tg[r * 49 + c_perm[s]]);
  }
}

// merged f32->bf16 conversions (up to 9 segments)
struct CvtM {
  const float* s[9];
  ushort_t* d[9];
  long long start[10];
};
__global__ __launch_bounds__(256) void k_cvt_multi(CvtM P) {
  long long id = (long long)blockIdx.x * 256 + threadIdx.x;
  if (id >= P.start[9]) return;
  int seg = 0;
  #pragma unroll
  for (int i = 1; i < 9; ++i) if (id >= P.start[i]) seg = i;
  long long o = id - P.start[seg];
  P.d[seg][o] = f2bf(P.s[seg][o]);
}

__global__ __launch_bounds__(256) void k_cvt(
    const float* __restrict__ src, ushort_t* __restrict__ dst, int n)
{
  int id = blockIdx.x * 256 + threadIdx.x;
  if (id < n) dst[id] = f2bf(src[id]);
}

// transpose x (f32 [49][128]) -> xbT (bf16 [128][64], j-padded)
__global__ __launch_bounds__(256) void k_xT(
    const float* __restrict__ x, ushort_t* __restrict__ xbT)
{
  __shared__ __align__(16) float xs[49 * 128];
  const int a = blockIdx.x, t = threadIdx.x;
  const float4* src = (const float4*)(x + (long long)a * 6272);
  float4* d = (float4*)xs;
  for (int i = t; i < 1568; i += 256) d[i] = src[i];
  __syncthreads();
  ushort_t* o = xbT + (long long)a * 8192;
  int c = t >> 1;
  int jg = (t & 1) << 2;
  #pragma unroll
  for (int u = 0; u < 4; ++u) {
    int g = jg + u;
    bf16x8 v = (bf16x8)0;
    #pragma unroll
    for (int j = 0; j < 8; ++j) {
      int jj = (g << 3) + j;
      if (jj < 49) v[j] = (short)f2bf(xs[jj * 128 + c]);
    }
    *(bf16x8*)&o[(c << 6) + (g << 3)] = v;
  }
}

// ---------------------------------------------------------------------------
// Edge features
// ---------------------------------------------------------------------------
__global__ __launch_bounds__(256) void k_basis(
    const float* __restrict__ dist, ushort_t* __restrict__ basis)
{
  int id = blockIdx.x * 256 + threadIdx.x;
  if (id >= EN * 512) return;
  int e = id >> 9, g = id & 511;
  const float step = 8.0f / 511.0f;
  const float coeff = -2040.0078125f;
  float df = dist[e] - (float)g * step;
  basis[id] = f2bf(expf(coeff * df * df));
}

__global__ __launch_bounds__(256) void k_emb(
    const float* __restrict__ src_emb, const float* __restrict__ tgt_emb,
    const int* __restrict__ anum, const int* __restrict__ eidx,
    const float* __restrict__ xd, ushort_t* __restrict__ out)
{
  int id = blockIdx.x * 256 + threadIdx.x;
  if (id >= EN * 128) return;
  int e = id >> 7, c = id & 127;
  int a0 = anum[eidx[e]], a1 = anum[eidx[EN + e]];
  out[id] = f2bf(siluf(src_emb[a0 * 128 + c] + tgt_emb[a1 * 128 + c] + xd[id]));
}

// ---------------------------------------------------------------------------
// MFMA Wigner rotation with coalesced (repacked) output
// ---------------------------------------------------------------------------
__global__ __launch_bounds__(256) void k_rot2(
    const float* __restrict__ wig, const ushort_t* __restrict__ xbT,
    const int* __restrict__ srcl, const int* __restrict__ tgtl,
    ushort_t* __restrict__ osrc, ushort_t* __restrict__ otgt)
{
  __shared__ short Ws[4096];
  __shared__ short Xs[8192];
  __shared__ short Xt[8192];
  const int e = blockIdx.x, tid = threadIdx.x;
  const int lane = tid & 63, wave = tid >> 6;
  const float* wge = wig + (long long)e * 2401;
  #pragma unroll
  for (int t = 0; t < 2; ++t) {
    int ci = (t << 8) + tid;
    int row = ci >> 3, g = ci & 7;
    bf16x8 v = (bf16x8)0;
    if (row < 49) {
      const float* wr = wge + c_perm[row] * 49;
      #pragma unroll
      for (int j = 0; j < 8; ++j) {
        int col = (g << 3) + j;
        if (col < 49) v[j] = (short)f2bf(wr[col]);
      }
    }
    *(bf16x8*)&Ws[(row << 6) + ((g ^ (row & 7)) << 3)] = v;
  }
  const int as = srcl[e], at = tgtl[e];
  const ushort_t* xsg = xbT + (long long)as * 8192;
  const ushort_t* xtg = xbT + (long long)at * 8192;
  #pragma unroll
  for (int t = 0; t < 4; ++t) {
    int ci = (t << 8) + tid;
    int row = ci >> 3, g = ci & 7;
    int ofs = (row << 6) + ((g ^ (row & 7)) << 3);
    *(bf16x8*)&Xs[ofs] = *(const bf16x8*)&xsg[ci << 3];
    *(bf16x8*)&Xt[ofs] = *(const bf16x8*)&xtg[ci << 3];
  }
  __syncthreads();
  const short* Xb = (wave >> 1) ? Xt : Xs;
  const int ch = (wave & 1) << 6;
  const int fr = lane & 15, g = lane >> 4;
  f32x4 acc[4][4];
  #pragma unroll
  for (int i = 0; i < 4; ++i)
    #pragma unroll
    for (int j = 0; j < 4; ++j) acc[i][j] = (f32x4){0.f, 0.f, 0.f, 0.f};
  #pragma unroll
  for (int ks = 0; ks < 2; ++ks) {
    bf16x8 af[4], bfv[4];
    int lc = (ks << 2) + g;
    #pragma unroll
    for (int i = 0; i < 4; ++i) {
      int ra = (i << 4) + fr;
      af[i] = *(const bf16x8*)&Ws[(ra << 6) + ((lc ^ (ra & 7)) << 3)];
      int rb = ch + (i << 4) + fr;
      bfv[i] = *(const bf16x8*)&Xb[(rb << 6) + ((lc ^ (rb & 7)) << 3)];
    }
    #pragma unroll
    for (int i = 0; i < 4; ++i)
      #pragma unroll
      for (int j = 0; j < 4; ++j)
        acc[i][j] = __builtin_amdgcn_mfma_f32_16x16x32_bf16(af[i], bfv[j], acc[i][j], 0, 0, 0);
  }
  const int crl = (lane >> 4) << 2, ccl = lane & 15;
  __syncthreads();
  short* Ob = (wave >> 1) ? Xt : Xs;
  #pragma unroll
  for (int i = 0; i < 4; ++i)
    #pragma unroll
    for (int r = 0; r < 4; ++r) {
      int q = (i << 4) + crl + r;
      if (q < 49) {
        #pragma unroll
        for (int j = 0; j < 4; ++j) {
          int col = ch + (j << 4) + ccl;
          Ob[(q << 7) + (((col >> 3) ^ (q & 15)) << 3) + (col & 7)] =
              (short)f2bf(acc[i][j][r]);
        }
      }
    }
  __syncthreads();
  for (int gid = tid; gid < 1568; gid += 256) {
    int half = gid >= 784;
    int c784 = half ? gid - 784 : gid;
    int row = c784 >> 4, cc = c784 & 15;
    const short* Sb = half ? Xt : Xs;
    bf16x8 v = *(const bf16x8*)&Sb[(row << 7) + ((cc ^ (row & 15)) << 3)];
    ushort_t* dst = (half ? otgt : osrc) + (long long)e * 6272 + (row << 7) + (cc << 3);
    *(bf16x8*)dst = v;
  }
}

// ---------------------------------------------------------------------------
// Grouped MFMA GEMM. __launch_bounds__(256,3): force 3 waves/EU (12 waves/CU
// = 3 blocks/CU) so a third block's K-loop overlaps another's epilogue.
// Budget check: 84 VGPR + 64 AGPR = 148 unified <= 512/3 = 170 (no spill).
// NOTE: epilogue extensions must stay under ~96 VGPR / 32KB LDS (round-9
// fused-gate at 172 VGPR/48KB collapsed occupancy to 8.5%, -43%).
// ---------------------------------------------------------------------------
struct GemmP {
  const ushort_t* A; const ushort_t* A2; const ushort_t* B;
  const float* bias; const ushort_t* gate; void* C;
  int a_se, a_si, pair, asplit;
  int ldb;
  int gate_ofs, gse;
  int c_se, c_si, c_ofs;
  int ihalf, act, c_bf16;
  int M, N, K;
  int ngx, ngy, wg_base;
};
struct Grouped { GemmP d[14]; int nd; int nwg; };

__global__ __launch_bounds__(256, 3) void gemm_g(Grouped G) {
  __shared__ short SH[16384];
  short* As = SH;
  short* Bs = SH + 8192;
  int bid;
  {
    int n = G.nwg, orig = blockIdx.x;
    int q = n >> 3, r = n & 7;
    int xcd = orig & 7, pos = orig >> 3;
    bid = (xcd < r ? xcd * (q + 1) : r * (q + 1) + (xcd - r) * q) + pos;
  }
  int di = G.nd - 1;
  for (int i = 1; i < G.nd; ++i) if (bid < G.d[i].wg_base) { di = i - 1; break; }
  const GemmP p = G.d[di];
  const int local = bid - p.wg_base;
  const int by = local % p.ngy, bx = local / p.ngy;
  const int m0 = bx << 7, n0 = by << 7;

  const int tid = threadIdx.x;
  const int lane = tid & 63, wave = tid >> 6;
  const int gl = ((lane & 3) ^ ((lane >> 3) & 3)) << 3;
  const int grow = (wave << 4) + (lane >> 2);
  const int fr = lane & 15, fkg = lane >> 4;
  const int sxor = (fr >> 1) & 3;
  const int wm = (wave >> 1) << 6, wn = (wave & 1) << 6;

  f32x4 acc[4][4];
  #pragma unroll
  for (int i = 0; i < 4; ++i)
    #pragma unroll
    for (int j = 0; j < 4; ++j) acc[i][j] = (f32x4){0.f, 0.f, 0.f, 0.f};

  long long abase;
  {
    int r0 = m0 + grow;
    abase = p.pair
        ? (long long)(r0 >> 1) * p.a_se + (long long)(r0 & 1) * p.a_si
        : (long long)r0 * p.a_se;
  }
  long long abase2;
  {
    int r1 = m0 + 64 + grow;
    abase2 = p.pair
        ? (long long)(r1 >> 1) * p.a_se + (long long)(r1 & 1) * p.a_si
        : (long long)r1 * p.a_se;
  }
  const long long bbase  = (long long)(n0 + grow) * p.ldb;
  const long long bbase2 = (long long)(n0 + 64 + grow) * p.ldb;

  const int nt = p.K >> 5;

  auto STAGE = [&](int buf, int k0) {
    const ushort_t* Ap = p.A;
    int kk = k0;
    if (p.A2 && k0 >= p.asplit) { Ap = p.A2; kk = k0 - p.asplit; }
    const int lofs = (buf << 12) + (wave << 9);
    gld16(Ap + abase + kk + gl,   &As[lofs]);
    gld16(p.B + bbase + k0 + gl,  &Bs[lofs]);
    gld16(Ap + abase2 + kk + gl,  &As[lofs + 2048]);
    gld16(p.B + bbase2 + k0 + gl, &Bs[lofs + 2048]);
  };

  STAGE(0, 0);
  int cur = 0;
  for (int t = 0; t < nt; ++t) {
    if (t + 1 < nt) {
      STAGE(cur ^ 1, (t + 1) << 5);
      asm volatile("s_waitcnt vmcnt(4)" ::: "memory");
    } else {
      asm volatile("s_waitcnt vmcnt(0)" ::: "memory");
    }
    __builtin_amdgcn_sched_barrier(0);
    __builtin_amdgcn_s_barrier();
    {
      const int bofs = cur << 12;
      bf16x8 af[4], bfv[4];
      #pragma unroll
      for (int i = 0; i < 4; ++i) {
        int ra = wm + (i << 4) + fr;
        int rb = wn + (i << 4) + fr;
        af[i]  = *(const bf16x8*)&As[bofs + (ra << 5) + ((fkg ^ sxor) << 3)];
        bfv[i] = *(const bf16x8*)&Bs[bofs + (rb << 5) + ((fkg ^ sxor) << 3)];
      }
      #pragma unroll
      for (int i = 0; i < 4; ++i)
        #pragma unroll
        for (int j = 0; j < 4; ++j)
          acc[i][j] = __builtin_amdgcn_mfma_f32_16x16x32_bf16(af[i], bfv[j], acc[i][j], 0, 0, 0);
    }
    __builtin_amdgcn_s_barrier();
    cur ^= 1;
  }

  const int crl = (lane >> 4) << 2, ccl = lane & 15;
  if (p.c_bf16) {
    #pragma unroll
    for (int mi = 0; mi < 4; ++mi)
      #pragma unroll
      for (int r = 0; r < 4; ++r) {
        int lrow = wm + mi * 16 + crl + r;
        #pragma unroll
        for (int ni = 0; ni < 4; ++ni) {
          int lcol = wn + ni * 16 + ccl;
          float v = acc[mi][ni][r];
          int gc = n0 + lcol;
          if (p.bias) v += p.bias[gc];
          if (p.act)  v = siluf(v);
          SH[(lrow << 7) + (((lcol >> 3) ^ (lrow & 15)) << 3) + (lcol & 7)] =
              (short)f2bf(v);
        }
      }
    __syncthreads();
    const int lr = tid >> 1, chalf = (tid & 1) << 6;
    int gr = m0 + lr;
    if (gr < p.M) {
      long long e; int ii;
      if (p.pair) { e = gr >> 1; ii = gr & 1; } else { e = gr; ii = 0; }
      const ushort_t* grw = p.gate ? p.gate + e * p.gse + p.gate_ofs : nullptr;
      #pragma unroll
      for (int j = 0; j < 8; ++j) {
        int lcol = chalf + (j << 3);
        bf16x8 v = *(const bf16x8*)&SH[(lr << 7) + (((lcol >> 3) ^ (lr & 15)) << 3)];
        int gc = n0 + lcol;
        if (grw) {
          bf16x8 g8 = *(const bf16x8*)&grw[gc];
          #pragma unroll
          for (int q2 = 0; q2 < 8; ++q2)
            v[q2] = (short)f2bf(bf2f((ushort_t)v[q2]) * bf2f((ushort_t)g8[q2]));
        }
        int par = (p.ihalf && gc >= 256) ? (1 - ii) : ii;
        long long co = e * (long long)p.c_se + (long long)par * p.c_si + p.c_ofs + gc;
        *(bf16x8*)&((ushort_t*)p.C)[co] = v;
      }
    }
  } else {
    #pragma unroll
    for (int mi = 0; mi < 4; ++mi) {
      #pragma unroll
      for (int r = 0; r < 4; ++r) {
        int gr = m0 + wm + mi * 16 + crl + r;
        if (gr >= p.M) continue;
        long long e = gr;
        float* crow = (float*)p.C + e * (long long)p.c_se + p.c_ofs;
        #pragma unroll
        for (int ni = 0; ni < 4; ++ni) {
          int gc = n0 + wn + ni * 16 + ccl;
          if (gc >= p.N) continue;
          float v = acc[mi][ni][r];
          if (p.bias) v += p.bias[gc];
          if (p.act)  v = siluf(v);
          crow[gc] = v;
        }
      }
    }
  }
}

// ---------------------------------------------------------------------------
// gridmm (atom phase)
// ---------------------------------------------------------------------------
struct GridP {
  const float* A; const ushort_t* B; void* C; const float* bias;
  int b_ib, c_ib;
  int M, K, permA, act, c_bf16;
};

#define LDW 40

__global__ __launch_bounds__(256) void gridmm(GridP p) {
  __shared__ short As[128 * LDW];
  __shared__ short Bs[128 * LDW];
  const int e = blockIdx.x;
  const int tid = threadIdx.x;
  const int srow = tid >> 1, sk = (tid & 1) << 4;
  const int lane = tid & 63, wave = tid >> 6;
  const int wm = (wave >> 1) << 6, wn = (wave & 1) << 6;
  const int fr = lane & 15, fk = (lane >> 4) << 3;

  f32x4 acc[4][4];
  #pragma unroll
  for (int i = 0; i < 4; ++i)
    #pragma unroll
    for (int j = 0; j < 4; ++j) acc[i][j] = (f32x4){0.f, 0.f, 0.f, 0.f};

  const ushort_t* bp0 = p.B + (long long)e * p.b_ib;

  for (int k0 = 0; k0 < p.K; k0 += 32) {
    {
      bf16x8 lo = (bf16x8)0, hi = (bf16x8)0;
      if (srow < p.M) {
        const float* ar = p.A + srow * p.K;
        #pragma unroll
        for (int j = 0; j < 8; ++j) {
          int col = k0 + sk + j;
          float v = 0.f;
          if (col < p.K) v = ar[p.permA ? c_perm[col] : col];
          lo[j] = (short)f2bf(v);
        }
        #pragma unroll
        for (int j = 0; j < 8; ++j) {
          int col = k0 + sk + 8 + j;
          float v = 0.f;
          if (col < p.K) v = ar[p.permA ? c_perm[col] : col];
          hi[j] = (short)f2bf(v);
        }
      }
      *(bf16x8*)&As[srow * LDW + sk] = lo;
      *(bf16x8*)&As[srow * LDW + sk + 8] = hi;
    }
    {
      const int c = tid & 127, kq = tid >> 7;
      #pragma unroll
      for (int i = 0; i < 8; ++i) {
        int kk = kq * 16 + i * 2;
        int k1 = k0 + kk, k2 = k1 + 1;
        uint32 v0 = (k1 < p.K) ? (uint32)bp0[(long long)k1 * 128 + c] : 0u;
        uint32 v1 = (k2 < p.K) ? (uint32)bp0[(long long)k2 * 128 + c] : 0u;
        *(uint32*)&Bs[c * LDW + kk] = v0 | (v1 << 16);
      }
    }
    __syncthreads();
    bf16x8 af[4], bfv[4];
    #pragma unroll
    for (int i = 0; i < 4; ++i) {
      af[i]  = *(const bf16x8*)(&As[(wm + i * 16 + fr) * LDW + fk]);
      bfv[i] = *(const bf16x8*)(&Bs[(wn + i * 16 + fr) * LDW + fk]);
    }
    #pragma unroll
    for (int i = 0; i < 4; ++i)
      #pragma unroll
      for (int j = 0; j < 4; ++j)
        acc[i][j] = __builtin_amdgcn_mfma_f32_16x16x32_bf16(af[i], bfv[j], acc[i][j], 0, 0, 0);
    __syncthreads();
  }

  const int crl = (lane >> 4) << 2, ccl = lane & 15;
  #pragma unroll
  for (int mi = 0; mi < 4; ++mi) {
    #pragma unroll
    for (int r = 0; r < 4; ++r) {
      int gr = wm + mi * 16 + crl + r;
      if (gr >= p.M) continue;
      #pragma unroll
      for (int ni = 0; ni < 4; ++ni) {
        int c = wn + ni * 16 + ccl;
        float v = acc[mi][ni][r];
        if (p.bias) v += p.bias[c];
        if (p.act)  v = siluf(v);
        long long co = (long long)e * p.c_ib + gr * 128 + c;
        if (p.c_bf16) ((ushort_t*)p.C)[co] = f2bf(v);
        else          ((float*)p.C)[co] = v;
      }
    }
  }
}

// ---------------------------------------------------------------------------
// Fused grid pipeline per edge: msg3 = WI @ (FG @ silu(TGp @ msgp))
// ---------------------------------------------------------------------------
#define SWZ8(cg, r) (((cg) ^ ((r) & 7)) & 7)
#define SWZ16(cg, r) (((cg) & 8) | (((cg) ^ (r)) & 7))

__global__ __launch_bounds__(256, 2) void k_grid(
    const ushort_t* __restrict__ tgb, const ushort_t* __restrict__ fgb,
    const float* __restrict__ wigv, const ushort_t* __restrict__ msgp,
    ushort_t* __restrict__ msg3)
{
  __shared__ short Abuf[8192];
  __shared__ short Bsh[8192];
  __shared__ short Ps[16384];
  const int e = blockIdx.x, tid = threadIdx.x;
  const int lane = tid & 63, wv = tid >> 6;
  const int fr = lane & 15, fk = (lane >> 4) << 3;
  const int crl = (lane >> 4) << 2, ccl = lane & 15;
  const ushort_t* me = msgp + (long long)e * 6272;

  for (int gid = tid; gid < 896; gid += 256) {
    int r = gid >> 3, cg = gid & 7;
    bf16x8 v = (bf16x8)0;
    if (r < 98) {
      #pragma unroll
      for (int j = 0; j < 8; ++j) {
        int col = (cg << 3) + j;
        if (col < 49) v[j] = (short)tgb[r * 49 + col];
      }
    }
    *(bf16x8*)&Abuf[(r << 6) + (SWZ8(cg, r) << 3)] = v;
  }
  for (int gid = tid; gid < 1024; gid += 256) {
    int kg = gid >> 7, c = gid & 127;
    bf16x8 v = (bf16x8)0;
    #pragma unroll
    for (int j = 0; j < 8; ++j) {
      int k = (kg << 3) + j;
      if (k < 49) v[j] = (short)me[k * 128 + c];
    }
    *(bf16x8*)&Bsh[(c << 6) + (SWZ8(kg, c) << 3)] = v;
  }
  {
    int c = tid >> 1, gg = 14 + (tid & 1);
    *(bf16x8*)&Ps[(c << 7) + (SWZ16(gg, c) << 3)] = (bf16x8)0;
  }
  __syncthreads();

  {
    f32x4 acc[7][2];
    #pragma unroll
    for (int i = 0; i < 7; ++i) { acc[i][0] = (f32x4){0,0,0,0}; acc[i][1] = (f32x4){0,0,0,0}; }
    #pragma unroll
    for (int k0 = 0; k0 < 64; k0 += 32) {
      int cg = (k0 + fk) >> 3;
      int br0 = ((2 * wv) << 4) + fr, br1 = ((2 * wv + 1) << 4) + fr;
      bf16x8 bf0 = *(const bf16x8*)&Bsh[(br0 << 6) + (SWZ8(cg, br0) << 3)];
      bf16x8 bf1 = *(const bf16x8*)&Bsh[(br1 << 6) + (SWZ8(cg, br1) << 3)];
      #pragma unroll
      for (int rt = 0; rt < 7; ++rt) {
        int ar = (rt << 4) + fr;
        bf16x8 af = *(const bf16x8*)&Abuf[(ar << 6) + (SWZ8(cg, ar) << 3)];
        acc[rt][0] = __builtin_amdgcn_mfma_f32_16x16x32_bf16(af, bf0, acc[rt][0], 0, 0, 0);
        acc[rt][1] = __builtin_amdgcn_mfma_f32_16x16x32_bf16(af, bf1, acc[rt][1], 0, 0, 0);
      }
    }
    #pragma unroll
    for (int rt = 0; rt < 7; ++rt)
      #pragma unroll
      for (int cj = 0; cj < 2; ++cj) {
        int c = ((2 * wv + cj) << 4) + ccl;
        #pragma unroll
        for (int r = 0; r < 4; ++r) {
          int g = (rt << 4) + crl + r;
          Ps[(c << 7) + (SWZ16(g >> 3, c) << 3) + (g & 7)] =
              (short)f2bf(siluf(acc[rt][cj][r]));
        }
      }
  }
  __syncthreads();
  for (int gid = tid; gid < 1024; gid += 256) {
    int r = gid >> 4, cg = gid & 15;
    bf16x8 v = (bf16x8)0;
    if (r < 49) {
      #pragma unroll
      for (int j = 0; j < 8; ++j) {
        int col = (cg << 3) + j;
        if (col < 98) v[j] = (short)fgb[r * 98 + col];
      }
    }
    *(bf16x8*)&Abuf[(r << 7) + (SWZ16(cg, r) << 3)] = v;
  }
  __syncthreads();

  {
    f32x4 acc[4][2];
    #pragma unroll
    for (int i = 0; i < 4; ++i) { acc[i][0] = (f32x4){0,0,0,0}; acc[i][1] = (f32x4){0,0,0,0}; }
    #pragma unroll
    for (int k0 = 0; k0 < 128; k0 += 32) {
      int cg = (k0 + fk) >> 3;
      int br0 = ((2 * wv) << 4) + fr, br1 = ((2 * wv + 1) << 4) + fr;
      bf16x8 bf0 = *(const bf16x8*)&Ps[(br0 << 7) + (SWZ16(cg, br0) << 3)];
      bf16x8 bf1 = *(const bf16x8*)&Ps[(br1 << 7) + (SWZ16(cg, br1) << 3)];
      #pragma unroll
      for (int rt = 0; rt < 4; ++rt) {
        int ar = (rt << 4) + fr;
        bf16x8 af = *(const bf16x8*)&Abuf[(ar << 7) + (SWZ16(cg, ar) << 3)];
        acc[rt][0] = __builtin_amdgcn_mfma_f32_16x16x32_bf16(af, bf0, acc[rt][0], 0, 0, 0);
        acc[rt][1] = __builtin_amdgcn_mfma_f32_16x16x32_bf16(af, bf1, acc[rt][1], 0, 0, 0);
      }
    }
    #pragma unroll
    for (int rt = 0; rt < 4; ++rt)
      #pragma unroll
      for (int cj = 0; cj < 2; ++cj) {
        int c = ((2 * wv + cj) << 4) + ccl;
        #pragma unroll
        for (int r = 0; r < 4; ++r) {
          int q = (rt << 4) + crl + r;
          Bsh[(c << 6) + (SWZ8(q >> 3, c) << 3) + (q & 7)] = (short)f2bf(acc[rt][cj][r]);
        }
      }
  }
  __syncthreads();
  {
    const float* we = wigv + (long long)e * 2401;
    for (int gid = tid; gid < 512; gid += 256) {
      int r = gid >> 3, cg = gid & 7;
      bf16x8 v = (bf16x8)0;
      if (r < 49) {
        #pragma unroll
        for (int j = 0; j < 8; ++j) {
          int col = (cg << 3) + j;
          if (col < 49) v[j] = (short)f2bf(we[r * 49 + col]);
        }
      }
      *(bf16x8*)&Abuf[(r << 6) + (SWZ8(cg, r) << 3)] = v;
    }
  }
  __syncthreads();

  {
    f32x4 acc[4][2];
    #pragma unroll
    for (int i = 0; i < 4; ++i) { acc[i][0] = (f32x4){0,0,0,0}; acc[i][1] = (f32x4){0,0,0,0}; }
    #pragma unroll
    for (int k0 = 0; k0 < 64; k0 += 32) {
      int cg = (k0 + fk) >> 3;
      int br0 = ((2 * wv) << 4) + fr, br1 = ((2 * wv + 1) << 4) + fr;
      bf16x8 bf0 = *(const bf16x8*)&Bsh[(br0 << 6) + (SWZ8(cg, br0) << 3)];
      bf16x8 bf1 = *(const bf16x8*)&Bsh[(br1 << 6) + (SWZ8(cg, br1) << 3)];
      #pragma unroll
      for (int rt = 0; rt < 4; ++rt) {
        int ar = (rt << 4) + fr;
        bf16x8 af = *(const bf16x8*)&Abuf[(ar << 6) + (SWZ8(cg, ar) << 3)];
        acc[rt][0] = __builtin_amdgcn_mfma_f32_16x16x32_bf16(af, bf0, acc[rt][0], 0, 0, 0);
        acc[rt][1] = __builtin_amdgcn_mfma_f32_16x16x32_bf16(af, bf1, acc[rt][1], 0, 0, 0);
      }
    }
    #pragma unroll
    for (int rt = 0; rt < 4; ++rt)
      #pragma unroll
      for (int r = 0; r < 4; ++r) {
        int gi = (rt << 4) + crl + r;
        if (gi < 49) {
          #pragma unroll
          for (int cj = 0; cj < 2; ++cj) {
            int c = ((2 * wv + cj) << 4) + ccl;
            Ps[(gi << 7) + (((c >> 3) ^ (gi & 15)) << 3) + (c & 7)] =
                (short)f2bf(acc[rt][cj][r]);
          }
        }
      }
    __syncthreads();
    ushort_t* oe = msg3 + (long long)e * 6272;
    for (int gid = tid; gid < 784; gid += 256) {
      int row = gid >> 4, cc = gid & 15;
      bf16x8 v = *(const bf16x8*)&Ps[(row << 7) + ((cc ^ (row & 15)) << 3)];
      *(bf16x8*)&oe[(row << 7) + (cc << 3)] = v;
    }
  }
}

// ---------------------------------------------------------------------------
// Segment-sum via per-atom edge lists (vectorized bf16x8 gather)
// ---------------------------------------------------------------------------
__global__ __launch_bounds__(256) void k_zeroi(int* __restrict__ p, int n) {
  int id = blockIdx.x * 256 + threadIdx.x;
  if (id < n) p[id] = 0;
}

__global__ __launch_bounds__(256) void k_deg(
    const int* __restrict__ tgt, int* __restrict__ deg) {
  int e = blockIdx.x * 256 + threadIdx.x;
  if (e < EN) atomicAdd(&deg[tgt[e]], 1);
}

__global__ __launch_bounds__(1024) void k_prefix(
    const int* __restrict__ deg, int* __restrict__ base) {
  __shared__ int s[1024];
  int t = threadIdx.x;
  s[t] = (t < AN) ? deg[t] : 0;
  __syncthreads();
  for (int ofs = 1; ofs < 1024; ofs <<= 1) {
    int u = (t >= ofs) ? s[t - ofs] : 0;
    __syncthreads();
    s[t] += u;
    __syncthreads();
  }
  if (t < AN) base[t + 1] = s[t];
  if (t == 0) base[0] = 0;
}

__global__ __launch_bounds__(256) void k_fill(
    const int* __restrict__ tgt, const int* __restrict__ base,
    int* __restrict__ list) {
  const int a = blockIdx.x, t = threadIdx.x;
  const int lane = t & 63, w = t >> 6;
  __shared__ int wtot[4];
  __shared__ int runbase;
  if (t == 0) runbase = base[a];
  __syncthreads();
  for (int i0 = 0; i0 < EN; i0 += 256) {
    int e = i0 + t;
    bool m = (e < EN) && (tgt[e] == a);
    unsigned long long bal = __ballot(m);
    if (lane == 0) wtot[w] = __popcll(bal);
    __syncthreads();
    int wbase = 0;
    for (int j = 0; j < w; ++j) wbase += wtot[j];
    int tot = wtot[0] + wtot[1] + wtot[2] + wtot[3];
    if (m) {
      int off = __popcll(bal & ((1ull << lane) - 1ull));
      list[runbase + wbase + off] = e;
    }
    __syncthreads();
    if (t == 0) runbase += tot;
    __syncthreads();
  }
}

__global__ __launch_bounds__(256) void k_gather4(
    const ushort_t* __restrict__ msg3, const int* __restrict__ base,
    const int* __restrict__ list, float* __restrict__ xmsg,
    ushort_t* __restrict__ xmsgb,
    int e0, int ce, int accum, int direct)
{
  const int a = blockIdx.x, part = blockIdx.y, t = threadIdx.x;
  if (t >= 196) return;
  const int b0 = base[a], b1 = base[a + 1];
  const int co = part * 1568 + t * 8;
  float a8[8];
  #pragma unroll
  for (int u = 0; u < 8; ++u) a8[u] = 0.f;
  for (int i = b0; i < b1; ++i) {
    int e = list[i];
    if (e < e0 || e >= e0 + ce) continue;
    bf16x8 v = *(const bf16x8*)&msg3[(long long)(e - e0) * 6272 + co];
    #pragma unroll
    for (int u = 0; u < 8; ++u) a8[u] += bf2f((ushort_t)v[u]);
  }
  if (direct) {
    bf16x8 o8;
    #pragma unroll
    for (int u = 0; u < 8; ++u) o8[u] = (short)f2bf(a8[u]);
    *(bf16x8*)&xmsgb[(long long)a * 6272 + co] = o8;
    return;
  }
  float* o = xmsg + (long long)a * 6272 + co;
  if (accum) {
    #pragma unroll
    for (int u = 0; u < 8; ++u) o[u] += a8[u];
  } else {
    float4 lo = make_float4(a8[0], a8[1], a8[2], a8[3]);
    float4 hi = make_float4(a8[4], a8[5], a8[6], a8[7]);
    *(float4*)o = lo;
    *(float4*)(o + 4) = hi;
  }
}

// ---------------------------------------------------------------------------
// Host orchestration
// ---------------------------------------------------------------------------
extern "C" void kernel_launch(void* const* d_in, const int* in_sizes, int n_in,
                              void* d_out, int out_size, void* d_ws, size_t ws_size,
                              hipStream_t stream) {
  const float* x         = (const float*)d_in[0];
  const float* edist     = (const float*)d_in[1];
  const float* wigner    = (const float*)d_in[2];
  const float* wiginv    = (const float*)d_in[3];
  const float* to_grid   = (const float*)d_in[4];
  const float* from_grid = (const float*)d_in[5];
  const float* w_dist1   = (const float*)d_in[6];
  const float* b_dist1   = (const float*)d_in[7];
  const float* src_emb   = (const float*)d_in[8];
  const float* tgt_emb   = (const float*)d_in[9];
  const float* w_edge1   = (const float*)d_in[10];
  const float* b_edge1   = (const float*)d_in[11];
  const float* ws1       = (const float*)d_in[12];
  const float* bs1       = (const float*)d_in[13];
  const float* ws2       = (const float*)d_in[14];
  const float* bs2       = (const float*)d_in[15];
  const float* ws3       = (const float*)d_in[16];
  const float* bs3       = (const float*)d_in[17];
  const int*   anum      = (const int*)d_in[18];
  const int*   eidx      = (const int*)d_in[19];
  const float* sw[10]; const float* tw[10];
  for (int i = 0; i < 10; ++i) {
    sw[i] = (const float*)d_in[20 + i];
    tw[i] = (const float*)d_in[30 + i];
  }
  float* outp = (float*)d_out;

  // ---- workspace ----
  char* wsb = (char*)d_ws;
  size_t off = 0;
  auto alloc = [&](long long nbytes) {
    char* p = wsb + off; off += (size_t)((nbytes + 63) & ~63LL); return p;
  };
  ushort_t* x_edge  = (ushort_t*)alloc((8000LL + 128) * 128 * 2);
  ushort_t* b2ab    = (ushort_t*)alloc(5505024LL * 2);
  ushort_t* bgcw    = (ushort_t*)alloc(851968LL * 2);
  float*    bgcb    = (float*)alloc(6656 * 4);
  ushort_t* b20b    = (ushort_t*)alloc(458752LL * 2);
  ushort_t* s1m0b   = (ushort_t*)alloc(458752LL * 2);
  ushort_t* s1mb    = (ushort_t*)alloc(2752512LL * 2);
  ushort_t* wd1b    = (ushort_t*)alloc(65536 * 2);
  ushort_t* we1b    = (ushort_t*)alloc(16384 * 2);
  ushort_t* ws1b    = (ushort_t*)alloc(32768 * 2);
  ushort_t* ws2b    = (ushort_t*)alloc(16384 * 2);
  ushort_t* ws3b    = (ushort_t*)alloc(16384 * 2);
  ushort_t* tgb     = (ushort_t*)alloc(4802 * 2);
  ushort_t* fgb     = (ushort_t*)alloc(4802 * 2);
  float*    xmsg    = (float*)alloc(5017600LL * 4);
  ushort_t* xmsgb   = (ushort_t*)alloc((5017600LL + 16384) * 2);
  ushort_t* xb      = (ushort_t*)alloc((5017600LL + 16384) * 2);
  ushort_t* xbT     = (ushort_t*)alloc(6553600LL * 2);
  ushort_t* basis   = (ushort_t*)alloc((8000LL + 128) * 512 * 2);
  float*    x_dist  = (float*)alloc(1024000LL * 4);
  ushort_t* x_distb = (ushort_t*)alloc((8000LL + 128) * 128 * 2);
  int*      deg     = (int*)alloc(800 * 4);
  int*      sbase   = (int*)alloc(801 * 4);
  int*      elist   = (int*)alloc(8000 * 4);
  const size_t fixedB = off;
  char* arena = wsb + off;

  static const int ces[6] = {8000, 4000, 2000, 1000, 500, 250};
  static const int cas[6] = {800, 800, 800, 400, 200, 100};
  int ce = 250, ca = 100;
  for (int i = 0; i < 6; ++i) {
    long long ne = (long long)ces[i] * 76544 + 64LL * 50688;
    long long na = (long long)cas[i] * 87808 + 64LL * 512;
    long long need = (long long)fixedB + (ne > na ? ne : na);
    if (need <= (long long)ws_size) { ce = ces[i]; ca = cas[i]; break; }
  }

  // edge-phase arena (padded A-sources)
  char* ap = arena;
  ushort_t* xrot_s = (ushort_t*)ap;  ap += (long long)(ce + 64) * 12544;
  ushort_t* xrot_t = (ushort_t*)ap;  ap += (long long)(ce + 64) * 12544;
  ushort_t* tb0    = (ushort_t*)ap;  ap += (long long)(ce + 64) * 1024;
  ushort_t* tbm    = (ushort_t*)ap;  ap += (long long)(ce + 64) * 24576;
  ushort_t* msgp   = (ushort_t*)ap;  ap += (long long)ce * 12544;
  ushort_t* gate   = (ushort_t*)ap;
  ushort_t* msg3   = (ushort_t*)arena;
  // atom-phase arena
  char* bp = arena;
  ushort_t* hb = (ushort_t*)bp;  bp += (long long)ca * 49 * 256;
  ushort_t* g1 = (ushort_t*)bp;  bp += ((long long)ca * 98 + 64) * 256;
  ushort_t* g2 = (ushort_t*)bp;  bp += ((long long)ca * 98 + 64) * 256;
  ushort_t* g3 = (ushort_t*)bp;

  long long ofs2[7][2], s1ofs[7][2];
  { long long cur = 0, cur1 = 0;
    for (int m = 1; m <= 6; ++m) {
      int k = (7 - m) * 128;
      ofs2[m][0] = cur; cur += (long long)k * 1024;
      ofs2[m][1] = cur; cur += (long long)k * 1024;
      s1ofs[m][0] = cur1; cur1 += 512LL * k;
      s1ofs[m][1] = cur1; cur1 += 512LL * k;
    } }

  auto D0 = []() { GemmP p; memset(&p, 0, sizeof(p)); p.asplit = 1 << 30; p.gse = 6656; return p; };
  auto finalize = [&](Grouped& G) {
    int base = 0;
    for (int i = 0; i < G.nd; ++i) {
      GemmP& p = G.d[i];
      p.ngx = (p.M + 127) >> 7;
      p.ngy = (p.N + 127) >> 7;
      p.wg_base = base;
      base += p.ngx * p.ngy;
    }
    G.nwg = base;
    gemm_g<<<base, 256, 0, stream>>>(G);
  };
  auto run1 = [&](GemmP p) { Grouped G; G.d[0] = p; G.nd = 1; finalize(G); };
  auto rungrid = [&](const float* A, int M, int K, int permA,
                     const ushort_t* B, int b_ib, void* C, int c_ib,
                     const float* bias, int act, int c_bf16, int nb) {
    GridP p;
    p.A = A; p.B = B; p.C = C; p.bias = bias;
    p.b_ib = b_ib; p.c_ib = c_ib;
    p.M = M; p.K = K; p.permA = permA; p.act = act; p.c_bf16 = c_bf16;
    gridmm<<<nb, 256, 0, stream>>>(p);
  };

  // 0) merged weight builds (one launch)
  { BuildP P;
    P.sw7 = sw[7]; P.sw9 = sw[9]; P.tw7 = tw[7]; P.tw9 = tw[9];
    P.sw0 = sw[0]; P.tw0 = tw[0]; P.sw4 = sw[4]; P.tw4 = tw[4];
    P.sb1 = sw[1]; P.tb1 = tw[1]; P.sbd = sw[5]; P.tbd = tw[5];
    P.sw3 = sw[3]; P.tw3 = tw[3];
    P.sw6 = sw[6]; P.sw8 = sw[8]; P.tw6 = tw[6]; P.tw8 = tw[8];
    P.tg = to_grid;
    P.b2ab = b2ab; P.bgcw = bgcw; P.b20b = b20b; P.s1mb = s1mb; P.tgb = tgb;
    P.bgcb = bgcb;
    k_build_all<<<(int)((BSEG4 + 255) / 256), 256, 0, stream>>>(P);
  }
  { // merged conversions
    CvtM P;
    const float* ss[9] = { sw[2], tw[2], w_dist1, w_edge1, ws1, ws2, ws3, from_grid, x };
    ushort_t* dd[9] = { s1m0b, s1m0b + 229376, wd1b, we1b, ws1b, ws2b, ws3b, fgb, xb };
    long long nn[9] = { 229376, 229376, 65536, 16384, 32768, 16384, 16384, 4802, 5017600 };
    long long cur = 0;
    for (int i = 0; i < 9; ++i) { P.s[i] = ss[i]; P.d[i] = dd[i]; P.start[i] = cur; cur += nn[i]; }
    P.start[9] = cur;
    k_cvt_multi<<<(int)((cur + 255) / 256), 256, 0, stream>>>(P);
  }
  k_xT<<<AN, 256, 0, stream>>>(x, xbT);

  // scatter lists
  k_zeroi<<<4, 256, 0, stream>>>(deg, 800);
  k_deg<<<(EN + 255) / 256, 256, 0, stream>>>(eidx + EN, deg);
  k_prefix<<<1, 1024, 0, stream>>>(deg, sbase);
  k_fill<<<AN, 256, 0, stream>>>(eidx + EN, sbase, elist);

  // 1) edge features
  k_basis<<<(EN * 512 + 255) / 256, 256, 0, stream>>>(edist, basis);
  { GemmP p = D0();
    p.A = basis; p.a_se = 512; p.B = wd1b; p.ldb = 512; p.bias = b_dist1;
    p.C = x_dist; p.c_se = 128; p.M = EN; p.N = 128; p.K = 512;
    run1(p); }
  k_emb<<<(EN * 128 + 255) / 256, 256, 0, stream>>>(src_emb, tgt_emb, anum, eidx,
                                                    x_dist, x_distb);
  { GemmP p = D0();
    p.A = x_distb; p.a_se = 128; p.B = we1b; p.ldb = 128; p.bias = b_edge1;
    p.act = 1; p.C = x_edge; p.c_se = 128; p.c_bf16 = 1;
    p.M = EN; p.N = 128; p.K = 128;
    run1(p); }

  static const int offq[7] = {0, 7, 19, 29, 37, 43, 47};
  const int single = (ce == EN);

  // 2) edge chunks
  for (int e0 = 0; e0 < EN; e0 += ce) {
    const int c = ce;
    k_rot2<<<c, 256, 0, stream>>>(wigner + (long long)e0 * 2401, xbT,
                                  eidx + e0, eidx + EN + e0, xrot_s, xrot_t);
    // gates (N=6656)
    { GemmP p = D0();
      p.A = x_edge + (long long)e0 * 128; p.a_se = 128;
      p.B = bgcw; p.ldb = 128; p.bias = bgcb; p.act = 1;
      p.C = gate; p.c_se = 6656; p.c_bf16 = 1;
      p.M = c; p.N = 6656; p.K = 128;
      run1(p); }
    // stage 1 grouped
    { Grouped G; G.nd = 14;
      for (int s = 0; s < 2; ++s) {
        GemmP p = D0();
        p.A = s ? xrot_t : xrot_s; p.a_se = 6272;
        p.B = s1m0b + (long long)s * 229376; p.ldb = 896;
        p.gate = gate; p.gate_ofs = s * 256;
        p.C = tb0; p.c_se = 512; p.c_ofs = s * 256; p.c_bf16 = 1;
        p.M = c; p.N = 256; p.K = 896;
        G.d[s] = p;
      }
      int di = 2;
      for (int m = 1; m <= 6; ++m) {
        const int k = (7 - m) * 128, off2 = offq[m];
        for (int s = 0; s < 2; ++s) {
          GemmP p = D0();
          p.A = (s ? xrot_t : xrot_s) + off2 * 128;
          p.a_se = 6272; p.a_si = k; p.pair = 1;
          p.B = s1mb + s1ofs[m][s]; p.ldb = k;
          p.gate = gate; p.gate_ofs = 512 + (m - 1) * 1024 + s * 512;
          p.C = tbm; p.c_se = 12288; p.c_si = 1024;
          p.c_ofs = (m - 1) * 2048 + s * 512;
          p.ihalf = 1; p.c_bf16 = 1;
          p.M = 2 * c; p.N = 512; p.K = k;
          G.d[di++] = p;
        }
      }
      finalize(G); }
    // stage 2 grouped
    { Grouped G; G.nd = 13;
      { GemmP p = D0();
        p.A = tb0; p.a_se = 512;
        p.B = b20b; p.ldb = 512;
        p.C = msgp; p.c_se = 6272; p.c_bf16 = 1;
        p.M = c; p.N = 896; p.K = 512;
        G.d[0] = p; }
      int di = 1;
      for (int m = 1; m <= 6; ++m) {
        const int n = 7 - m, k = n * 128, off2 = offq[m];
        for (int pp = 0; pp < 2; ++pp) {
          GemmP p = D0();
          p.A = tbm + (m - 1) * 2048 + pp * 1024; p.a_se = 12288;
          p.B = b2ab + ofs2[m][pp]; p.ldb = 1024;
          p.C = msgp; p.c_se = 6272; p.c_ofs = (off2 + (pp ? n : 0)) * 128; p.c_bf16 = 1;
          p.M = c; p.N = k; p.K = 1024;
          G.d[di++] = p;
        }
      }
      finalize(G); }
    // fused grid pipeline + gather
    k_grid<<<c, 256, 0, stream>>>(tgb, fgb, wiginv + (long long)e0 * 2401, msgp, msg3);
    k_gather4<<<dim3(AN, 4), 256, 0, stream>>>(msg3, sbase, elist, xmsg, xmsgb,
                                               e0, c, e0 > 0, single);
  }

  // xmsg -> bf16 (only needed when chunked)
  if (!single)
    k_cvt<<<(5017600 + 255) / 256, 256, 0, stream>>>(xmsg, xmsgb, 5017600);

  // 3) atom phase
  for (int a0 = 0; a0 < AN; a0 += ca) {
    { GemmP p = D0();
      p.A = xb + (long long)a0 * 6272; p.A2 = xmsgb + (long long)a0 * 6272;
      p.a_se = 128; p.asplit = 128;
      p.B = ws1b; p.ldb = 256;
      p.C = hb; p.c_se = 128; p.c_bf16 = 1;
      p.M = ca * 49; p.N = 128; p.K = 256;
      run1(p); }
    rungrid(to_grid, 98, 49, 0, hb, 6272, g1, 12544, bs1, 1, 1, ca);
    { GemmP p = D0();
      p.A = g1; p.a_se = 128;
      p.B = ws2b; p.ldb = 128; p.bias = bs2; p.act = 1;
      p.C = g2; p.c_se = 128; p.c_bf16 = 1;
      p.M = ca * 98; p.N = 128; p.K = 128;
      run1(p); }
    { GemmP p = D0();
      p.A = g2; p.a_se = 128;
      p.B = ws3b; p.ldb = 128; p.bias = bs3;
      p.C = g3; p.c_se = 128; p.c_bf16 = 1;
      p.M = ca * 98; p.N = 128; p.K = 128;
      run1(p); }
    rungrid(from_grid, 49, 98, 0, g3, 12544, outp + (long long)a0 * 6272, 6272,
            nullptr, 0, 0, ca);
  }
}